// Round 1
// baseline (5022.719 us; speedup 1.0000x reference)
//
#include <hip/hip_runtime.h>
#include <hip/hip_bf16.h>
#include <math.h>

// Problem constants
#define Bc   4
#define Tc   6
#define Nc   1024
#define CSc  48
#define GSc  32
#define Hc   270
#define ATc  32
#define DAc  64
#define Ec   32
#define Lc   32
#define EDc  400
#define OUTc 4000
#define H3c  810    // 3*H
#define H4c  1080   // 4*H
#define BEc  128    // B*E
#define INV_SQRT_AT_F 0.17677669529663687f

__device__ __forceinline__ float sigmoid_f(float x){ return 1.0f/(1.0f+expf(-x)); }

// ---------------------------------------------------------------------------
// Generic f32 tiled GEMM: C = act(A[M,K] @ B[K,N] + bias), row-major, batched
// ACT: 0 none, 1 leaky_relu(0.01), 2 tanh, 3 sigmoid
// ---------------------------------------------------------------------------
template<int ACT>
__global__ __launch_bounds__(256)
void gemm_kernel(const float* __restrict__ A, const float* __restrict__ Bm,
                 const float* __restrict__ bias, float* __restrict__ C,
                 int M, int Nn, int K,
                 long long sA, long long sB, long long sC)
{
    constexpr int BM=64, BN=64, BK=16;
    __shared__ float As[BK][BM+4];
    __shared__ float Bs[BK][BN+4];
    A  += (size_t)blockIdx.z * (size_t)sA;
    Bm += (size_t)blockIdx.z * (size_t)sB;
    C  += (size_t)blockIdx.z * (size_t)sC;
    const int row0 = blockIdx.y*BM, col0 = blockIdx.x*BN;
    const int tid = threadIdx.x;
    const int tr = (tid>>4)<<2;
    const int tc = (tid&15)<<2;
    const int ar = tid>>2;         // 0..63
    const int ac = (tid&3)<<2;     // 0,4,8,12
    const int br = tid>>4;         // 0..15
    const int bc = (tid&15)<<2;    // 0..60
    float acc[4][4] = {};
    for (int k0=0;k0<K;k0+=BK){
        #pragma unroll
        for (int i=0;i<4;i++){
            int gr=row0+ar, gc=k0+ac+i;
            As[ac+i][ar] = (gr<M && gc<K) ? A[(size_t)gr*K+gc] : 0.0f;
        }
        #pragma unroll
        for (int i=0;i<4;i++){
            int gr=k0+br, gc=col0+bc+i;
            Bs[br][bc+i] = (gr<K && gc<Nn) ? Bm[(size_t)gr*Nn+gc] : 0.0f;
        }
        __syncthreads();
        #pragma unroll
        for (int kk=0;kk<BK;kk++){
            float a0=As[kk][tr+0], a1=As[kk][tr+1], a2=As[kk][tr+2], a3=As[kk][tr+3];
            float b0=Bs[kk][tc+0], b1=Bs[kk][tc+1], b2=Bs[kk][tc+2], b3=Bs[kk][tc+3];
            acc[0][0]+=a0*b0; acc[0][1]+=a0*b1; acc[0][2]+=a0*b2; acc[0][3]+=a0*b3;
            acc[1][0]+=a1*b0; acc[1][1]+=a1*b1; acc[1][2]+=a1*b2; acc[1][3]+=a1*b3;
            acc[2][0]+=a2*b0; acc[2][1]+=a2*b1; acc[2][2]+=a2*b2; acc[2][3]+=a2*b3;
            acc[3][0]+=a3*b0; acc[3][1]+=a3*b1; acc[3][2]+=a3*b2; acc[3][3]+=a3*b3;
        }
        __syncthreads();
    }
    #pragma unroll
    for (int i=0;i<4;i++){
        int r=row0+tr+i; if (r>=M) continue;
        #pragma unroll
        for (int j=0;j<4;j++){
            int c=col0+tc+j; if (c>=Nn) continue;
            float x = acc[i][j];
            if (bias) x += bias[c];
            if (ACT==1) x = (x>0.0f)? x : 0.01f*x;
            if (ACT==2) x = tanhf(x);
            if (ACT==3) x = 1.0f/(1.0f+expf(-x));
            C[(size_t)r*Nn+c] = x;
        }
    }
}

static void launch_gemm(hipStream_t st, const float* A, const float* Bm, const float* bias,
                        float* C, int M, int Nn, int K, int act, int nb,
                        long long sA, long long sB, long long sC)
{
    dim3 grid((Nn+63)/64, (M+63)/64, nb);
    dim3 block(256);
    switch(act){
      case 0: gemm_kernel<0><<<grid,block,0,st>>>(A,Bm,bias,C,M,Nn,K,sA,sB,sC); break;
      case 1: gemm_kernel<1><<<grid,block,0,st>>>(A,Bm,bias,C,M,Nn,K,sA,sB,sC); break;
      case 2: gemm_kernel<2><<<grid,block,0,st>>>(A,Bm,bias,C,M,Nn,K,sA,sB,sC); break;
      default: gemm_kernel<3><<<grid,block,0,st>>>(A,Bm,bias,C,M,Nn,K,sA,sB,sC); break;
    }
}

// ---------------------------------------------------------------------------
// Y[n, b*CS+c] = cx[b,t,n]*c_emb[n,c] + nb[b,t,n]*n_emb[n,c]   (for S = adj@Y)
// ---------------------------------------------------------------------------
__global__ void build_Y_kernel(const int* __restrict__ code_x, const int* __restrict__ neighbors,
                               const float* __restrict__ c_emb, const float* __restrict__ n_emb,
                               int t, float* __restrict__ Y)
{
    int n = blockIdx.x;
    int idx = threadIdx.x;                 // 0..191
    if (idx >= Bc*CSc) return;
    int b = idx / CSc, c = idx % CSc;
    float cm = (float)code_x[((size_t)b*Tc+t)*Nc + n];
    float nm = (float)neighbors[((size_t)b*Tc+t)*Nc + n];
    Y[(size_t)n*(Bc*CSc) + idx] = cm*c_emb[(size_t)n*CSc+c] + nm*n_emb[(size_t)n*CSc+c];
}

// ---------------------------------------------------------------------------
// co_in = cm*(c_emb + S), no_in = nm*(n_emb + S); stacked into X2 (2*B*N x CS)
// ---------------------------------------------------------------------------
__global__ void build_conoin_kernel(const int* __restrict__ code_x, const int* __restrict__ neighbors,
                                    const float* __restrict__ c_emb, const float* __restrict__ n_emb,
                                    const float* __restrict__ S, int t, float* __restrict__ X2)
{
    int r = blockIdx.x;            // b*N+n
    int b = r / Nc, n = r % Nc;
    int c = threadIdx.x; if (c >= CSc) return;
    float s  = S[(size_t)n*(Bc*CSc) + b*CSc + c];
    float cm = (float)code_x[((size_t)b*Tc+t)*Nc + n];
    float nm = (float)neighbors[((size_t)b*Tc+t)*Nc + n];
    X2[(size_t)r*CSc + c]               = cm*(c_emb[(size_t)n*CSc+c] + s);
    X2[((size_t)(r+Bc*Nc))*CSc + c]     = nm*(n_emb[(size_t)n*CSc+c] + s);
}

// ---------------------------------------------------------------------------
// q_in = m3 ? u_emb : no_prev
// ---------------------------------------------------------------------------
__global__ void build_qin_kernel(const int* __restrict__ divided, const float* __restrict__ u_emb,
                                 const float* __restrict__ no_prev, int t, float* __restrict__ qin)
{
    int r = blockIdx.x;  // b*N+n
    int b = r / Nc, n = r % Nc;
    int c = threadIdx.x; if (c >= GSc) return;
    bool m3 = divided[(((size_t)b*Tc+t)*Nc+n)*3 + 2] > 0;
    qin[(size_t)r*GSc+c] = m3 ? u_emb[(size_t)n*GSc+c] : no_prev[(size_t)r*GSc+c];
}

// ---------------------------------------------------------------------------
// GRU elementwise combine: hm1 = (1-z)*n + z*h
// ---------------------------------------------------------------------------
__global__ void gru_combine_kernel(const float* __restrict__ gi, const float* __restrict__ gh,
                                   const float* __restrict__ h, float* __restrict__ hm1)
{
    int r = blockIdx.x;  // 0..4095
    size_t o3 = (size_t)r*H3c;
    for (int j = threadIdx.x; j < Hc; j += blockDim.x){
        float ir = gi[o3+j],      hr = gh[o3+j];
        float iz = gi[o3+Hc+j],   hz = gh[o3+Hc+j];
        float in_= gi[o3+2*Hc+j], hn = gh[o3+2*Hc+j];
        float rg = sigmoid_f(ir+hr);
        float zg = sigmoid_f(iz+hz);
        float ng = tanhf(in_ + rg*hn);
        size_t oh = (size_t)r*Hc + j;
        hm1[oh] = (1.0f-zg)*ng + zg*h[oh];
    }
}

// ---------------------------------------------------------------------------
// Attention scores with mask + softmax: one block per (i,b) row
// ---------------------------------------------------------------------------
__global__ __launch_bounds__(256)
void attn_score_kernel(const float* __restrict__ q, const float* __restrict__ k,
                       const int* __restrict__ divided, int t, float* __restrict__ score)
{
    int i = blockIdx.x, b = blockIdx.y;
    int tid = threadIdx.x;
    __shared__ float qs[ATc];
    __shared__ float red[8];
    if (tid < ATc) qs[tid] = q[((size_t)b*Nc+i)*ATc + tid];
    __syncthreads();

    float gvals[4];
    float lmax = -INFINITY, lhas = 0.0f;
    #pragma unroll
    for (int jj=0;jj<4;jj++){
        int j = jj*256 + tid;
        const float* kr = k + ((size_t)b*Nc+j)*ATc;
        float d = 0.0f;
        #pragma unroll
        for (int a=0;a<ATc;a++) d += qs[a]*kr[a];
        d *= INV_SQRT_AT_F;
        const int* dv = divided + (((size_t)b*Tc+t)*Nc + j)*3;
        bool m23 = (dv[1] > 0) || (dv[2] > 0);
        lhas = fmaxf(lhas, m23 ? 1.0f : 0.0f);
        d = m23 ? d : -INFINITY;
        gvals[jj] = d;
        lmax = fmaxf(lmax, d);
    }
    #pragma unroll
    for (int o=1;o<64;o<<=1){
        lmax = fmaxf(lmax, __shfl_xor(lmax, o, 64));
        lhas = fmaxf(lhas, __shfl_xor(lhas, o, 64));
    }
    int wid = tid >> 6;
    if ((tid & 63) == 0){ red[wid] = lmax; red[4+wid] = lhas; }
    __syncthreads();
    float gmax = fmaxf(fmaxf(red[0],red[1]), fmaxf(red[2],red[3]));
    bool  has  = fmaxf(fmaxf(red[4],red[5]), fmaxf(red[6],red[7])) > 0.5f;

    float evals[4];
    float lsum = 0.0f;
    #pragma unroll
    for (int jj=0;jj<4;jj++){
        float e_;
        if (has) e_ = (gvals[jj] == -INFINITY) ? 0.0f : expf(gvals[jj]-gmax);
        else     e_ = 1.0f;   // no masked keys: reference softmaxes zeros -> uniform
        evals[jj] = e_; lsum += e_;
    }
    #pragma unroll
    for (int o=1;o<64;o<<=1) lsum += __shfl_xor(lsum, o, 64);
    __syncthreads();
    if ((tid & 63) == 0) red[wid] = lsum;
    __syncthreads();
    float invs = 1.0f/(red[0]+red[1]+red[2]+red[3]);
    #pragma unroll
    for (int jj=0;jj<4;jj++){
        int j = jj*256 + tid;
        score[((size_t)b*Nc+i)*Nc + j] = evals[jj]*invs;
    }
}

// ---------------------------------------------------------------------------
// h_new = (t>0 && m23) ? hm23 : (m1 ? hm1 : 0)
// ---------------------------------------------------------------------------
__global__ void h_update_kernel(const int* __restrict__ divided, int t,
                                const float* __restrict__ hm1, const float* __restrict__ hm23,
                                float* __restrict__ h)
{
    int r = blockIdx.x; int b = r/Nc, n = r%Nc;
    const int* dv = divided + (((size_t)b*Tc+t)*Nc+n)*3;
    bool m1  = dv[0] > 0;
    bool m23 = (dv[1] > 0) || (dv[2] > 0);
    bool use23 = (t > 0) && m23;
    for (int j = threadIdx.x; j < Hc; j += blockDim.x){
        size_t o = (size_t)r*Hc+j;
        float v_ = 0.0f;
        if (m1)    v_ = hm1[o];
        if (use23) v_ = hm23[o];
        h[o] = v_;
    }
}

// ---------------------------------------------------------------------------
// out_last = (has1 ? max_{m1} hm1 : 0) + (has23 ? max_{m23} hm23 : 0)  [t = T-1]
// ---------------------------------------------------------------------------
__global__ void out_last_kernel(const int* __restrict__ divided,
                                const float* __restrict__ hm1, const float* __restrict__ hm23,
                                float* __restrict__ out_last)
{
    int b = blockIdx.x;
    for (int j = threadIdx.x; j < Hc; j += blockDim.x){
        float mx1 = -INFINITY, mx23 = -INFINITY;
        bool h1 = false, h23 = false;
        for (int n=0;n<Nc;n++){
            const int* dv = divided + (((size_t)b*Tc + (Tc-1))*Nc + n)*3;
            bool m1  = dv[0] > 0;
            bool m23 = (dv[1] > 0) || (dv[2] > 0);
            if (m1) { h1 = true;  mx1  = fmaxf(mx1,  hm1[((size_t)b*Nc+n)*Hc + j]); }
            if (m23){ h23 = true; mx23 = fmaxf(mx23, hm23[((size_t)b*Nc+n)*Hc + j]); }
        }
        out_last[(size_t)b*Hc + j] = (h1 ? mx1 : 0.0f) + (h23 ? mx23 : 0.0f);
    }
}

// ---------------------------------------------------------------------------
// Gather Eemb rows: Xg[l*BE + be, :] = Eemb[events[b, T-1, e, l], :]
// ---------------------------------------------------------------------------
__global__ void gather_emb_kernel(const int* __restrict__ events, const float* __restrict__ Eemb,
                                  float* __restrict__ Xg)
{
    int blk = blockIdx.x;                 // 0..BE*L-1, = l*BE + be
    int l = blk / BEc, be = blk % BEc;
    int b = be / Ec, e = be % Ec;
    int ev = events[(((size_t)b*Tc + (Tc-1))*Ec + e)*Lc + l];
    const float* src = Eemb + (size_t)ev*EDc;
    float* dst = Xg + (size_t)blk*EDc;
    for (int d = threadIdx.x; d < EDc; d += blockDim.x) dst[d] = src[d];
}

// ---------------------------------------------------------------------------
// One LSTM recurrence step for 2 (b,e) cells per block
// ---------------------------------------------------------------------------
__global__ __launch_bounds__(256)
void lstm_step_kernel(const float* __restrict__ gatesx,  // already offset to step l: (BE, 4H)
                      const float* __restrict__ Whh,     // (H, 4H)
                      float* __restrict__ hev, float* __restrict__ cev)
{
    int r0 = blockIdx.x * 2;
    __shared__ float hs[2][Hc];
    __shared__ float gs[2][H4c];
    int tid = threadIdx.x;
    for (int i = tid; i < 2*Hc; i += 256)
        hs[i/Hc][i%Hc] = hev[(size_t)(r0 + i/Hc)*Hc + (i%Hc)];
    __syncthreads();
    for (int idx = tid; idx < 2*H4c; idx += 256){
        int rr = idx / H4c, c = idx % H4c;
        float acc = gatesx[(size_t)(r0+rr)*H4c + c];
        const float* hrow = hs[rr];
        for (int hh=0; hh<Hc; hh++) acc += hrow[hh]*Whh[(size_t)hh*H4c + c];
        gs[rr][c] = acc;
    }
    __syncthreads();
    for (int idx = tid; idx < 2*Hc; idx += 256){
        int rr = idx/Hc, j = idx%Hc;
        float ig = sigmoid_f(gs[rr][j]);
        float fg = sigmoid_f(gs[rr][Hc + j]);
        float gg = tanhf(gs[rr][2*Hc + j]);
        float og = sigmoid_f(gs[rr][3*Hc + j]);
        size_t off = (size_t)(r0+rr)*Hc + j;
        float cn = fg*cev[off] + ig*gg;
        hev[off] = og*tanhf(cn);
        cev[off] = cn;
    }
}

// ---------------------------------------------------------------------------
// stacked[b,0,:] = out_last[b]; stacked[b,1+e,:] = hev[b*E+e]
// ---------------------------------------------------------------------------
__global__ void build_stacked_kernel(const float* __restrict__ out_last, const float* __restrict__ hev,
                                     float* __restrict__ stacked)
{
    int b = blockIdx.x, s = blockIdx.y;
    const float* src = (s==0) ? (out_last + (size_t)b*Hc)
                              : (hev + ((size_t)b*Ec + (s-1))*Hc);
    float* dst = stacked + ((size_t)b*(Ec+1) + s)*Hc;
    for (int j = threadIdx.x; j < Hc; j += blockDim.x) dst[j] = src[j];
}

// wdc[0..H-1] = Wd @ ctx ; wdc[H] = bd . ctx
__global__ void wdctx_kernel(const float* __restrict__ Wd, const float* __restrict__ bd,
                             const float* __restrict__ ctx, float* __restrict__ wdc)
{
    int j = blockIdx.x*blockDim.x + threadIdx.x;
    if (j < Hc){
        float s = 0.0f;
        for (int d=0;d<DAc;d++) s += Wd[(size_t)j*DAc+d]*ctx[d];
        wdc[j] = s;
    } else if (j == Hc){
        float s = 0.0f;
        for (int d=0;d<DAc;d++) s += bd[d]*ctx[d];
        wdc[Hc] = s;
    }
}

// dp_attention over 33 stacked vectors -> o1 (B,H)
__global__ void dp_attn_kernel(const float* __restrict__ stacked, const float* __restrict__ wdc,
                               float* __restrict__ o1)
{
    int b = blockIdx.x;
    int tid = threadIdx.x;
    __shared__ float sc[Ec+1];
    if (tid < Ec+1){
        float s = wdc[Hc];
        const float* x = stacked + ((size_t)b*(Ec+1)+tid)*Hc;
        for (int j=0;j<Hc;j++) s += x[j]*wdc[j];
        sc[tid] = s;
    }
    __syncthreads();
    if (tid == 0){
        float m = -INFINITY;
        for (int s=0;s<Ec+1;s++) m = fmaxf(m, sc[s]);
        float sum = 0.0f;
        for (int s=0;s<Ec+1;s++){ sc[s] = expf(sc[s]-m); sum += sc[s]; }
        float inv = 1.0f/sum;
        for (int s=0;s<Ec+1;s++) sc[s] *= inv;
    }
    __syncthreads();
    for (int j = tid; j < Hc; j += blockDim.x){
        float acc = 0.0f;
        for (int s=0;s<Ec+1;s++) acc += sc[s]*stacked[((size_t)b*(Ec+1)+s)*Hc + j];
        o1[(size_t)b*Hc + j] = acc;
    }
}

// ---------------------------------------------------------------------------
extern "C" void kernel_launch(void* const* d_in, const int* in_sizes, int n_in,
                              void* d_out, int out_size, void* d_ws, size_t ws_size,
                              hipStream_t stream)
{
    const int*   code_x    = (const int*)d_in[0];
    const int*   divided   = (const int*)d_in[1];
    const int*   neighbors = (const int*)d_in[2];
    const int*   events    = (const int*)d_in[4];
    const float* c_emb     = (const float*)d_in[5];
    const float* n_emb     = (const float*)d_in[6];
    const float* u_emb     = (const float*)d_in[7];
    const float* adj       = (const float*)d_in[8];
    const float* Wg        = (const float*)d_in[9];
    const float* bg        = (const float*)d_in[10];
    const float* gru_Wih   = (const float*)d_in[11];
    const float* gru_Whh   = (const float*)d_in[12];
    const float* gru_bih   = (const float*)d_in[13];
    const float* gru_bhh   = (const float*)d_in[14];
    const float* Wq        = (const float*)d_in[15];
    const float* bq        = (const float*)d_in[16];
    const float* Wk        = (const float*)d_in[17];
    const float* bk        = (const float*)d_in[18];
    const float* Wv        = (const float*)d_in[19];
    const float* bv        = (const float*)d_in[20];
    const float* Wd        = (const float*)d_in[21];
    const float* bd        = (const float*)d_in[22];
    const float* ctx       = (const float*)d_in[23];
    const float* Eemb      = (const float*)d_in[24];
    const float* lstm_Wih  = (const float*)d_in[25];
    const float* lstm_Whh  = (const float*)d_in[26];
    const float* lstm_b    = (const float*)d_in[27];
    const float* Wc        = (const float*)d_in[28];
    const float* bc        = (const float*)d_in[29];
    float* out = (float*)d_out;

    float* ws = (float*)d_ws;
    size_t off = 0;
    auto alloc = [&](size_t n){ float* p = ws + off; off += n; return p; };

    float* h_buf   = alloc((size_t)Bc*Nc*Hc);      // GRU/attention hidden state
    float* hm1     = alloc((size_t)Bc*Nc*Hc);
    float* hm23    = alloc((size_t)Bc*Nc*Hc);
    float* vbuf    = alloc((size_t)Bc*Nc*Hc);
    float* noA     = alloc((size_t)Bc*Nc*GSc);
    float* noB     = alloc((size_t)Bc*Nc*GSc);
    float* Ybuf    = alloc((size_t)Nc*Bc*CSc);
    float* Sbuf    = alloc((size_t)Nc*Bc*CSc);
    float* X2      = alloc((size_t)2*Bc*Nc*CSc);
    float* cobuf   = alloc((size_t)Bc*Nc*GSc);
    float* qin     = alloc((size_t)Bc*Nc*GSc);
    float* qb      = alloc((size_t)Bc*Nc*ATc);
    float* kb      = alloc((size_t)Bc*Nc*ATc);
    float* outlast = alloc((size_t)Bc*Hc);
    float* stacked = alloc((size_t)Bc*(Ec+1)*Hc);
    float* wdc     = alloc((size_t)(Hc+1));
    float* o1      = alloc((size_t)Bc*Hc);
    float* hev     = alloc((size_t)BEc*Hc);
    float* cev     = alloc((size_t)BEc*Hc);
    float* gi      = alloc((size_t)Bc*Nc*H3c);     // big region: gi, gh, score
    float* gh      = alloc((size_t)Bc*Nc*H3c);
    float* score   = alloc((size_t)Bc*Nc*Nc);
    (void)ws_size; (void)in_sizes; (void)n_in; (void)out_size;

    // LSTM buffers alias the visit-loop big region (used only after the loop)
    float* Xg     = gi;                              // BE*L*ED = 1,638,400
    float* gatesx = gi + (size_t)BEc*Lc*EDc;         // BE*L*4H = 4,423,680 (fits in gi..score)

    hipMemsetAsync(h_buf, 0, (size_t)Bc*Nc*Hc*sizeof(float), stream);
    hipMemsetAsync(noA,   0, (size_t)Bc*Nc*GSc*sizeof(float), stream);
    hipMemsetAsync(noB,   0, (size_t)Bc*Nc*GSc*sizeof(float), stream);
    hipMemsetAsync(hev,   0, (size_t)BEc*Hc*sizeof(float), stream);
    hipMemsetAsync(cev,   0, (size_t)BEc*Hc*sizeof(float), stream);

    float* no_prev = noB;
    float* no_cur  = noA;
    for (int t=0; t<Tc; t++){
        build_Y_kernel<<<dim3(Nc), dim3(192), 0, stream>>>(code_x, neighbors, c_emb, n_emb, t, Ybuf);
        // S = adj @ Y  (N x 192, K=N)
        launch_gemm(stream, adj, Ybuf, nullptr, Sbuf, Nc, Bc*CSc, Nc, 0, 1, 0,0,0);
        build_conoin_kernel<<<dim3(Bc*Nc), dim3(64), 0, stream>>>(code_x, neighbors, c_emb, n_emb, Sbuf, t, X2);
        // co = leaky(co_in @ Wg + bg), no = leaky(no_in @ Wg + bg)
        launch_gemm(stream, X2,                      Wg, bg, cobuf,  Bc*Nc, GSc, CSc, 1, 1, 0,0,0);
        launch_gemm(stream, X2+(size_t)Bc*Nc*CSc,    Wg, bg, no_cur, Bc*Nc, GSc, CSc, 1, 1, 0,0,0);
        build_qin_kernel<<<dim3(Bc*Nc), dim3(64), 0, stream>>>(divided, u_emb, no_prev, t, qin);
        launch_gemm(stream, qin,   Wq, bq, qb,   Bc*Nc, ATc, GSc, 0, 1, 0,0,0);
        launch_gemm(stream, cobuf, Wk, bk, kb,   Bc*Nc, ATc, GSc, 0, 1, 0,0,0);
        launch_gemm(stream, cobuf, Wv, bv, vbuf, Bc*Nc, Hc,  GSc, 0, 1, 0,0,0);
        // GRU
        launch_gemm(stream, cobuf, gru_Wih, gru_bih, gi, Bc*Nc, H3c, GSc, 0, 1, 0,0,0);
        launch_gemm(stream, h_buf, gru_Whh, gru_bhh, gh, Bc*Nc, H3c, Hc,  0, 1, 0,0,0);
        gru_combine_kernel<<<dim3(Bc*Nc), dim3(256), 0, stream>>>(gi, gh, h_buf, hm1);
        // attention
        attn_score_kernel<<<dim3(Nc, Bc), dim3(256), 0, stream>>>(qb, kb, divided, t, score);
        launch_gemm(stream, score, vbuf, nullptr, hm23, Nc, Hc, Nc, 2, Bc,
                    (long long)Nc*Nc, (long long)Nc*Hc, (long long)Nc*Hc);
        h_update_kernel<<<dim3(Bc*Nc), dim3(256), 0, stream>>>(divided, t, hm1, hm23, h_buf);
        if (t == Tc-1)
            out_last_kernel<<<dim3(Bc), dim3(256), 0, stream>>>(divided, hm1, hm23, outlast);
        float* tmp = no_prev; no_prev = no_cur; no_cur = tmp;
    }

    // LSTM over last-visit events
    gather_emb_kernel<<<dim3(BEc*Lc), dim3(256), 0, stream>>>(events, Eemb, Xg);
    launch_gemm(stream, Xg, lstm_Wih, lstm_b, gatesx, BEc*Lc, H4c, EDc, 0, 1, 0,0,0);
    for (int l=0; l<Lc; l++){
        lstm_step_kernel<<<dim3(BEc/2), dim3(256), 0, stream>>>(gatesx + (size_t)l*BEc*H4c,
                                                                lstm_Whh, hev, cev);
    }

    // heads
    build_stacked_kernel<<<dim3(Bc, Ec+1), dim3(64), 0, stream>>>(outlast, hev, stacked);
    wdctx_kernel<<<dim3(2), dim3(256), 0, stream>>>(Wd, bd, ctx, wdc);
    dp_attn_kernel<<<dim3(Bc), dim3(256), 0, stream>>>(stacked, wdc, o1);
    // final: sigmoid(o1 @ Wc + bc) -> out (B x OUT)
    launch_gemm(stream, o1, Wc, bc, out, Bc, OUTc, Hc, 3, 1, 0,0,0);
}

// Round 2
// 3145.572 us; speedup vs baseline: 1.5968x; 1.5968x over previous
//
#include <hip/hip_runtime.h>
#include <hip/hip_bf16.h>
#include <math.h>

// Problem constants
#define Bc   4
#define Tc   6
#define Nc   1024
#define CSc  48
#define GSc  32
#define Hc   270
#define ATc  32
#define DAc  64
#define Ec   32
#define Lc   32
#define EDc  400
#define OUTc 4000
#define H3c  810    // 3*H
#define H4c  1080   // 4*H
#define BEc  128    // B*E
#define KPH  288    // H padded to multiple of 32 (gh K-dim)
#define KPE  416    // ED padded to multiple of 32 (lstm K-dim)
#define INV_SQRT_AT_F 0.17677669529663687f

typedef unsigned short ushort_t;
using s8v = __attribute__((ext_vector_type(8))) short;
using f4v = __attribute__((ext_vector_type(4))) float;

__device__ __forceinline__ float sigmoid_f(float x){ return 1.0f/(1.0f+expf(-x)); }
__device__ __forceinline__ ushort_t f2bf(float x){
    __hip_bfloat16 b = __float2bfloat16(x);
    return *reinterpret_cast<ushort_t*>(&b);
}

// ---------------------------------------------------------------------------
// bf16 MFMA GEMM: C[M,N](f32) = act(A[M,Kp](bf16,lda) @ BT[N,Kp](bf16,ldb)^T + bias)
// Kp multiple of 32; pads must be zero-filled. 128x128 tile, 4 waves.
// ACT: 0 none, 2 tanh.
// ---------------------------------------------------------------------------
template<int ACT, int BIAS>
__global__ __launch_bounds__(256)
void mfma_gemm(const ushort_t* __restrict__ A, const ushort_t* __restrict__ BT,
               const float* __restrict__ bias, float* __restrict__ C,
               int M, int N, int Kp, int lda, int ldb, int ldc,
               long long sA, long long sB, long long sC)
{
    __shared__ ushort_t As[128*40];   // [row][k] with row stride 40 (+8 pad) -> conflict-free b128
    __shared__ ushort_t Bs[128*40];
    A  += (size_t)blockIdx.z * (size_t)sA;
    BT += (size_t)blockIdx.z * (size_t)sB;
    C  += (size_t)blockIdx.z * (size_t)sC;
    const int m0 = blockIdx.y*128, n0 = blockIdx.x*128;
    const int tid = threadIdx.x;
    const int w = tid>>6, l = tid&63;
    const int wm = (w>>1)*64, wn = (w&1)*64;
    const int lr = l&15, lk = (l>>4)*8, lq = l>>4;
    const int srow = tid>>2, kseg = tid&3;

    f4v acc[4][4];
    #pragma unroll
    for (int mi=0;mi<4;mi++)
      #pragma unroll
      for (int ni=0;ni<4;ni++)
        acc[mi][ni] = (f4v){0.0f,0.0f,0.0f,0.0f};

    for (int k0=0;k0<Kp;k0+=32){
        #pragma unroll
        for (int i=0;i<2;i++){
            int row = srow + i*64;
            int ga = m0+row;
            uint4 va = make_uint4(0u,0u,0u,0u);
            if (ga < M) va = *(const uint4*)(A + (size_t)ga*lda + k0 + kseg*8);
            *(uint4*)&As[row*40 + kseg*8] = va;
            int gb = n0+row;
            uint4 vb = make_uint4(0u,0u,0u,0u);
            if (gb < N) vb = *(const uint4*)(BT + (size_t)gb*ldb + k0 + kseg*8);
            *(uint4*)&Bs[row*40 + kseg*8] = vb;
        }
        __syncthreads();
        s8v af[4], bfr[4];
        #pragma unroll
        for (int mi=0;mi<4;mi++) af[mi]  = *(const s8v*)&As[(wm+mi*16+lr)*40 + lk];
        #pragma unroll
        for (int ni=0;ni<4;ni++) bfr[ni] = *(const s8v*)&Bs[(wn+ni*16+lr)*40 + lk];
        #pragma unroll
        for (int mi=0;mi<4;mi++)
          #pragma unroll
          for (int ni=0;ni<4;ni++)
            acc[mi][ni] = __builtin_amdgcn_mfma_f32_16x16x32_bf16(af[mi], bfr[ni], acc[mi][ni], 0,0,0);
        __syncthreads();
    }

    #pragma unroll
    for (int mi=0;mi<4;mi++){
      #pragma unroll
      for (int ni=0;ni<4;ni++){
        int col = n0+wn+ni*16+lr;
        if (col >= N) continue;
        float bv_ = BIAS ? bias[col] : 0.0f;
        #pragma unroll
        for (int r=0;r<4;r++){
          int row = m0+wm+mi*16+lq*4+r;
          if (row >= M) continue;
          float x = acc[mi][ni][r] + bv_;
          if (ACT==2) x = tanhf(x);
          C[(size_t)row*ldc + col] = x;
        }
      }
    }
}

static void launch_mfma(hipStream_t st, const ushort_t* A, const ushort_t* BT, const float* bias,
                        float* C, int M, int N, int Kp, int lda, int ldb, int ldc,
                        int act, int nb, long long sA, long long sB, long long sC)
{
    dim3 grid((N+127)/128, (M+127)/128, nb);
    dim3 block(256);
    if (act==0 && bias)      mfma_gemm<0,1><<<grid,block,0,st>>>(A,BT,bias,C,M,N,Kp,lda,ldb,ldc,sA,sB,sC);
    else if (act==0)         mfma_gemm<0,0><<<grid,block,0,st>>>(A,BT,bias,C,M,N,Kp,lda,ldb,ldc,sA,sB,sC);
    else if (act==2 && bias) mfma_gemm<2,1><<<grid,block,0,st>>>(A,BT,bias,C,M,N,Kp,lda,ldb,ldc,sA,sB,sC);
    else                     mfma_gemm<2,0><<<grid,block,0,st>>>(A,BT,bias,C,M,N,Kp,lda,ldb,ldc,sA,sB,sC);
}

// ---------------------------------------------------------------------------
// f32 tiled GEMM (small GEMMs). ACT: 0 none, 1 leaky, 3 sigmoid.
// OMODE: 0 normal f32 store; 1 bf16 transposed store CT[c*sC + r]
// ---------------------------------------------------------------------------
template<int ACT, int OMODE>
__global__ __launch_bounds__(256)
void gemm_kernel(const float* __restrict__ A, const float* __restrict__ Bm,
                 const float* __restrict__ bias, float* __restrict__ C,
                 int M, int Nn, int K, long long sC)
{
    constexpr int BM=64, BN=64, BK=16;
    __shared__ float As[BK][BM+4];
    __shared__ float Bs[BK][BN+4];
    const int row0 = blockIdx.y*BM, col0 = blockIdx.x*BN;
    const int tid = threadIdx.x;
    const int tr = (tid>>4)<<2;
    const int tc = (tid&15)<<2;
    const int ar = tid>>2;
    const int ac = (tid&3)<<2;
    const int br = tid>>4;
    const int bc = (tid&15)<<2;
    float acc[4][4] = {};
    for (int k0=0;k0<K;k0+=BK){
        #pragma unroll
        for (int i=0;i<4;i++){
            int gr=row0+ar, gc=k0+ac+i;
            As[ac+i][ar] = (gr<M && gc<K) ? A[(size_t)gr*K+gc] : 0.0f;
        }
        #pragma unroll
        for (int i=0;i<4;i++){
            int gr=k0+br, gc=col0+bc+i;
            Bs[br][bc+i] = (gr<K && gc<Nn) ? Bm[(size_t)gr*Nn+gc] : 0.0f;
        }
        __syncthreads();
        #pragma unroll
        for (int kk=0;kk<BK;kk++){
            float a0=As[kk][tr+0], a1=As[kk][tr+1], a2=As[kk][tr+2], a3=As[kk][tr+3];
            float b0=Bs[kk][tc+0], b1=Bs[kk][tc+1], b2=Bs[kk][tc+2], b3=Bs[kk][tc+3];
            acc[0][0]+=a0*b0; acc[0][1]+=a0*b1; acc[0][2]+=a0*b2; acc[0][3]+=a0*b3;
            acc[1][0]+=a1*b0; acc[1][1]+=a1*b1; acc[1][2]+=a1*b2; acc[1][3]+=a1*b3;
            acc[2][0]+=a2*b0; acc[2][1]+=a2*b1; acc[2][2]+=a2*b2; acc[2][3]+=a2*b3;
            acc[3][0]+=a3*b0; acc[3][1]+=a3*b1; acc[3][2]+=a3*b2; acc[3][3]+=a3*b3;
        }
        __syncthreads();
    }
    #pragma unroll
    for (int i=0;i<4;i++){
        int r=row0+tr+i; if (r>=M) continue;
        #pragma unroll
        for (int j=0;j<4;j++){
            int c=col0+tc+j; if (c>=Nn) continue;
            float x = acc[i][j];
            if (bias) x += bias[c];
            if (ACT==1) x = (x>0.0f)? x : 0.01f*x;
            if (ACT==3) x = 1.0f/(1.0f+expf(-x));
            if (OMODE==0) C[(size_t)r*Nn+c] = x;
            else ((ushort_t*)C)[(size_t)c*sC + r] = f2bf(x);
        }
    }
}

static void launch_gemm(hipStream_t st, const float* A, const float* Bm, const float* bias,
                        float* C, int M, int Nn, int K, int act, int omode, long long sC)
{
    dim3 grid((Nn+63)/64, (M+63)/64, 1);
    dim3 block(256);
    if (omode==1)      gemm_kernel<0,1><<<grid,block,0,st>>>(A,Bm,bias,C,M,Nn,K,sC);
    else if (act==0)   gemm_kernel<0,0><<<grid,block,0,st>>>(A,Bm,bias,C,M,Nn,K,sC);
    else if (act==1)   gemm_kernel<1,0><<<grid,block,0,st>>>(A,Bm,bias,C,M,Nn,K,sC);
    else               gemm_kernel<3,0><<<grid,block,0,st>>>(A,Bm,bias,C,M,Nn,K,sC);
}

// ---------------------------------------------------------------------------
// Conversions
// ---------------------------------------------------------------------------
__global__ void convert_pad_kernel(const float* __restrict__ in, ushort_t* __restrict__ out,
                                   int K, int Kp, long long total)
{
    long long idx = (long long)blockIdx.x*blockDim.x + threadIdx.x;
    if (idx >= total) return;
    int row = (int)(idx / Kp), col = (int)(idx % Kp);
    out[idx] = (col < K) ? f2bf(in[(size_t)row*K + col]) : (ushort_t)0;
}

// out[n*Kp + k] = (k<K) ? bf16(in[k*ldin + n]) : 0
__global__ void transpose_conv_kernel(const float* __restrict__ in, ushort_t* __restrict__ out,
                                      int Nrows, int K, int Kp, int ldin)
{
    long long idx = (long long)blockIdx.x*blockDim.x + threadIdx.x;
    if (idx >= (long long)Nrows*Kp) return;
    int n = (int)(idx / Kp), k = (int)(idx % Kp);
    out[idx] = (k < K) ? f2bf(in[(size_t)k*ldin + n]) : (ushort_t)0;
}

// ---------------------------------------------------------------------------
// YT[bc][n] = bf16(cm*c_emb[n,c] + nm*n_emb[n,c]),  bc = b*CS+c
// ---------------------------------------------------------------------------
__global__ void build_YT_kernel(const int* __restrict__ code_x, const int* __restrict__ neighbors,
                                const float* __restrict__ c_emb, const float* __restrict__ n_emb,
                                int t, ushort_t* __restrict__ YT)
{
    int bc = blockIdx.x;          // 0..191
    int b = bc / CSc, c = bc % CSc;
    for (int n = threadIdx.x; n < Nc; n += 256){
        float cm = (float)code_x[((size_t)b*Tc+t)*Nc + n];
        float nm = (float)neighbors[((size_t)b*Tc+t)*Nc + n];
        YT[(size_t)bc*Nc + n] = f2bf(cm*c_emb[(size_t)n*CSc+c] + nm*n_emb[(size_t)n*CSc+c]);
    }
}

// ---------------------------------------------------------------------------
// co_in/no_in stacked into X2 (2*B*N x CS), from f32 S
// ---------------------------------------------------------------------------
__global__ void build_conoin_kernel(const int* __restrict__ code_x, const int* __restrict__ neighbors,
                                    const float* __restrict__ c_emb, const float* __restrict__ n_emb,
                                    const float* __restrict__ S, int t, float* __restrict__ X2)
{
    int r = blockIdx.x;            // b*N+n
    int b = r / Nc, n = r % Nc;
    int c = threadIdx.x; if (c >= CSc) return;
    float s  = S[(size_t)n*(Bc*CSc) + b*CSc + c];
    float cm = (float)code_x[((size_t)b*Tc+t)*Nc + n];
    float nm = (float)neighbors[((size_t)b*Tc+t)*Nc + n];
    X2[(size_t)r*CSc + c]               = cm*(c_emb[(size_t)n*CSc+c] + s);
    X2[((size_t)(r+Bc*Nc))*CSc + c]     = nm*(n_emb[(size_t)n*CSc+c] + s);
}

__global__ void build_qin_kernel(const int* __restrict__ divided, const float* __restrict__ u_emb,
                                 const float* __restrict__ no_prev, int t, float* __restrict__ qin)
{
    int r = blockIdx.x;  // b*N+n
    int b = r / Nc, n = r % Nc;
    int c = threadIdx.x; if (c >= GSc) return;
    bool m3 = divided[(((size_t)b*Tc+t)*Nc+n)*3 + 2] > 0;
    qin[(size_t)r*GSc+c] = m3 ? u_emb[(size_t)n*GSc+c] : no_prev[(size_t)r*GSc+c];
}

__global__ void gru_combine_kernel(const float* __restrict__ gi, const float* __restrict__ gh,
                                   const float* __restrict__ h, float* __restrict__ hm1)
{
    int r = blockIdx.x;
    size_t o3 = (size_t)r*H3c;
    for (int j = threadIdx.x; j < Hc; j += blockDim.x){
        float ir = gi[o3+j],      hr = gh[o3+j];
        float iz = gi[o3+Hc+j],   hz = gh[o3+Hc+j];
        float in_= gi[o3+2*Hc+j], hn = gh[o3+2*Hc+j];
        float rg = sigmoid_f(ir+hr);
        float zg = sigmoid_f(iz+hz);
        float ng = tanhf(in_ + rg*hn);
        size_t oh = (size_t)r*Hc + j;
        hm1[oh] = (1.0f-zg)*ng + zg*h[oh];
    }
}

// ---------------------------------------------------------------------------
// Attention scores with mask + softmax -> bf16 score matrix
// ---------------------------------------------------------------------------
__global__ __launch_bounds__(256)
void attn_score_kernel(const float* __restrict__ q, const float* __restrict__ k,
                       const int* __restrict__ divided, int t, ushort_t* __restrict__ scoreb)
{
    int i = blockIdx.x, b = blockIdx.y;
    int tid = threadIdx.x;
    __shared__ float qs[ATc];
    __shared__ float red[8];
    if (tid < ATc) qs[tid] = q[((size_t)b*Nc+i)*ATc + tid];
    __syncthreads();

    float gvals[4];
    float lmax = -INFINITY, lhas = 0.0f;
    #pragma unroll
    for (int jj=0;jj<4;jj++){
        int j = jj*256 + tid;
        const float* kr = k + ((size_t)b*Nc+j)*ATc;
        float d = 0.0f;
        #pragma unroll
        for (int a=0;a<ATc;a++) d += qs[a]*kr[a];
        d *= INV_SQRT_AT_F;
        const int* dv = divided + (((size_t)b*Tc+t)*Nc + j)*3;
        bool m23 = (dv[1] > 0) || (dv[2] > 0);
        lhas = fmaxf(lhas, m23 ? 1.0f : 0.0f);
        d = m23 ? d : -INFINITY;
        gvals[jj] = d;
        lmax = fmaxf(lmax, d);
    }
    #pragma unroll
    for (int o=1;o<64;o<<=1){
        lmax = fmaxf(lmax, __shfl_xor(lmax, o, 64));
        lhas = fmaxf(lhas, __shfl_xor(lhas, o, 64));
    }
    int wid = tid >> 6;
    if ((tid & 63) == 0){ red[wid] = lmax; red[4+wid] = lhas; }
    __syncthreads();
    float gmax = fmaxf(fmaxf(red[0],red[1]), fmaxf(red[2],red[3]));
    bool  has  = fmaxf(fmaxf(red[4],red[5]), fmaxf(red[6],red[7])) > 0.5f;

    float evals[4];
    float lsum = 0.0f;
    #pragma unroll
    for (int jj=0;jj<4;jj++){
        float e_;
        if (has) e_ = (gvals[jj] == -INFINITY) ? 0.0f : expf(gvals[jj]-gmax);
        else     e_ = 1.0f;
        evals[jj] = e_; lsum += e_;
    }
    #pragma unroll
    for (int o=1;o<64;o<<=1) lsum += __shfl_xor(lsum, o, 64);
    __syncthreads();
    if ((tid & 63) == 0) red[wid] = lsum;
    __syncthreads();
    float invs = 1.0f/(red[0]+red[1]+red[2]+red[3]);
    #pragma unroll
    for (int jj=0;jj<4;jj++){
        int j = jj*256 + tid;
        scoreb[((size_t)b*Nc+i)*Nc + j] = f2bf(evals[jj]*invs);
    }
}

__global__ void h_update_kernel(const int* __restrict__ divided, int t,
                                const float* __restrict__ hm1, const float* __restrict__ hm23,
                                float* __restrict__ h)
{
    int r = blockIdx.x; int b = r/Nc, n = r%Nc;
    const int* dv = divided + (((size_t)b*Tc+t)*Nc+n)*3;
    bool m1  = dv[0] > 0;
    bool m23 = (dv[1] > 0) || (dv[2] > 0);
    bool use23 = (t > 0) && m23;
    for (int j = threadIdx.x; j < Hc; j += blockDim.x){
        size_t o = (size_t)r*Hc+j;
        float v_ = 0.0f;
        if (m1)    v_ = hm1[o];
        if (use23) v_ = hm23[o];
        h[o] = v_;
    }
}

// ---------------------------------------------------------------------------
// out_last two-phase reduction (t = T-1). -inf sentinel = "mask empty".
// ---------------------------------------------------------------------------
__global__ __launch_bounds__(256)
void outlast_partial_kernel(const int* __restrict__ divided,
                            const float* __restrict__ hm1, const float* __restrict__ hm23,
                            float* __restrict__ part1, float* __restrict__ part23)
{
    int nc = blockIdx.x, b = blockIdx.y;
    int jl = threadIdx.x & 63, nl = threadIdx.x >> 6;
    __shared__ float r1[4][64], r23[4][64];
    for (int jseg=0;jseg<5;jseg++){
        int j = jseg*64 + jl;
        float m1v = -INFINITY, m23v = -INFINITY;
        if (j < Hc){
            for (int n = nc*128+nl; n < nc*128+128; n += 4){
                const int* dv = divided + (((size_t)b*Tc + (Tc-1))*Nc + n)*3;
                bool m1  = dv[0] > 0;
                bool m23 = (dv[1] > 0) || (dv[2] > 0);
                size_t o = ((size_t)b*Nc+n)*Hc + j;
                if (m1)  m1v  = fmaxf(m1v,  hm1[o]);
                if (m23) m23v = fmaxf(m23v, hm23[o]);
            }
        }
        r1[nl][jl] = m1v; r23[nl][jl] = m23v;
        __syncthreads();
        if (nl == 0){
            float a = fmaxf(fmaxf(r1[0][jl],r1[1][jl]), fmaxf(r1[2][jl],r1[3][jl]));
            float c = fmaxf(fmaxf(r23[0][jl],r23[1][jl]), fmaxf(r23[2][jl],r23[3][jl]));
            part1 [((size_t)b*8+nc)*320 + jseg*64+jl] = a;
            part23[((size_t)b*8+nc)*320 + jseg*64+jl] = c;
        }
        __syncthreads();
    }
}

__global__ void outlast_combine_kernel(const float* __restrict__ part1, const float* __restrict__ part23,
                                       float* __restrict__ outlast)
{
    int b = blockIdx.x; int j = threadIdx.x;
    if (j >= Hc) return;
    float a = -INFINITY, c = -INFINITY;
    for (int nc=0;nc<8;nc++){
        a = fmaxf(a, part1 [((size_t)b*8+nc)*320 + j]);
        c = fmaxf(c, part23[((size_t)b*8+nc)*320 + j]);
    }
    outlast[(size_t)b*Hc + j] = (a==-INFINITY ? 0.0f : a) + (c==-INFINITY ? 0.0f : c);
}

// ---------------------------------------------------------------------------
// Gather event embeddings -> bf16 padded rows [l*BE+be][KPE]
// ---------------------------------------------------------------------------
__global__ void gather_emb_kernel(const int* __restrict__ events, const float* __restrict__ Eemb,
                                  ushort_t* __restrict__ Xg)
{
    int blk = blockIdx.x;                 // l*BE + be
    int l = blk / BEc, be = blk % BEc;
    int b = be / Ec, e = be % Ec;
    int ev = events[(((size_t)b*Tc + (Tc-1))*Ec + e)*Lc + l];
    const float* src = Eemb + (size_t)ev*EDc;
    ushort_t* dst = Xg + (size_t)blk*KPE;
    for (int d = threadIdx.x; d < KPE; d += blockDim.x)
        dst[d] = (d < EDc) ? f2bf(src[d]) : (ushort_t)0;
}

// ---------------------------------------------------------------------------
// LSTM step: block owns 2 hidden cols (x4 gates) for all 128 cells.
// Reads hin, writes hout (ping-pong); cev in-place (disjoint per thread).
// ---------------------------------------------------------------------------
__global__ __launch_bounds__(256)
void lstm_step2_kernel(const float* __restrict__ gatesx,  // offset to step l: (BE,4H)
                       const float* __restrict__ Whh,     // (H,4H)
                       const float* __restrict__ hin, float* __restrict__ hout,
                       float* __restrict__ cev)
{
    int j0 = blockIdx.x*2;
    __shared__ float Wsl[Hc][8];   // [hh][jj*4 + gate]
    int tid = threadIdx.x;
    for (int e = tid; e < Hc*8; e += 256){
        int hh = e>>3, idx = e&7;
        int jj = idx>>2, g = idx&3;
        Wsl[hh][idx] = Whh[(size_t)hh*H4c + g*Hc + j0 + jj];
    }
    __syncthreads();
    int cell = tid>>1, jj = tid&1, j = j0+jj;
    const float* hrow = hin + (size_t)cell*Hc;
    float a0=0.f,a1=0.f,a2=0.f,a3=0.f;
    #pragma unroll 2
    for (int hh=0; hh<Hc; hh++){
        float hv = hrow[hh];
        f4v wv = *(const f4v*)&Wsl[hh][jj*4];
        a0 += hv*wv.x; a1 += hv*wv.y; a2 += hv*wv.z; a3 += hv*wv.w;
    }
    const float* gx = gatesx + (size_t)cell*H4c + j;
    float ig = sigmoid_f(a0 + gx[0]);
    float fg = sigmoid_f(a1 + gx[Hc]);
    float gg = tanhf    (a2 + gx[2*Hc]);
    float og = sigmoid_f(a3 + gx[3*Hc]);
    size_t o = (size_t)cell*Hc + j;
    float cn = fg*cev[o] + ig*gg;
    cev[o] = cn;
    hout[o] = og*tanhf(cn);
}

__global__ void build_stacked_kernel(const float* __restrict__ out_last, const float* __restrict__ hev,
                                     float* __restrict__ stacked)
{
    int b = blockIdx.x, s = blockIdx.y;
    const float* src = (s==0) ? (out_last + (size_t)b*Hc)
                              : (hev + ((size_t)b*Ec + (s-1))*Hc);
    float* dst = stacked + ((size_t)b*(Ec+1) + s)*Hc;
    for (int j = threadIdx.x; j < Hc; j += blockDim.x) dst[j] = src[j];
}

__global__ void wdctx_kernel(const float* __restrict__ Wd, const float* __restrict__ bd,
                             const float* __restrict__ ctx, float* __restrict__ wdc)
{
    int j = blockIdx.x*blockDim.x + threadIdx.x;
    if (j < Hc){
        float s = 0.0f;
        for (int d=0;d<DAc;d++) s += Wd[(size_t)j*DAc+d]*ctx[d];
        wdc[j] = s;
    } else if (j == Hc){
        float s = 0.0f;
        for (int d=0;d<DAc;d++) s += bd[d]*ctx[d];
        wdc[Hc] = s;
    }
}

__global__ void dp_attn_kernel(const float* __restrict__ stacked, const float* __restrict__ wdc,
                               float* __restrict__ o1)
{
    int b = blockIdx.x;
    int tid = threadIdx.x;
    __shared__ float sc[Ec+1];
    if (tid < Ec+1){
        float s = wdc[Hc];
        const float* x = stacked + ((size_t)b*(Ec+1)+tid)*Hc;
        for (int j=0;j<Hc;j++) s += x[j]*wdc[j];
        sc[tid] = s;
    }
    __syncthreads();
    if (tid == 0){
        float m = -INFINITY;
        for (int s=0;s<Ec+1;s++) m = fmaxf(m, sc[s]);
        float sum = 0.0f;
        for (int s=0;s<Ec+1;s++){ sc[s] = expf(sc[s]-m); sum += sc[s]; }
        float inv = 1.0f/sum;
        for (int s=0;s<Ec+1;s++) sc[s] *= inv;
    }
    __syncthreads();
    for (int j = tid; j < Hc; j += blockDim.x){
        float acc = 0.0f;
        for (int s=0;s<Ec+1;s++) acc += sc[s]*stacked[((size_t)b*(Ec+1)+s)*Hc + j];
        o1[(size_t)b*Hc + j] = acc;
    }
}

// ---------------------------------------------------------------------------
extern "C" void kernel_launch(void* const* d_in, const int* in_sizes, int n_in,
                              void* d_out, int out_size, void* d_ws, size_t ws_size,
                              hipStream_t stream)
{
    const int*   code_x    = (const int*)d_in[0];
    const int*   divided   = (const int*)d_in[1];
    const int*   neighbors = (const int*)d_in[2];
    const int*   events    = (const int*)d_in[4];
    const float* c_emb     = (const float*)d_in[5];
    const float* n_emb     = (const float*)d_in[6];
    const float* u_emb     = (const float*)d_in[7];
    const float* adj       = (const float*)d_in[8];
    const float* Wg        = (const float*)d_in[9];
    const float* bg        = (const float*)d_in[10];
    const float* gru_Wih   = (const float*)d_in[11];
    const float* gru_Whh   = (const float*)d_in[12];
    const float* gru_bih   = (const float*)d_in[13];
    const float* gru_bhh   = (const float*)d_in[14];
    const float* Wq        = (const float*)d_in[15];
    const float* bq        = (const float*)d_in[16];
    const float* Wk        = (const float*)d_in[17];
    const float* bk        = (const float*)d_in[18];
    const float* Wv        = (const float*)d_in[19];
    const float* bv        = (const float*)d_in[20];
    const float* Wd        = (const float*)d_in[21];
    const float* bd        = (const float*)d_in[22];
    const float* ctx       = (const float*)d_in[23];
    const float* Eemb      = (const float*)d_in[24];
    const float* lstm_Wih  = (const float*)d_in[25];
    const float* lstm_Whh  = (const float*)d_in[26];
    const float* lstm_b    = (const float*)d_in[27];
    const float* Wc        = (const float*)d_in[28];
    const float* bc        = (const float*)d_in[29];
    float* out = (float*)d_out;

    float* ws = (float*)d_ws;
    size_t off = 0;
    auto alloc = [&](size_t n){ n = (n+7)&~(size_t)7; float* p = ws + off; off += n; return p; };
    auto allocU = [&](size_t n){ return (ushort_t*)alloc((n+1)/2); };

    float* h_buf   = alloc((size_t)Bc*Nc*Hc);
    float* hm1     = alloc((size_t)Bc*Nc*Hc);
    float* hm23    = alloc((size_t)Bc*Nc*Hc);
    float* noA     = alloc((size_t)Bc*Nc*GSc);
    float* noB     = alloc((size_t)Bc*Nc*GSc);
    float* Sbuf    = alloc((size_t)Nc*Bc*CSc);
    float* X2      = alloc((size_t)2*Bc*Nc*CSc);
    float* cobuf   = alloc((size_t)Bc*Nc*GSc);
    float* qin     = alloc((size_t)Bc*Nc*GSc);
    float* qb      = alloc((size_t)Bc*Nc*ATc);
    float* kb      = alloc((size_t)Bc*Nc*ATc);
    float* outlast = alloc((size_t)Bc*Hc);
    float* stacked = alloc((size_t)Bc*(Ec+1)*Hc);
    float* wdc     = alloc((size_t)(Hc+1));
    float* o1      = alloc((size_t)Bc*Hc);
    float* hevA    = alloc((size_t)BEc*Hc);
    float* hevB    = alloc((size_t)BEc*Hc);
    float* cev     = alloc((size_t)BEc*Hc);
    float* part1   = alloc((size_t)Bc*8*320);
    float* part23  = alloc((size_t)Bc*8*320);

    ushort_t* adjb   = allocU((size_t)Nc*Nc);
    ushort_t* YTb    = allocU((size_t)Bc*CSc*Nc);
    ushort_t* WhhT   = allocU((size_t)H3c*KPH);
    ushort_t* WihT   = allocU((size_t)H3c*GSc);
    ushort_t* WTl    = allocU((size_t)H4c*KPE);
    ushort_t* vT     = allocU((size_t)Hc*Bc*Nc);       // [270][4096]
    ushort_t* cob    = allocU((size_t)Bc*Nc*GSc);
    ushort_t* hb     = allocU((size_t)Bc*Nc*KPH);
    float* gi        = alloc((size_t)Bc*Nc*H3c);
    float* gh        = alloc((size_t)Bc*Nc*H3c);       // contiguous with gi
    float* scoref    = alloc((size_t)Bc*Nc*Nc/2);      // scoreb bf16 region (2.1M floats)
    ushort_t* scoreb = (ushort_t*)scoref;
    // Aliases (used only after the visit loop):
    float* gatesx = gi;                                 // needs 4096*1080 <= gi+gh
    ushort_t* Xgb = scoreb;                             // needs 4096*416 ushorts <= scoreb region
    (void)ws_size; (void)in_sizes; (void)n_in; (void)out_size; (void)adj;

    hipMemsetAsync(h_buf, 0, (size_t)Bc*Nc*Hc*sizeof(float), stream);
    hipMemsetAsync(noA,   0, (size_t)Bc*Nc*GSc*sizeof(float), stream);
    hipMemsetAsync(noB,   0, (size_t)Bc*Nc*GSc*sizeof(float), stream);
    hipMemsetAsync(hevA,  0, (size_t)BEc*Hc*sizeof(float), stream);
    hipMemsetAsync(cev,   0, (size_t)BEc*Hc*sizeof(float), stream);

    // ---- per-launch weight conversions ----
    {
        long long tot;
        tot = (long long)Nc*Nc;
        convert_pad_kernel<<<(int)((tot+255)/256),256,0,stream>>>(adj, adjb, Nc, Nc, tot);
        tot = (long long)H3c*KPH;
        transpose_conv_kernel<<<(int)((tot+255)/256),256,0,stream>>>(gru_Whh, WhhT, H3c, Hc, KPH, H3c);
        tot = (long long)H3c*GSc;
        transpose_conv_kernel<<<(int)((tot+255)/256),256,0,stream>>>(gru_Wih, WihT, H3c, GSc, GSc, H3c);
        tot = (long long)H4c*KPE;
        transpose_conv_kernel<<<(int)((tot+255)/256),256,0,stream>>>(lstm_Wih, WTl, H4c, EDc, KPE, H4c);
    }

    float* no_prev = noB;
    float* no_cur  = noA;
    for (int t=0; t<Tc; t++){
        build_YT_kernel<<<dim3(Bc*CSc), dim3(256), 0, stream>>>(code_x, neighbors, c_emb, n_emb, t, YTb);
        launch_mfma(stream, adjb, YTb, nullptr, Sbuf, Nc, Bc*CSc, Nc, Nc, Nc, Bc*CSc, 0, 1, 0,0,0);
        build_conoin_kernel<<<dim3(Bc*Nc), dim3(64), 0, stream>>>(code_x, neighbors, c_emb, n_emb, Sbuf, t, X2);
        launch_gemm(stream, X2,                   Wg, bg, cobuf,  Bc*Nc, GSc, CSc, 1, 0, 0);
        launch_gemm(stream, X2+(size_t)Bc*Nc*CSc, Wg, bg, no_cur, Bc*Nc, GSc, CSc, 1, 0, 0);
        build_qin_kernel<<<dim3(Bc*Nc), dim3(64), 0, stream>>>(divided, u_emb, no_prev, t, qin);
        launch_gemm(stream, qin,   Wq, bq, qb, Bc*Nc, ATc, GSc, 0, 0, 0);
        launch_gemm(stream, cobuf, Wk, bk, kb, Bc*Nc, ATc, GSc, 0, 0, 0);
        launch_gemm(stream, cobuf, Wv, bv, (float*)vT, Bc*Nc, Hc, GSc, 0, 1, (long long)Bc*Nc);
        {
            long long tot = (long long)Bc*Nc*GSc;
            convert_pad_kernel<<<(int)((tot+255)/256),256,0,stream>>>(cobuf, cob, GSc, GSc, tot);
            tot = (long long)Bc*Nc*KPH;
            convert_pad_kernel<<<(int)((tot+255)/256),256,0,stream>>>(h_buf, hb, Hc, KPH, tot);
        }
        launch_mfma(stream, cob, WihT, gru_bih, gi, Bc*Nc, H3c, GSc, GSc, GSc, H3c, 0, 1, 0,0,0);
        launch_mfma(stream, hb,  WhhT, gru_bhh, gh, Bc*Nc, H3c, KPH, KPH, KPH, H3c, 0, 1, 0,0,0);
        gru_combine_kernel<<<dim3(Bc*Nc), dim3(256), 0, stream>>>(gi, gh, h_buf, hm1);
        attn_score_kernel<<<dim3(Nc, Bc), dim3(256), 0, stream>>>(qb, kb, divided, t, scoreb);
        launch_mfma(stream, scoreb, vT, nullptr, hm23, Nc, Hc, Nc, Nc, Bc*Nc, Hc,
                    2, Bc, (long long)Nc*Nc, (long long)Nc, (long long)Nc*Hc);
        h_update_kernel<<<dim3(Bc*Nc), dim3(256), 0, stream>>>(divided, t, hm1, hm23, h_buf);
        if (t == Tc-1){
            outlast_partial_kernel<<<dim3(8, Bc), dim3(256), 0, stream>>>(divided, hm1, hm23, part1, part23);
            outlast_combine_kernel<<<dim3(Bc), dim3(320), 0, stream>>>(part1, part23, outlast);
        }
        float* tmp = no_prev; no_prev = no_cur; no_cur = tmp;
    }

    // ---- LSTM over last-visit events ----
    gather_emb_kernel<<<dim3(BEc*Lc), dim3(256), 0, stream>>>(events, Eemb, Xgb);
    launch_mfma(stream, Xgb, WTl, lstm_b, gatesx, BEc*Lc, H4c, KPE, KPE, KPE, H4c, 0, 1, 0,0,0);
    {
        float* hin = hevA; float* hout = hevB;
        for (int l=0; l<Lc; l++){
            lstm_step2_kernel<<<dim3(Hc/2), dim3(256), 0, stream>>>(gatesx + (size_t)l*BEc*H4c,
                                                                    lstm_Whh, hin, hout, cev);
            float* tmp = hin; hin = hout; hout = tmp;
        }
        // final h in hin
        build_stacked_kernel<<<dim3(Bc, Ec+1), dim3(64), 0, stream>>>(outlast, hin, stacked);
    }
    wdctx_kernel<<<dim3(2), dim3(256), 0, stream>>>(Wd, bd, ctx, wdc);
    dp_attn_kernel<<<dim3(Bc), dim3(256), 0, stream>>>(stacked, wdc, o1);
    launch_gemm(stream, o1, Wc, bc, out, Bc, OUTc, Hc, 3, 0, 0);
}

// Round 3
// 1915.062 us; speedup vs baseline: 2.6227x; 1.6425x over previous
//
#include <hip/hip_runtime.h>
#include <hip/hip_bf16.h>
#include <math.h>

// Problem constants
#define Bc   4
#define Tc   6
#define Nc   1024
#define CSc  48
#define GSc  32
#define Hc   270
#define ATc  32
#define DAc  64
#define Ec   32
#define Lc   32
#define EDc  400
#define OUTc 4000
#define H3c  810    // 3*H
#define H4c  1080   // 4*H
#define BEc  128    // B*E
#define KPH  288    // H padded to 32
#define KPE  416    // ED padded to 32
#define KPG  64     // CS padded to 32
#define NKVI 1112   // 32 + 270 + 810
#define INV_SQRT_AT_F 0.17677669529663687f

typedef unsigned short ushort_t;
using s8v = __attribute__((ext_vector_type(8))) short;
using f4v = __attribute__((ext_vector_type(4))) float;

__device__ __forceinline__ float sigmoid_f(float x){ return 1.0f/(1.0f+expf(-x)); }
__device__ __forceinline__ ushort_t f2bf(float x){
    __hip_bfloat16 b = __float2bfloat16(x);
    return *reinterpret_cast<ushort_t*>(&b);
}
__device__ __forceinline__ float b2f(ushort_t u){
    return __uint_as_float(((unsigned int)u)<<16);
}

// ---------------------------------------------------------------------------
// bf16 MFMA GEMM, 128x128 tile, 4 waves. Epilogues:
//  EPIL 0: f32 store P0[(+z*sC if SPLITK)][grow*ldc+col] (+bias if nonnull)
//  EPIL 1: leaky-relu, dual bf16: row<4096 -> P0, else P1 (ldc=32)
//  EPIL 2: bf16 store P0 (+bias)
//  EPIL 3: kvgi mixed: col<32 kb bf16; col<302 vT bf16 transposed; else gi f32. bias all.
//  EPIL 4: pv: x=tanh(acc); h-update fused: P0=hb bf16 [grow*288], P1=hm23 f32,
//          PF=hm1 (const), DV=divided, tpar=t
// SPLITK>0: blockIdx.z = K-slice (A/BT not offset, P0 += z*sC); else z = batch.
// ---------------------------------------------------------------------------
template<int EPIL, int SPLITK>
__global__ __launch_bounds__(256)
void mfma_k(const ushort_t* __restrict__ A, const ushort_t* __restrict__ BT,
            const float* __restrict__ bias,
            void* __restrict__ P0, void* __restrict__ P1, void* __restrict__ P2,
            const float* __restrict__ PF, const int* __restrict__ DV,
            int M, int N, int Kp, int lda, int ldb, int ldc,
            long long sA, long long sB, long long sC, int tpar)
{
    __shared__ ushort_t As[128*40];
    __shared__ ushort_t Bs[128*40];
    const int z = blockIdx.z;
    int kbeg = 0, kend = Kp;
    if (SPLITK > 0){
        int ks = Kp / SPLITK;
        kbeg = z*ks; kend = kbeg + ks;
    } else {
        A  += (size_t)z * (size_t)sA;
        BT += (size_t)z * (size_t)sB;
    }
    const int m0 = blockIdx.y*128, n0 = blockIdx.x*128;
    const int tid = threadIdx.x;
    const int w = tid>>6, l = tid&63;
    const int wm = (w>>1)*64, wn = (w&1)*64;
    const int lr = l&15, lk = (l>>4)*8, lq = l>>4;
    const int srow = tid>>2, kseg = tid&3;

    f4v acc[4][4];
    #pragma unroll
    for (int mi=0;mi<4;mi++)
      #pragma unroll
      for (int ni=0;ni<4;ni++)
        acc[mi][ni] = (f4v){0.0f,0.0f,0.0f,0.0f};

    for (int k0=kbeg;k0<kend;k0+=32){
        #pragma unroll
        for (int i=0;i<2;i++){
            int row = srow + i*64;
            int ga = m0+row;
            uint4 va = make_uint4(0u,0u,0u,0u);
            if (ga < M) va = *(const uint4*)(A + (size_t)ga*lda + k0 + kseg*8);
            *(uint4*)&As[row*40 + kseg*8] = va;
            int gb = n0+row;
            uint4 vb = make_uint4(0u,0u,0u,0u);
            if (gb < N) vb = *(const uint4*)(BT + (size_t)gb*ldb + k0 + kseg*8);
            *(uint4*)&Bs[row*40 + kseg*8] = vb;
        }
        __syncthreads();
        s8v af[4], bfr[4];
        #pragma unroll
        for (int mi=0;mi<4;mi++) af[mi]  = *(const s8v*)&As[(wm+mi*16+lr)*40 + lk];
        #pragma unroll
        for (int ni=0;ni<4;ni++) bfr[ni] = *(const s8v*)&Bs[(wn+ni*16+lr)*40 + lk];
        #pragma unroll
        for (int mi=0;mi<4;mi++)
          #pragma unroll
          for (int ni=0;ni<4;ni++)
            acc[mi][ni] = __builtin_amdgcn_mfma_f32_16x16x32_bf16(af[mi], bfr[ni], acc[mi][ni], 0,0,0);
        __syncthreads();
    }

    #pragma unroll
    for (int mi=0;mi<4;mi++){
      #pragma unroll
      for (int ni=0;ni<4;ni++){
        int col = n0+wn+ni*16+lr;
        if (col >= N) continue;
        float bv_ = (EPIL!=4 && bias) ? bias[col] : 0.0f;
        #pragma unroll
        for (int r=0;r<4;r++){
          int row = m0+wm+mi*16+lq*4+r;
          if (row >= M) continue;
          float x = acc[mi][ni][r] + bv_;
          if (EPIL == 0){
              float* C = (float*)P0;
              size_t base = (SPLITK>0) ? (size_t)z*(size_t)sC : 0;
              size_t grow = (SPLITK>0) ? (size_t)row : (size_t)z*M + row;
              C[base + grow*ldc + col] = x;
          } else if (EPIL == 1){
              x = (x>0.0f) ? x : 0.01f*x;
              if (row < 4096) ((ushort_t*)P0)[(size_t)row*32 + col] = f2bf(x);
              else            ((ushort_t*)P1)[(size_t)(row-4096)*32 + col] = f2bf(x);
          } else if (EPIL == 2){
              ((ushort_t*)P0)[(size_t)row*ldc + col] = f2bf(x);
          } else if (EPIL == 3){
              if (col < 32)        ((ushort_t*)P0)[(size_t)row*32 + col] = f2bf(x);
              else if (col < 302)  ((ushort_t*)P1)[(size_t)(col-32)*4096 + row] = f2bf(x);
              else                 ((float*)P2)[(size_t)row*H3c + (col-302)] = x;
          } else if (EPIL == 4){
              float xt = tanhf(x);
              size_t grow = (size_t)z*M + row;
              const int* dv = DV + (((size_t)z*Tc + tpar)*Nc + row)*3;
              bool m1  = dv[0] > 0;
              bool m23 = (dv[1] > 0) || (dv[2] > 0);
              bool use23 = (tpar > 0) && m23;
              float hv = use23 ? xt : (m1 ? PF[grow*Hc + col] : 0.0f);
              ((ushort_t*)P0)[grow*KPH + col] = f2bf(hv);
              ((float*)P1)[grow*Hc + col] = xt;
          }
        }
      }
    }
}

// ---------------------------------------------------------------------------
// f32 tiled GEMM (final layer only). ACT: 3 sigmoid.
// ---------------------------------------------------------------------------
template<int ACT>
__global__ __launch_bounds__(256)
void gemm_kernel(const float* __restrict__ A, const float* __restrict__ Bm,
                 const float* __restrict__ bias, float* __restrict__ C,
                 int M, int Nn, int K)
{
    constexpr int BM=64, BN=64, BK=16;
    __shared__ float As[BK][BM+4];
    __shared__ float Bs[BK][BN+4];
    const int row0 = blockIdx.y*BM, col0 = blockIdx.x*BN;
    const int tid = threadIdx.x;
    const int tr = (tid>>4)<<2;
    const int tc = (tid&15)<<2;
    const int ar = tid>>2;
    const int ac = (tid&3)<<2;
    const int br = tid>>4;
    const int bc = (tid&15)<<2;
    float acc[4][4] = {};
    for (int k0=0;k0<K;k0+=BK){
        #pragma unroll
        for (int i=0;i<4;i++){
            int gr=row0+ar, gc=k0+ac+i;
            As[ac+i][ar] = (gr<M && gc<K) ? A[(size_t)gr*K+gc] : 0.0f;
        }
        #pragma unroll
        for (int i=0;i<4;i++){
            int gr=k0+br, gc=col0+bc+i;
            Bs[br][bc+i] = (gr<K && gc<Nn) ? Bm[(size_t)gr*Nn+gc] : 0.0f;
        }
        __syncthreads();
        #pragma unroll
        for (int kk=0;kk<BK;kk++){
            float a0=As[kk][tr+0], a1=As[kk][tr+1], a2=As[kk][tr+2], a3=As[kk][tr+3];
            float b0=Bs[kk][tc+0], b1=Bs[kk][tc+1], b2=Bs[kk][tc+2], b3=Bs[kk][tc+3];
            acc[0][0]+=a0*b0; acc[0][1]+=a0*b1; acc[0][2]+=a0*b2; acc[0][3]+=a0*b3;
            acc[1][0]+=a1*b0; acc[1][1]+=a1*b1; acc[1][2]+=a1*b2; acc[1][3]+=a1*b3;
            acc[2][0]+=a2*b0; acc[2][1]+=a2*b1; acc[2][2]+=a2*b2; acc[2][3]+=a2*b3;
            acc[3][0]+=a3*b0; acc[3][1]+=a3*b1; acc[3][2]+=a3*b2; acc[3][3]+=a3*b3;
        }
        __syncthreads();
    }
    #pragma unroll
    for (int i=0;i<4;i++){
        int r=row0+tr+i; if (r>=M) continue;
        #pragma unroll
        for (int j=0;j<4;j++){
            int c=col0+tc+j; if (c>=Nn) continue;
            float x = acc[i][j];
            if (bias) x += bias[c];
            if (ACT==3) x = 1.0f/(1.0f+expf(-x));
            C[(size_t)r*Nn+c] = x;
        }
    }
}

// ---------------------------------------------------------------------------
// Conversions / prep
// ---------------------------------------------------------------------------
__global__ void convert_pad_kernel(const float* __restrict__ in, ushort_t* __restrict__ out,
                                   int K, int Kp, long long total)
{
    long long idx = (long long)blockIdx.x*blockDim.x + threadIdx.x;
    if (idx >= total) return;
    int row = (int)(idx / Kp), col = (int)(idx % Kp);
    out[idx] = (col < K) ? f2bf(in[(size_t)row*K + col]) : (ushort_t)0;
}

// out[n*Kp + k] = (k<K) ? bf16(in[k*ldin + n]) : 0
__global__ void transpose_conv_kernel(const float* __restrict__ in, ushort_t* __restrict__ out,
                                      int Nrows, int K, int Kp, int ldin)
{
    long long idx = (long long)blockIdx.x*blockDim.x + threadIdx.x;
    if (idx >= (long long)Nrows*Kp) return;
    int n = (int)(idx / Kp), k = (int)(idx % Kp);
    out[idx] = (k < K) ? f2bf(in[(size_t)k*ldin + n]) : (ushort_t)0;
}

// WkviT[n][k]: n<32 Wk^T, n<302 Wv^T, else Wih^T (all K=32)
__global__ void build_wkvit_kernel(const float* __restrict__ Wk, const float* __restrict__ Wv,
                                   const float* __restrict__ Wih, ushort_t* __restrict__ out)
{
    int idx = blockIdx.x*blockDim.x + threadIdx.x;
    if (idx >= NKVI*32) return;
    int n = idx >> 5, k = idx & 31;
    float v_;
    if (n < 32)       v_ = Wk[(size_t)k*ATc + n];
    else if (n < 302) v_ = Wv[(size_t)k*Hc + (n-32)];
    else              v_ = Wih[(size_t)k*H3c + (n-302)];
    out[idx] = f2bf(v_);
}

__global__ void build_bkvi_kernel(const float* __restrict__ bk, const float* __restrict__ bv,
                                  const float* __restrict__ bih, float* __restrict__ out)
{
    int idx = blockIdx.x*blockDim.x + threadIdx.x;
    if (idx >= NKVI) return;
    if (idx < 32)       out[idx] = bk[idx];
    else if (idx < 302) out[idx] = bv[idx-32];
    else                out[idx] = bih[idx-302];
}

// ---------------------------------------------------------------------------
// YT[bc][n] = bf16(cm*c_emb[n,c] + nm*n_emb[n,c])
// ---------------------------------------------------------------------------
__global__ void build_YT_kernel(const int* __restrict__ code_x, const int* __restrict__ neighbors,
                                const float* __restrict__ c_emb, const float* __restrict__ n_emb,
                                int t, ushort_t* __restrict__ YT)
{
    int bc = blockIdx.x;
    int b = bc / CSc, c = bc % CSc;
    for (int n = threadIdx.x; n < Nc; n += 256){
        float cm = (float)code_x[((size_t)b*Tc+t)*Nc + n];
        float nm = (float)neighbors[((size_t)b*Tc+t)*Nc + n];
        YT[(size_t)bc*Nc + n] = f2bf(cm*c_emb[(size_t)n*CSc+c] + nm*n_emb[(size_t)n*CSc+c]);
    }
}

// ---------------------------------------------------------------------------
// conoin: sum 8 split-K partials of S, build X2b bf16 [8192][64] (pad 48..63 = 0)
// ---------------------------------------------------------------------------
__global__ __launch_bounds__(256)
void build_conoin_kernel(const int* __restrict__ code_x, const int* __restrict__ neighbors,
                         const float* __restrict__ c_emb, const float* __restrict__ n_emb,
                         const float* __restrict__ Spart, int t, ushort_t* __restrict__ X2b)
{
    int idx = blockIdx.x*256 + threadIdx.x;   // r(0..4095) x c(0..63)
    int r = idx >> 6, c = idx & 63;
    int b = r >> 10, n = r & 1023;
    float xa = 0.0f, xb = 0.0f;
    if (c < CSc){
        float s = 0.0f;
        #pragma unroll
        for (int z=0;z<8;z++) s += Spart[(size_t)z*(Nc*Bc*CSc) + (size_t)n*(Bc*CSc) + b*CSc + c];
        float cm = (float)code_x[((size_t)b*Tc+t)*Nc + n];
        float nm = (float)neighbors[((size_t)b*Tc+t)*Nc + n];
        xa = cm*(c_emb[(size_t)n*CSc+c] + s);
        xb = nm*(n_emb[(size_t)n*CSc+c] + s);
    }
    X2b[(size_t)r*KPG + c] = f2bf(xa);
    X2b[((size_t)r+4096)*KPG + c] = f2bf(xb);
}

// qinb = m3 ? u_embb : no_prev   (bf16)
__global__ void build_qin_kernel(const int* __restrict__ divided, const ushort_t* __restrict__ u_embb,
                                 const ushort_t* __restrict__ no_prev, int t, ushort_t* __restrict__ qinb)
{
    int idx = blockIdx.x*256 + threadIdx.x;   // r x c(0..31)
    int r = idx >> 5, c = idx & 31;
    int b = r >> 10, n = r & 1023;
    bool m3 = divided[(((size_t)b*Tc+t)*Nc+n)*3 + 2] > 0;
    qinb[(size_t)r*GSc+c] = m3 ? u_embb[(size_t)n*GSc+c] : no_prev[(size_t)r*GSc+c];
}

// GRU combine: hm1 = (1-z)*n + z*h   (h read from bf16 hb)
__global__ void gru_combine_kernel(const float* __restrict__ gi, const float* __restrict__ gh,
                                   const ushort_t* __restrict__ hb, float* __restrict__ hm1)
{
    int r = blockIdx.x;
    size_t o3 = (size_t)r*H3c;
    for (int j = threadIdx.x; j < Hc; j += blockDim.x){
        float ir = gi[o3+j],      hr = gh[o3+j];
        float iz = gi[o3+Hc+j],   hz = gh[o3+Hc+j];
        float in_= gi[o3+2*Hc+j], hn = gh[o3+2*Hc+j];
        float rg = sigmoid_f(ir+hr);
        float zg = sigmoid_f(iz+hz);
        float ng = tanhf(in_ + rg*hn);
        hm1[(size_t)r*Hc + j] = (1.0f-zg)*ng + zg*b2f(hb[(size_t)r*KPH + j]);
    }
}

// ---------------------------------------------------------------------------
// masked softmax over precomputed g (f32) -> bf16 score
// ---------------------------------------------------------------------------
__global__ __launch_bounds__(256)
void softmax_kernel(const float* __restrict__ g, const int* __restrict__ divided,
                    int t, ushort_t* __restrict__ scoreb)
{
    int i = blockIdx.x, b = blockIdx.y;
    int tid = threadIdx.x;
    __shared__ float red[8];
    const float* gr = g + ((size_t)b*Nc + i)*Nc;

    float gvals[4];
    float lmax = -INFINITY, lhas = 0.0f;
    #pragma unroll
    for (int jj=0;jj<4;jj++){
        int j = jj*256 + tid;
        float d = gr[j] * INV_SQRT_AT_F;
        const int* dv = divided + (((size_t)b*Tc+t)*Nc + j)*3;
        bool m23 = (dv[1] > 0) || (dv[2] > 0);
        lhas = fmaxf(lhas, m23 ? 1.0f : 0.0f);
        d = m23 ? d : -INFINITY;
        gvals[jj] = d;
        lmax = fmaxf(lmax, d);
    }
    #pragma unroll
    for (int o=1;o<64;o<<=1){
        lmax = fmaxf(lmax, __shfl_xor(lmax, o, 64));
        lhas = fmaxf(lhas, __shfl_xor(lhas, o, 64));
    }
    int wid = tid >> 6;
    if ((tid & 63) == 0){ red[wid] = lmax; red[4+wid] = lhas; }
    __syncthreads();
    float gmax = fmaxf(fmaxf(red[0],red[1]), fmaxf(red[2],red[3]));
    bool  has  = fmaxf(fmaxf(red[4],red[5]), fmaxf(red[6],red[7])) > 0.5f;

    float evals[4];
    float lsum = 0.0f;
    #pragma unroll
    for (int jj=0;jj<4;jj++){
        float e_;
        if (has) e_ = (gvals[jj] == -INFINITY) ? 0.0f : expf(gvals[jj]-gmax);
        else     e_ = 1.0f;
        evals[jj] = e_; lsum += e_;
    }
    #pragma unroll
    for (int o=1;o<64;o<<=1) lsum += __shfl_xor(lsum, o, 64);
    __syncthreads();
    if ((tid & 63) == 0) red[wid] = lsum;
    __syncthreads();
    float invs = 1.0f/(red[0]+red[1]+red[2]+red[3]);
    #pragma unroll
    for (int jj=0;jj<4;jj++){
        int j = jj*256 + tid;
        scoreb[((size_t)b*Nc+i)*Nc + j] = f2bf(evals[jj]*invs);
    }
}

// ---------------------------------------------------------------------------
// out_last two-phase reduction (t = T-1)
// ---------------------------------------------------------------------------
__global__ __launch_bounds__(256)
void outlast_partial_kernel(const int* __restrict__ divided,
                            const float* __restrict__ hm1, const float* __restrict__ hm23,
                            float* __restrict__ part1, float* __restrict__ part23)
{
    int nc = blockIdx.x, b = blockIdx.y;
    int jl = threadIdx.x & 63, nl = threadIdx.x >> 6;
    __shared__ float r1[4][64], r23[4][64];
    for (int jseg=0;jseg<5;jseg++){
        int j = jseg*64 + jl;
        float m1v = -INFINITY, m23v = -INFINITY;
        if (j < Hc){
            for (int n = nc*128+nl; n < nc*128+128; n += 4){
                const int* dv = divided + (((size_t)b*Tc + (Tc-1))*Nc + n)*3;
                bool m1  = dv[0] > 0;
                bool m23 = (dv[1] > 0) || (dv[2] > 0);
                size_t o = ((size_t)b*Nc+n)*Hc + j;
                if (m1)  m1v  = fmaxf(m1v,  hm1[o]);
                if (m23) m23v = fmaxf(m23v, hm23[o]);
            }
        }
        r1[nl][jl] = m1v; r23[nl][jl] = m23v;
        __syncthreads();
        if (nl == 0){
            float a = fmaxf(fmaxf(r1[0][jl],r1[1][jl]), fmaxf(r1[2][jl],r1[3][jl]));
            float c = fmaxf(fmaxf(r23[0][jl],r23[1][jl]), fmaxf(r23[2][jl],r23[3][jl]));
            part1 [((size_t)b*8+nc)*320 + jseg*64+jl] = a;
            part23[((size_t)b*8+nc)*320 + jseg*64+jl] = c;
        }
        __syncthreads();
    }
}

__global__ void outlast_combine_kernel(const float* __restrict__ part1, const float* __restrict__ part23,
                                       float* __restrict__ outlast)
{
    int b = blockIdx.x; int j = threadIdx.x;
    if (j >= Hc) return;
    float a = -INFINITY, c = -INFINITY;
    for (int nc=0;nc<8;nc++){
        a = fmaxf(a, part1 [((size_t)b*8+nc)*320 + j]);
        c = fmaxf(c, part23[((size_t)b*8+nc)*320 + j]);
    }
    outlast[(size_t)b*Hc + j] = (a==-INFINITY ? 0.0f : a) + (c==-INFINITY ? 0.0f : c);
}

// ---------------------------------------------------------------------------
// Gather event embeddings -> bf16 padded rows [l*BE+be][KPE]
// ---------------------------------------------------------------------------
__global__ void gather_emb_kernel(const int* __restrict__ events, const float* __restrict__ Eemb,
                                  ushort_t* __restrict__ Xg)
{
    int blk = blockIdx.x;
    int l = blk / BEc, be = blk % BEc;
    int b = be / Ec, e = be % Ec;
    int ev = events[(((size_t)b*Tc + (Tc-1))*Ec + e)*Lc + l];
    const float* src = Eemb + (size_t)ev*EDc;
    ushort_t* dst = Xg + (size_t)blk*KPE;
    for (int d = threadIdx.x; d < KPE; d += blockDim.x)
        dst[d] = (d < EDc) ? f2bf(src[d]) : (ushort_t)0;
}

// ---------------------------------------------------------------------------
// Persistent LSTM: 64 blocks x 512 threads, 2 cells/block, all 32 steps.
// WhhTl bf16 [1080][272] (transposed, padded). gatesx f32 (4096,1080).
// ---------------------------------------------------------------------------
__global__ __launch_bounds__(512)
void lstm_all_kernel(const float* __restrict__ gatesx, const ushort_t* __restrict__ WhhTl,
                     float* __restrict__ h_final)
{
    __shared__ float hs[2][272];
    __shared__ float cs[2][Hc];
    __shared__ float gs[2][H4c];
    int tid = threadIdx.x;
    int cell0 = blockIdx.x*2;
    for (int i = tid; i < 2*272; i += 512) hs[i/272][i%272] = 0.0f;
    for (int i = tid; i < 2*Hc; i += 512) cs[i/Hc][i%Hc] = 0.0f;
    __syncthreads();
    for (int l=0; l<Lc; l++){
        for (int c = tid; c < H4c; c += 512){
            const ushort4* wr4 = (const ushort4*)(WhhTl + (size_t)c*272);
            float a0 = gatesx[((size_t)l*BEc + cell0)*H4c + c];
            float a1 = gatesx[((size_t)l*BEc + cell0+1)*H4c + c];
            #pragma unroll 4
            for (int q=0; q<68; q++){
                ushort4 w4 = wr4[q];
                float w0=b2f(w4.x), w1=b2f(w4.y), w2=b2f(w4.z), w3=b2f(w4.w);
                int hh = q*4;
                a0 += hs[0][hh]*w0 + hs[0][hh+1]*w1 + hs[0][hh+2]*w2 + hs[0][hh+3]*w3;
                a1 += hs[1][hh]*w0 + hs[1][hh+1]*w1 + hs[1][hh+2]*w2 + hs[1][hh+3]*w3;
            }
            gs[0][c] = a0; gs[1][c] = a1;
        }
        __syncthreads();
        for (int i = tid; i < 2*Hc; i += 512){
            int cc = i/Hc, j = i%Hc;
            float ig = sigmoid_f(gs[cc][j]);
            float fg = sigmoid_f(gs[cc][Hc + j]);
            float gg = tanhf    (gs[cc][2*Hc + j]);
            float og = sigmoid_f(gs[cc][3*Hc + j]);
            float cn = fg*cs[cc][j] + ig*gg;
            cs[cc][j] = cn;
            hs[cc][j] = og*tanhf(cn);
        }
        __syncthreads();
    }
    for (int i = tid; i < 2*Hc; i += 512)
        h_final[(size_t)(cell0 + i/Hc)*Hc + (i%Hc)] = hs[i/Hc][i%Hc];
}

__global__ void build_stacked_kernel(const float* __restrict__ out_last, const float* __restrict__ hev,
                                     float* __restrict__ stacked)
{
    int b = blockIdx.x, s = blockIdx.y;
    const float* src = (s==0) ? (out_last + (size_t)b*Hc)
                              : (hev + ((size_t)b*Ec + (s-1))*Hc);
    float* dst = stacked + ((size_t)b*(Ec+1) + s)*Hc;
    for (int j = threadIdx.x; j < Hc; j += blockDim.x) dst[j] = src[j];
}

__global__ void wdctx_kernel(const float* __restrict__ Wd, const float* __restrict__ bd,
                             const float* __restrict__ ctx, float* __restrict__ wdc)
{
    int j = blockIdx.x*blockDim.x + threadIdx.x;
    if (j < Hc){
        float s = 0.0f;
        for (int d=0;d<DAc;d++) s += Wd[(size_t)j*DAc+d]*ctx[d];
        wdc[j] = s;
    } else if (j == Hc){
        float s = 0.0f;
        for (int d=0;d<DAc;d++) s += bd[d]*ctx[d];
        wdc[Hc] = s;
    }
}

__global__ void dp_attn_kernel(const float* __restrict__ stacked, const float* __restrict__ wdc,
                               float* __restrict__ o1)
{
    int b = blockIdx.x;
    int tid = threadIdx.x;
    __shared__ float sc[Ec+1];
    if (tid < Ec+1){
        float s = wdc[Hc];
        const float* x = stacked + ((size_t)b*(Ec+1)+tid)*Hc;
        for (int j=0;j<Hc;j++) s += x[j]*wdc[j];
        sc[tid] = s;
    }
    __syncthreads();
    if (tid == 0){
        float m = -INFINITY;
        for (int s=0;s<Ec+1;s++) m = fmaxf(m, sc[s]);
        float sum = 0.0f;
        for (int s=0;s<Ec+1;s++){ sc[s] = expf(sc[s]-m); sum += sc[s]; }
        float inv = 1.0f/sum;
        for (int s=0;s<Ec+1;s++) sc[s] *= inv;
    }
    __syncthreads();
    for (int j = tid; j < Hc; j += blockDim.x){
        float acc = 0.0f;
        for (int s=0;s<Ec+1;s++) acc += sc[s]*stacked[((size_t)b*(Ec+1)+s)*Hc + j];
        o1[(size_t)b*Hc + j] = acc;
    }
}

// ---------------------------------------------------------------------------
extern "C" void kernel_launch(void* const* d_in, const int* in_sizes, int n_in,
                              void* d_out, int out_size, void* d_ws, size_t ws_size,
                              hipStream_t stream)
{
    const int*   code_x    = (const int*)d_in[0];
    const int*   divided   = (const int*)d_in[1];
    const int*   neighbors = (const int*)d_in[2];
    const int*   events    = (const int*)d_in[4];
    const float* c_emb     = (const float*)d_in[5];
    const float* n_emb     = (const float*)d_in[6];
    const float* u_emb     = (const float*)d_in[7];
    const float* adj       = (const float*)d_in[8];
    const float* Wg        = (const float*)d_in[9];
    const float* bg        = (const float*)d_in[10];
    const float* gru_Wih   = (const float*)d_in[11];
    const float* gru_Whh   = (const float*)d_in[12];
    const float* gru_bih   = (const float*)d_in[13];
    const float* gru_bhh   = (const float*)d_in[14];
    const float* Wq        = (const float*)d_in[15];
    const float* bq        = (const float*)d_in[16];
    const float* Wk        = (const float*)d_in[17];
    const float* bk        = (const float*)d_in[18];
    const float* Wv        = (const float*)d_in[19];
    const float* bv        = (const float*)d_in[20];
    const float* Wd        = (const float*)d_in[21];
    const float* bd        = (const float*)d_in[22];
    const float* ctx       = (const float*)d_in[23];
    const float* Eemb      = (const float*)d_in[24];
    const float* lstm_Wih  = (const float*)d_in[25];
    const float* lstm_Whh  = (const float*)d_in[26];
    const float* lstm_b    = (const float*)d_in[27];
    const float* Wc        = (const float*)d_in[28];
    const float* bc        = (const float*)d_in[29];
    float* out = (float*)d_out;

    float* ws = (float*)d_ws;
    size_t off = 0;
    auto alloc = [&](size_t n){ n = (n+7)&~(size_t)7; float* p = ws + off; off += n; return p; };
    auto allocU = [&](size_t n){ return (ushort_t*)alloc((n+1)/2); };

    float* hm1     = alloc((size_t)Bc*Nc*Hc);
    float* hm23    = alloc((size_t)Bc*Nc*Hc);
    float* Spart   = alloc((size_t)8*Nc*Bc*CSc);
    float* gi      = alloc((size_t)Bc*Nc*H3c);
    float* gh      = alloc((size_t)Bc*Nc*H3c);     // g (4096x1024) aliases gi..gh region
    ushort_t* scoreb = allocU((size_t)Bc*Nc*Nc);
    ushort_t* X2b   = allocU((size_t)2*Bc*Nc*KPG);
    ushort_t* cob   = allocU((size_t)Bc*Nc*GSc);
    ushort_t* noA   = allocU((size_t)Bc*Nc*GSc);
    ushort_t* noB   = allocU((size_t)Bc*Nc*GSc);
    ushort_t* qinb  = allocU((size_t)Bc*Nc*GSc);
    ushort_t* qb    = allocU((size_t)Bc*Nc*ATc);
    ushort_t* kb    = allocU((size_t)Bc*Nc*ATc);
    ushort_t* vT    = allocU((size_t)Hc*Bc*Nc);
    ushort_t* hb    = allocU((size_t)Bc*Nc*KPH);
    ushort_t* adjb  = allocU((size_t)Nc*Nc);
    ushort_t* YTb   = allocU((size_t)Bc*CSc*Nc);
    ushort_t* u_embb= allocU((size_t)Nc*GSc);
    ushort_t* WgT   = allocU((size_t)GSc*KPG);
    ushort_t* WqT   = allocU((size_t)ATc*GSc);
    ushort_t* WkviT = allocU((size_t)NKVI*GSc);
    ushort_t* WhhT  = allocU((size_t)H3c*KPH);
    ushort_t* WTl   = allocU((size_t)H4c*KPE);
    ushort_t* WhhTl = allocU((size_t)H4c*272);
    float* bkvi    = alloc((size_t)NKVI);
    float* outlast = alloc((size_t)Bc*Hc);
    float* stacked = alloc((size_t)Bc*(Ec+1)*Hc);
    float* wdc     = alloc((size_t)(Hc+1));
    float* o1      = alloc((size_t)Bc*Hc);
    float* hev     = alloc((size_t)BEc*Hc);
    float* part1   = alloc((size_t)Bc*8*320);
    float* part23  = alloc((size_t)Bc*8*320);

    float* g       = gi;                    // alias: qk scores, dead before gi rewritten
    float* gatesx  = gi;                    // alias: lstm input gates (post-loop)
    ushort_t* Xgb  = scoreb;                // alias: lstm gathered embeddings (post-loop)
    (void)ws_size; (void)in_sizes; (void)n_in; (void)out_size; (void)adj;

    hipMemsetAsync(hb,  0, (size_t)Bc*Nc*KPH*sizeof(ushort_t), stream);
    hipMemsetAsync(noB, 0, (size_t)Bc*Nc*GSc*sizeof(ushort_t), stream);

    // ---- prep: weight conversions ----
    {
        long long tot;
        tot = (long long)Nc*Nc;
        convert_pad_kernel<<<(int)((tot+255)/256),256,0,stream>>>(adj, adjb, Nc, Nc, tot);
        tot = (long long)Nc*GSc;
        convert_pad_kernel<<<(int)((tot+255)/256),256,0,stream>>>(u_emb, u_embb, GSc, GSc, tot);
        tot = (long long)GSc*KPG;
        transpose_conv_kernel<<<(int)((tot+255)/256),256,0,stream>>>(Wg, WgT, GSc, CSc, KPG, GSc);
        tot = (long long)ATc*GSc;
        transpose_conv_kernel<<<(int)((tot+255)/256),256,0,stream>>>(Wq, WqT, ATc, GSc, GSc, ATc);
        tot = (long long)H3c*KPH;
        transpose_conv_kernel<<<(int)((tot+255)/256),256,0,stream>>>(gru_Whh, WhhT, H3c, Hc, KPH, H3c);
        tot = (long long)H4c*KPE;
        transpose_conv_kernel<<<(int)((tot+255)/256),256,0,stream>>>(lstm_Wih, WTl, H4c, EDc, KPE, H4c);
        tot = (long long)H4c*272;
        transpose_conv_kernel<<<(int)((tot+255)/256),256,0,stream>>>(lstm_Whh, WhhTl, H4c, Hc, 272, H4c);
        build_wkvit_kernel<<<(NKVI*32+255)/256,256,0,stream>>>(Wk, Wv, gru_Wih, WkviT);
        build_bkvi_kernel<<<(NKVI+255)/256,256,0,stream>>>(bk, bv, gru_bih, bkvi);
    }

    ushort_t* no_prev = noB;
    ushort_t* no_cur  = noA;
    for (int t=0; t<Tc; t++){
        build_YT_kernel<<<dim3(Bc*CSc), dim3(256), 0, stream>>>(code_x, neighbors, c_emb, n_emb, t, YTb);
        // S (split-K x8) : Spart[z] = adj[:, z*128:(z+1)*128] @ Y[z...]
        mfma_k<0,8><<<dim3(2,8,8),256,0,stream>>>(adjb, YTb, nullptr,
            Spart, nullptr, nullptr, nullptr, nullptr,
            Nc, Bc*CSc, Nc, Nc, Nc, Bc*CSc, 0,0,(long long)Nc*Bc*CSc, 0);
        build_conoin_kernel<<<dim3(1024),dim3(256),0,stream>>>(code_x, neighbors, c_emb, n_emb, Spart, t, X2b);
        // co|no = leaky(X2 @ Wg + bg), bf16 out, dual pointer
        mfma_k<1,0><<<dim3(1,64,1),256,0,stream>>>(X2b, WgT, bg,
            cob, no_cur, nullptr, nullptr, nullptr,
            2*Bc*Nc, GSc, KPG, KPG, KPG, GSc, 0,0,0, 0);
        build_qin_kernel<<<dim3(512),dim3(256),0,stream>>>(divided, u_embb, no_prev, t, qinb);
        // q = qin @ Wq + bq -> bf16
        mfma_k<2,0><<<dim3(1,32,1),256,0,stream>>>(qinb, WqT, bq,
            qb, nullptr, nullptr, nullptr, nullptr,
            Bc*Nc, ATc, GSc, GSc, GSc, ATc, 0,0,0, 0);
        // k|v|gi fused
        mfma_k<3,0><<<dim3(9,32,1),256,0,stream>>>(cob, WkviT, bkvi,
            kb, vT, gi, nullptr, nullptr,
            Bc*Nc, NKVI, GSc, GSc, GSc, 0, 0,0,0, 0);
        // gh = h @ Whh + bhh
        mfma_k<0,0><<<dim3(7,32,1),256,0,stream>>>(hb, WhhT, gru_bhh,
            gh, nullptr, nullptr, nullptr, nullptr,
            Bc*Nc, H3c, KPH, KPH, KPH, H3c, 0,0,0, 0);
        gru_combine_kernel<<<dim3(Bc*Nc), dim3(256), 0, stream>>>(gi, gh, hb, hm1);
        // g = q @ k^T (batched over b)
        mfma_k<0,0><<<dim3(8,8,Bc),256,0,stream>>>(qb, kb, nullptr,
            g, nullptr, nullptr, nullptr, nullptr,
            Nc, Nc, ATc, ATc, ATc, Nc,
            (long long)Nc*ATc, (long long)Nc*ATc, 0, 0);
        softmax_kernel<<<dim3(Nc,Bc),256,0,stream>>>(g, divided, t, scoreb);
        // hm23 = tanh(score @ v); fused h-update writes hb (bf16) + hm23 (f32)
        mfma_k<4,0><<<dim3(3,8,Bc),256,0,stream>>>(scoreb, vT, nullptr,
            hb, hm23, nullptr, hm1, divided,
            Nc, Hc, Nc, Nc, Bc*Nc, 0,
            (long long)Nc*Nc, (long long)Nc, 0, t);
        if (t == Tc-1){
            outlast_partial_kernel<<<dim3(8, Bc), dim3(256), 0, stream>>>(divided, hm1, hm23, part1, part23);
            outlast_combine_kernel<<<dim3(Bc), dim3(320), 0, stream>>>(part1, part23, outlast);
        }
        ushort_t* tmp = no_prev; no_prev = no_cur; no_cur = tmp;
    }

    // ---- LSTM over last-visit events ----
    gather_emb_kernel<<<dim3(BEc*Lc), dim3(256), 0, stream>>>(events, Eemb, Xgb);
    mfma_k<0,0><<<dim3(9,32,1),256,0,stream>>>(Xgb, WTl, lstm_b,
        gatesx, nullptr, nullptr, nullptr, nullptr,
        BEc*Lc, H4c, KPE, KPE, KPE, H4c, 0,0,0, 0);
    lstm_all_kernel<<<dim3(BEc/2), dim3(512), 0, stream>>>(gatesx, WhhTl, hev);

    // ---- heads ----
    build_stacked_kernel<<<dim3(Bc, Ec+1), dim3(64), 0, stream>>>(outlast, hev, stacked);
    wdctx_kernel<<<dim3(2), dim3(256), 0, stream>>>(Wd, bd, ctx, wdc);
    dp_attn_kernel<<<dim3(Bc), dim3(256), 0, stream>>>(stacked, wdc, o1);
    {
        dim3 grid((OUTc+63)/64, 1, 1);
        gemm_kernel<3><<<grid,dim3(256),0,stream>>>(o1, Wc, bc, out, Bc, OUTc, Hc);
    }
}

// Round 4
// 1478.775 us; speedup vs baseline: 3.3965x; 1.2950x over previous
//
#include <hip/hip_runtime.h>
#include <hip/hip_bf16.h>
#include <math.h>

// Problem constants
#define Bc   4
#define Tc   6
#define Nc   1024
#define CSc  48
#define GSc  32
#define Hc   270
#define ATc  32
#define DAc  64
#define Ec   32
#define Lc   32
#define EDc  400
#define OUTc 4000
#define H3c  810    // 3*H
#define H4c  1080   // 4*H
#define BEc  128    // B*E
#define KPH  288    // H padded to 32
#define KPE  416    // ED padded to 32
#define KPG  64     // CS padded to 32
#define NKVI 1112   // 32 + 270 + 810
#define INV_SQRT_AT_F 0.17677669529663687f

typedef unsigned short ushort_t;
using s8v = __attribute__((ext_vector_type(8))) short;
using f4v = __attribute__((ext_vector_type(4))) float;

__device__ __forceinline__ float sigmoid_f(float x){ return 1.0f/(1.0f+expf(-x)); }
__device__ __forceinline__ ushort_t f2bf(float x){
    __hip_bfloat16 b = __float2bfloat16(x);
    return *reinterpret_cast<ushort_t*>(&b);
}
__device__ __forceinline__ float b2f(ushort_t u){
    return __uint_as_float(((unsigned int)u)<<16);
}

// ---------------------------------------------------------------------------
// bf16 MFMA GEMM, 128x128 tile, 4 waves.
// EPIL 0: f32 store (+bias) ; SPLITK>0: z = K-slice, C += z*sC
// EPIL 1: leaky-relu dual bf16 (row<4096 -> P0 else P1, ld 32)
// EPIL 2: bf16 store P0 (+bias)
// EPIL 3: kvgi mixed: col<32 kb bf16; col<302 vT bf16 transposed; else gi f32
// EPIL 4: pv: x=tanh(acc); fused h-update: P0=hb bf16 [grow*KPH], P1=hm23 f32,
//         PF=hm1, DV=divided, tpar=t
// ASEL 1: A-row select (q_in): row r -> m3 ? u_embb[n] : no_prev[r]; P2=u_embb
// ---------------------------------------------------------------------------
template<int EPIL, int SPLITK, int ASEL>
__global__ __launch_bounds__(256)
void mfma_k(const ushort_t* __restrict__ A, const ushort_t* __restrict__ BT,
            const float* __restrict__ bias,
            void* __restrict__ P0, void* __restrict__ P1, void* __restrict__ P2,
            const float* __restrict__ PF, const int* __restrict__ DV,
            int M, int N, int Kp, int lda, int ldb, int ldc,
            long long sA, long long sB, long long sC, int tpar)
{
    __shared__ ushort_t As[128*40];
    __shared__ ushort_t Bs[128*40];
    const int z = blockIdx.z;
    int kbeg = 0, kend = Kp;
    if (SPLITK > 0){
        int ks = Kp / SPLITK;
        kbeg = z*ks; kend = kbeg + ks;
    } else {
        A  += (size_t)z * (size_t)sA;
        BT += (size_t)z * (size_t)sB;
    }
    const int m0 = blockIdx.y*128, n0 = blockIdx.x*128;
    const int tid = threadIdx.x;
    const int w = tid>>6, l = tid&63;
    const int wm = (w>>1)*64, wn = (w&1)*64;
    const int lr = l&15, lk = (l>>4)*8, lq = l>>4;
    const int srow = tid>>2, kseg = tid&3;

    f4v acc[4][4];
    #pragma unroll
    for (int mi=0;mi<4;mi++)
      #pragma unroll
      for (int ni=0;ni<4;ni++)
        acc[mi][ni] = (f4v){0.0f,0.0f,0.0f,0.0f};

    for (int k0=kbeg;k0<kend;k0+=32){
        #pragma unroll
        for (int i=0;i<2;i++){
            int row = srow + i*64;
            int ga = m0+row;
            uint4 va = make_uint4(0u,0u,0u,0u);
            if (ga < M){
                if (ASEL == 1){
                    int b = ga>>10, n = ga&1023;
                    bool m3 = DV[(((size_t)b*Tc+tpar)*Nc+n)*3 + 2] > 0;
                    const ushort_t* src = m3 ? ((const ushort_t*)P2 + (size_t)n*GSc)
                                             : (A + (size_t)ga*lda);
                    va = *(const uint4*)(src + k0 + kseg*8);
                } else {
                    va = *(const uint4*)(A + (size_t)ga*lda + k0 + kseg*8);
                }
            }
            *(uint4*)&As[row*40 + kseg*8] = va;
            int gb = n0+row;
            uint4 vb = make_uint4(0u,0u,0u,0u);
            if (gb < N) vb = *(const uint4*)(BT + (size_t)gb*ldb + k0 + kseg*8);
            *(uint4*)&Bs[row*40 + kseg*8] = vb;
        }
        __syncthreads();
        s8v af[4], bfr[4];
        #pragma unroll
        for (int mi=0;mi<4;mi++) af[mi]  = *(const s8v*)&As[(wm+mi*16+lr)*40 + lk];
        #pragma unroll
        for (int ni=0;ni<4;ni++) bfr[ni] = *(const s8v*)&Bs[(wn+ni*16+lr)*40 + lk];
        #pragma unroll
        for (int mi=0;mi<4;mi++)
          #pragma unroll
          for (int ni=0;ni<4;ni++)
            acc[mi][ni] = __builtin_amdgcn_mfma_f32_16x16x32_bf16(af[mi], bfr[ni], acc[mi][ni], 0,0,0);
        __syncthreads();
    }

    #pragma unroll
    for (int mi=0;mi<4;mi++){
      #pragma unroll
      for (int ni=0;ni<4;ni++){
        int col = n0+wn+ni*16+lr;
        if (col >= N) continue;
        float bv_ = (EPIL!=4 && bias) ? bias[col] : 0.0f;
        #pragma unroll
        for (int r=0;r<4;r++){
          int row = m0+wm+mi*16+lq*4+r;
          if (row >= M) continue;
          float x = acc[mi][ni][r] + bv_;
          if (EPIL == 0){
              float* C = (float*)P0;
              size_t base = (SPLITK>0) ? (size_t)z*(size_t)sC : 0;
              size_t grow = (SPLITK>0) ? (size_t)row : (size_t)z*M + row;
              C[base + grow*ldc + col] = x;
          } else if (EPIL == 1){
              x = (x>0.0f) ? x : 0.01f*x;
              if (row < 4096) ((ushort_t*)P0)[(size_t)row*32 + col] = f2bf(x);
              else            ((ushort_t*)P1)[(size_t)(row-4096)*32 + col] = f2bf(x);
          } else if (EPIL == 2){
              ((ushort_t*)P0)[(size_t)row*ldc + col] = f2bf(x);
          } else if (EPIL == 3){
              if (col < 32)        ((ushort_t*)P0)[(size_t)row*32 + col] = f2bf(x);
              else if (col < 302)  ((ushort_t*)P1)[(size_t)(col-32)*4096 + row] = f2bf(x);
              else                 ((float*)P2)[(size_t)row*H3c + (col-302)] = x;
          } else if (EPIL == 4){
              float xt = tanhf(x);
              size_t grow = (size_t)z*M + row;
              const int* dv = DV + (((size_t)z*Tc + tpar)*Nc + row)*3;
              bool m1  = dv[0] > 0;
              bool m23 = (dv[1] > 0) || (dv[2] > 0);
              bool use23 = (tpar > 0) && m23;
              float hv = use23 ? xt : (m1 ? PF[grow*Hc + col] : 0.0f);
              ((ushort_t*)P0)[grow*KPH + col] = f2bf(hv);
              ((float*)P1)[grow*Hc + col] = xt;
          }
        }
      }
    }
}

// ---------------------------------------------------------------------------
// f32 tiled GEMM (final layer only). ACT 3 = sigmoid.
// ---------------------------------------------------------------------------
template<int ACT>
__global__ __launch_bounds__(256)
void gemm_kernel(const float* __restrict__ A, const float* __restrict__ Bm,
                 const float* __restrict__ bias, float* __restrict__ C,
                 int M, int Nn, int K)
{
    constexpr int BM=64, BN=64, BK=16;
    __shared__ float As[BK][BM+4];
    __shared__ float Bs[BK][BN+4];
    const int row0 = blockIdx.y*BM, col0 = blockIdx.x*BN;
    const int tid = threadIdx.x;
    const int tr = (tid>>4)<<2;
    const int tc = (tid&15)<<2;
    const int ar = tid>>2;
    const int ac = (tid&3)<<2;
    const int br = tid>>4;
    const int bc = (tid&15)<<2;
    float acc[4][4] = {};
    for (int k0=0;k0<K;k0+=BK){
        #pragma unroll
        for (int i=0;i<4;i++){
            int gr=row0+ar, gc=k0+ac+i;
            As[ac+i][ar] = (gr<M && gc<K) ? A[(size_t)gr*K+gc] : 0.0f;
        }
        #pragma unroll
        for (int i=0;i<4;i++){
            int gr=k0+br, gc=col0+bc+i;
            Bs[br][bc+i] = (gr<K && gc<Nn) ? Bm[(size_t)gr*Nn+gc] : 0.0f;
        }
        __syncthreads();
        #pragma unroll
        for (int kk=0;kk<BK;kk++){
            float a0=As[kk][tr+0], a1=As[kk][tr+1], a2=As[kk][tr+2], a3=As[kk][tr+3];
            float b0=Bs[kk][tc+0], b1=Bs[kk][tc+1], b2=Bs[kk][tc+2], b3=Bs[kk][tc+3];
            acc[0][0]+=a0*b0; acc[0][1]+=a0*b1; acc[0][2]+=a0*b2; acc[0][3]+=a0*b3;
            acc[1][0]+=a1*b0; acc[1][1]+=a1*b1; acc[1][2]+=a1*b2; acc[1][3]+=a1*b3;
            acc[2][0]+=a2*b0; acc[2][1]+=a2*b1; acc[2][2]+=a2*b2; acc[2][3]+=a2*b3;
            acc[3][0]+=a3*b0; acc[3][1]+=a3*b1; acc[3][2]+=a3*b2; acc[3][3]+=a3*b3;
        }
        __syncthreads();
    }
    #pragma unroll
    for (int i=0;i<4;i++){
        int r=row0+tr+i; if (r>=M) continue;
        #pragma unroll
        for (int j=0;j<4;j++){
            int c=col0+tc+j; if (c>=Nn) continue;
            float x = acc[i][j];
            if (bias) x += bias[c];
            if (ACT==3) x = 1.0f/(1.0f+expf(-x));
            C[(size_t)r*Nn+c] = x;
        }
    }
}

// ---------------------------------------------------------------------------
// Single prep kernel: all weight conversions + zero-fills. Ranges cascade.
// ---------------------------------------------------------------------------
#define PR0 1048576LL   // adjb
#define PR1 32768LL     // u_embb
#define PR2 2048LL      // WgT
#define PR3 1024LL      // WqT
#define PR4 233280LL    // WhhT (gru)
#define PR5 449280LL    // WTl (lstm Wih)
#define PR6 313344LL    // WhhRT (lstm recurrent reorg) 17*64*288
#define PR7 35584LL     // WkviT
#define PR8 1112LL      // bkvi
#define PR9 73728LL     // zero hbLA+hbLB
#define PR10 36864LL    // zero cst
#define PR11 1179648LL  // zero hb (visit)
#define PRTOT (PR0+PR1+PR2+PR3+PR4+PR5+PR6+PR7+PR8+PR9+PR10+PR11)

__global__ void prep_kernel(const float* __restrict__ adj, const float* __restrict__ u_emb,
                            const float* __restrict__ Wg, const float* __restrict__ Wq,
                            const float* __restrict__ gru_Whh, const float* __restrict__ lstm_Wih,
                            const float* __restrict__ lstm_Whh,
                            const float* __restrict__ Wk, const float* __restrict__ Wv,
                            const float* __restrict__ gru_Wih,
                            const float* __restrict__ bk, const float* __restrict__ bv,
                            const float* __restrict__ gru_bih,
                            ushort_t* adjb, ushort_t* u_embb, ushort_t* WgT, ushort_t* WqT,
                            ushort_t* WhhT, ushort_t* WTl, ushort_t* WhhRT, ushort_t* WkviT,
                            float* bkvi, ushort_t* hbLA, ushort_t* hbLB, float* cst, ushort_t* hb)
{
    long long idx = (long long)blockIdx.x*256 + threadIdx.x;
    if (idx < PR0){ adjb[idx] = f2bf(adj[idx]); return; } idx -= PR0;
    if (idx < PR1){ u_embb[idx] = f2bf(u_emb[idx]); return; } idx -= PR1;
    if (idx < PR2){ int n=(int)(idx>>6), k=(int)(idx&63);
        WgT[idx] = (k<CSc) ? f2bf(Wg[(size_t)k*GSc+n]) : (ushort_t)0; return; } idx -= PR2;
    if (idx < PR3){ int n=(int)(idx>>5), k=(int)(idx&31);
        WqT[idx] = f2bf(Wq[(size_t)k*ATc+n]); return; } idx -= PR3;
    if (idx < PR4){ int n=(int)(idx/KPH), k=(int)(idx%KPH);
        WhhT[idx] = (k<Hc) ? f2bf(gru_Whh[(size_t)k*H3c+n]) : (ushort_t)0; return; } idx -= PR4;
    if (idx < PR5){ int n=(int)(idx/KPE), k=(int)(idx%KPE);
        WTl[idx] = (k<EDc) ? f2bf(lstm_Wih[(size_t)k*H4c+n]) : (ushort_t)0; return; } idx -= PR5;
    if (idx < PR6){
        int jg=(int)(idx/(64*288)); int r2=(int)(idx%(64*288));
        int n=r2/288, k=r2%288;
        int gate=n>>4, jj=n&15, j=jg*16+jj;
        WhhRT[idx] = (k<Hc && j<Hc) ? f2bf(lstm_Whh[(size_t)k*H4c + gate*Hc + j]) : (ushort_t)0;
        return; } idx -= PR6;
    if (idx < PR7){ int n=(int)(idx>>5), k=(int)(idx&31);
        float v;
        if (n < 32)       v = Wk[(size_t)k*ATc + n];
        else if (n < 302) v = Wv[(size_t)k*Hc + (n-32)];
        else              v = gru_Wih[(size_t)k*H3c + (n-302)];
        WkviT[idx] = f2bf(v); return; } idx -= PR7;
    if (idx < PR8){
        float v;
        if (idx < 32)       v = bk[idx];
        else if (idx < 302) v = bv[idx-32];
        else                v = gru_bih[idx-302];
        bkvi[idx] = v; return; } idx -= PR8;
    if (idx < PR9){ if (idx < 36864) hbLA[idx] = 0; else hbLB[idx-36864] = 0; return; } idx -= PR9;
    if (idx < PR10){ cst[idx] = 0.0f; return; } idx -= PR10;
    if (idx < PR11){ hb[idx] = 0; }
}

// ---------------------------------------------------------------------------
// YT[bc][n] = bf16(cm*c_emb[n,c] + nm*n_emb[n,c])
// ---------------------------------------------------------------------------
__global__ void build_YT_kernel(const int* __restrict__ code_x, const int* __restrict__ neighbors,
                                const float* __restrict__ c_emb, const float* __restrict__ n_emb,
                                int t, ushort_t* __restrict__ YT)
{
    int bc = blockIdx.x;
    int b = bc / CSc, c = bc % CSc;
    for (int n = threadIdx.x; n < Nc; n += 256){
        float cm = (float)code_x[((size_t)b*Tc+t)*Nc + n];
        float nm = (float)neighbors[((size_t)b*Tc+t)*Nc + n];
        YT[(size_t)bc*Nc + n] = f2bf(cm*c_emb[(size_t)n*CSc+c] + nm*n_emb[(size_t)n*CSc+c]);
    }
}

// ---------------------------------------------------------------------------
// conoin: sum 8 split-K partials of S, build X2b bf16 [8192][64]
// ---------------------------------------------------------------------------
__global__ __launch_bounds__(256)
void build_conoin_kernel(const int* __restrict__ code_x, const int* __restrict__ neighbors,
                         const float* __restrict__ c_emb, const float* __restrict__ n_emb,
                         const float* __restrict__ Spart, int t, ushort_t* __restrict__ X2b)
{
    int idx = blockIdx.x*256 + threadIdx.x;
    int r = idx >> 6, c = idx & 63;
    int b = r >> 10, n = r & 1023;
    float xa = 0.0f, xb = 0.0f;
    if (c < CSc){
        float s = 0.0f;
        #pragma unroll
        for (int z=0;z<8;z++) s += Spart[(size_t)z*(Nc*Bc*CSc) + (size_t)n*(Bc*CSc) + b*CSc + c];
        float cm = (float)code_x[((size_t)b*Tc+t)*Nc + n];
        float nm = (float)neighbors[((size_t)b*Tc+t)*Nc + n];
        xa = cm*(c_emb[(size_t)n*CSc+c] + s);
        xb = nm*(n_emb[(size_t)n*CSc+c] + s);
    }
    X2b[(size_t)r*KPG + c] = f2bf(xa);
    X2b[((size_t)r+4096)*KPG + c] = f2bf(xb);
}

// GRU combine (t>=1): hm1 = (1-z)*n + z*h
__global__ void gru_combine_kernel(const float* __restrict__ gi, const float* __restrict__ gh,
                                   const ushort_t* __restrict__ hb, float* __restrict__ hm1)
{
    int r = blockIdx.x;
    size_t o3 = (size_t)r*H3c;
    for (int j = threadIdx.x; j < Hc; j += blockDim.x){
        float ir = gi[o3+j],      hr = gh[o3+j];
        float iz = gi[o3+Hc+j],   hz = gh[o3+Hc+j];
        float in_= gi[o3+2*Hc+j], hn = gh[o3+2*Hc+j];
        float rg = sigmoid_f(ir+hr);
        float zg = sigmoid_f(iz+hz);
        float ng = tanhf(in_ + rg*hn);
        hm1[(size_t)r*Hc + j] = (1.0f-zg)*ng + zg*b2f(hb[(size_t)r*KPH + j]);
    }
}

// GRU combine at t=0: gh = bhh (h=0); writes hb directly (h_new = m1 ? hm1 : 0)
__global__ void gru_combine_t0_kernel(const float* __restrict__ gi, const float* __restrict__ bhh,
                                      const int* __restrict__ divided, ushort_t* __restrict__ hb)
{
    int r = blockIdx.x;
    int b = r >> 10, n = r & 1023;
    bool m1 = divided[(((size_t)b*Tc+0)*Nc+n)*3 + 0] > 0;
    size_t o3 = (size_t)r*H3c;
    for (int j = threadIdx.x; j < Hc; j += blockDim.x){
        float rg = sigmoid_f(gi[o3+j]      + bhh[j]);
        float zg = sigmoid_f(gi[o3+Hc+j]   + bhh[Hc+j]);
        float ng = tanhf(gi[o3+2*Hc+j] + rg*bhh[2*Hc+j]);
        float hv = (1.0f-zg)*ng;
        hb[(size_t)r*KPH + j] = m1 ? f2bf(hv) : (ushort_t)0;
    }
}

// ---------------------------------------------------------------------------
// masked softmax over f32 g -> bf16 score
// ---------------------------------------------------------------------------
__global__ __launch_bounds__(256)
void softmax_kernel(const float* __restrict__ g, const int* __restrict__ divided,
                    int t, ushort_t* __restrict__ scoreb)
{
    int i = blockIdx.x, b = blockIdx.y;
    int tid = threadIdx.x;
    __shared__ float red[8];
    const float* gr = g + ((size_t)b*Nc + i)*Nc;

    float gvals[4];
    float lmax = -INFINITY, lhas = 0.0f;
    #pragma unroll
    for (int jj=0;jj<4;jj++){
        int j = jj*256 + tid;
        float d = gr[j] * INV_SQRT_AT_F;
        const int* dv = divided + (((size_t)b*Tc+t)*Nc + j)*3;
        bool m23 = (dv[1] > 0) || (dv[2] > 0);
        lhas = fmaxf(lhas, m23 ? 1.0f : 0.0f);
        d = m23 ? d : -INFINITY;
        gvals[jj] = d;
        lmax = fmaxf(lmax, d);
    }
    #pragma unroll
    for (int o=1;o<64;o<<=1){
        lmax = fmaxf(lmax, __shfl_xor(lmax, o, 64));
        lhas = fmaxf(lhas, __shfl_xor(lhas, o, 64));
    }
    int wid = tid >> 6;
    if ((tid & 63) == 0){ red[wid] = lmax; red[4+wid] = lhas; }
    __syncthreads();
    float gmax = fmaxf(fmaxf(red[0],red[1]), fmaxf(red[2],red[3]));
    bool  has  = fmaxf(fmaxf(red[4],red[5]), fmaxf(red[6],red[7])) > 0.5f;

    float evals[4];
    float lsum = 0.0f;
    #pragma unroll
    for (int jj=0;jj<4;jj++){
        float e_;
        if (has) e_ = (gvals[jj] == -INFINITY) ? 0.0f : expf(gvals[jj]-gmax);
        else     e_ = 1.0f;
        evals[jj] = e_; lsum += e_;
    }
    #pragma unroll
    for (int o=1;o<64;o<<=1) lsum += __shfl_xor(lsum, o, 64);
    __syncthreads();
    if ((tid & 63) == 0) red[wid] = lsum;
    __syncthreads();
    float invs = 1.0f/(red[0]+red[1]+red[2]+red[3]);
    #pragma unroll
    for (int jj=0;jj<4;jj++){
        int j = jj*256 + tid;
        scoreb[((size_t)b*Nc+i)*Nc + j] = f2bf(evals[jj]*invs);
    }
}

// ---------------------------------------------------------------------------
// out_last two-phase reduction (t = T-1)
// ---------------------------------------------------------------------------
__global__ __launch_bounds__(256)
void outlast_partial_kernel(const int* __restrict__ divided,
                            const float* __restrict__ hm1, const float* __restrict__ hm23,
                            float* __restrict__ part1, float* __restrict__ part23)
{
    int nc = blockIdx.x, b = blockIdx.y;
    int jl = threadIdx.x & 63, nl = threadIdx.x >> 6;
    __shared__ float r1[4][64], r23[4][64];
    for (int jseg=0;jseg<5;jseg++){
        int j = jseg*64 + jl;
        float m1v = -INFINITY, m23v = -INFINITY;
        if (j < Hc){
            for (int n = nc*128+nl; n < nc*128+128; n += 4){
                const int* dv = divided + (((size_t)b*Tc + (Tc-1))*Nc + n)*3;
                bool m1  = dv[0] > 0;
                bool m23 = (dv[1] > 0) || (dv[2] > 0);
                size_t o = ((size_t)b*Nc+n)*Hc + j;
                if (m1)  m1v  = fmaxf(m1v,  hm1[o]);
                if (m23) m23v = fmaxf(m23v, hm23[o]);
            }
        }
        r1[nl][jl] = m1v; r23[nl][jl] = m23v;
        __syncthreads();
        if (nl == 0){
            float a = fmaxf(fmaxf(r1[0][jl],r1[1][jl]), fmaxf(r1[2][jl],r1[3][jl]));
            float c = fmaxf(fmaxf(r23[0][jl],r23[1][jl]), fmaxf(r23[2][jl],r23[3][jl]));
            part1 [((size_t)b*8+nc)*320 + jseg*64+jl] = a;
            part23[((size_t)b*8+nc)*320 + jseg*64+jl] = c;
        }
        __syncthreads();
    }
}

__global__ void outlast_combine_kernel(const float* __restrict__ part1, const float* __restrict__ part23,
                                       float* __restrict__ outlast)
{
    int b = blockIdx.x; int j = threadIdx.x;
    if (j >= Hc) return;
    float a = -INFINITY, c = -INFINITY;
    for (int nc=0;nc<8;nc++){
        a = fmaxf(a, part1 [((size_t)b*8+nc)*320 + j]);
        c = fmaxf(c, part23[((size_t)b*8+nc)*320 + j]);
    }
    outlast[(size_t)b*Hc + j] = (a==-INFINITY ? 0.0f : a) + (c==-INFINITY ? 0.0f : c);
}

// ---------------------------------------------------------------------------
// Gather event embeddings -> bf16 padded rows [l*BE+be][KPE]
// ---------------------------------------------------------------------------
__global__ void gather_emb_kernel(const int* __restrict__ events, const float* __restrict__ Eemb,
                                  ushort_t* __restrict__ Xg)
{
    int blk = blockIdx.x;
    int l = blk / BEc, be = blk % BEc;
    int b = be / Ec, e = be % Ec;
    int ev = events[(((size_t)b*Tc + (Tc-1))*Ec + e)*Lc + l];
    const float* src = Eemb + (size_t)ev*EDc;
    ushort_t* dst = Xg + (size_t)blk*KPE;
    for (int d = threadIdx.x; d < KPE; d += blockDim.x)
        dst[d] = (d < EDc) ? f2bf(src[d]) : (ushort_t)0;
}

// ---------------------------------------------------------------------------
// LSTM MFMA step: 68 blocks = 4 cellgroups(32) x 17 jgroups(16 j-cols).
// gates = hb_in @ WhhRT-slice (M=32,N=64,K=288 MFMA) + gatesx; cell update;
// write hb_out bf16 slice + c (exclusive). hev_out written on last step.
// ---------------------------------------------------------------------------
__global__ __launch_bounds__(256)
void lstm_step_mfma(const float* __restrict__ gx,       // [128][1080] at step l
                    const ushort_t* __restrict__ WhhRT, // [17][64][288]
                    const ushort_t* __restrict__ hb_in, // [128][288]
                    ushort_t* __restrict__ hb_out,
                    float* __restrict__ cst,            // [128][288]
                    float* __restrict__ hev_out)        // [128][270] or null
{
    int cg = blockIdx.x & 3, jg = blockIdx.x >> 2;
    int tid = threadIdx.x;
    int w = tid>>6, l = tid&63;
    int mi = w>>1, ni0 = (w&1)*2;
    int arow = cg*32 + mi*16 + (l&15);
    int koff = (l>>4)*8;
    const ushort_t* Wb = WhhRT + (size_t)jg*64*288;

    f4v acc0 = (f4v){0,0,0,0}, acc1 = (f4v){0,0,0,0};
    #pragma unroll
    for (int k0=0;k0<288;k0+=32){
        s8v a  = *(const s8v*)(hb_in + (size_t)arow*288 + k0 + koff);
        s8v b0 = *(const s8v*)(Wb + (size_t)(ni0*16 + (l&15))*288 + k0 + koff);
        s8v b1 = *(const s8v*)(Wb + (size_t)((ni0+1)*16 + (l&15))*288 + k0 + koff);
        acc0 = __builtin_amdgcn_mfma_f32_16x16x32_bf16(a, b0, acc0, 0,0,0);
        acc1 = __builtin_amdgcn_mfma_f32_16x16x32_bf16(a, b1, acc1, 0,0,0);
    }
    __shared__ float gs[32][64];
    int crow = mi*16 + (l>>4)*4;
    int ccol = l&15;
    #pragma unroll
    for (int r=0;r<4;r++){
        gs[crow+r][ni0*16 + ccol]     = acc0[r];
        gs[crow+r][(ni0+1)*16 + ccol] = acc1[r];
    }
    __syncthreads();
    #pragma unroll
    for (int p=0;p<2;p++){
        int idx = tid + p*256;
        int cl = idx>>4, jj = idx&15;
        int j = jg*16 + jj;
        if (j < Hc){
            int cell = cg*32 + cl;
            const float* g = gx + (size_t)cell*H4c;
            float ig = sigmoid_f(gs[cl][jj]      + g[j]);
            float fg = sigmoid_f(gs[cl][16+jj]   + g[Hc+j]);
            float gg = tanhf    (gs[cl][32+jj]   + g[2*Hc+j]);
            float og = sigmoid_f(gs[cl][48+jj]   + g[3*Hc+j]);
            size_t co = (size_t)cell*288 + j;
            float cn = fg*cst[co] + ig*gg;
            cst[co] = cn;
            float hn = og*tanhf(cn);
            hb_out[co] = f2bf(hn);
            if (hev_out) hev_out[(size_t)cell*Hc + j] = hn;
        }
    }
}

// ---------------------------------------------------------------------------
// heads: wdc + dp_attention over [outlast ; hev] -> o1 (o2 == o1)
// ---------------------------------------------------------------------------
__global__ __launch_bounds__(256)
void heads_kernel(const float* __restrict__ outlast, const float* __restrict__ hev,
                  const float* __restrict__ Wd, const float* __restrict__ bd,
                  const float* __restrict__ ctx, float* __restrict__ o1)
{
    int b = blockIdx.x, tid = threadIdx.x;
    __shared__ float wdc[Hc+1];
    __shared__ float sc[Ec+1];
    for (int j=tid;j<Hc;j+=256){
        float s = 0.0f;
        for (int d=0;d<DAc;d++) s += Wd[(size_t)j*DAc+d]*ctx[d];
        wdc[j] = s;
    }
    if (tid == 255){
        float s = 0.0f;
        for (int d=0;d<DAc;d++) s += bd[d]*ctx[d];
        wdc[Hc] = s;
    }
    __syncthreads();
    if (tid < Ec+1){
        const float* x = (tid==0) ? (outlast + (size_t)b*Hc)
                                  : (hev + ((size_t)b*Ec + tid-1)*Hc);
        float s = wdc[Hc];
        for (int j=0;j<Hc;j++) s += x[j]*wdc[j];
        sc[tid] = s;
    }
    __syncthreads();
    if (tid == 0){
        float m = -INFINITY;
        for (int s=0;s<Ec+1;s++) m = fmaxf(m, sc[s]);
        float sum = 0.0f;
        for (int s=0;s<Ec+1;s++){ sc[s] = expf(sc[s]-m); sum += sc[s]; }
        float inv = 1.0f/sum;
        for (int s=0;s<Ec+1;s++) sc[s] *= inv;
    }
    __syncthreads();
    for (int j=tid;j<Hc;j+=256){
        float acc = sc[0]*outlast[(size_t)b*Hc + j];
        for (int e=0;e<Ec;e++) acc += sc[1+e]*hev[((size_t)b*Ec+e)*Hc + j];
        o1[(size_t)b*Hc + j] = acc;
    }
}

// ---------------------------------------------------------------------------
extern "C" void kernel_launch(void* const* d_in, const int* in_sizes, int n_in,
                              void* d_out, int out_size, void* d_ws, size_t ws_size,
                              hipStream_t stream)
{
    const int*   code_x    = (const int*)d_in[0];
    const int*   divided   = (const int*)d_in[1];
    const int*   neighbors = (const int*)d_in[2];
    const int*   events    = (const int*)d_in[4];
    const float* c_emb     = (const float*)d_in[5];
    const float* n_emb     = (const float*)d_in[6];
    const float* u_emb     = (const float*)d_in[7];
    const float* adj       = (const float*)d_in[8];
    const float* Wg        = (const float*)d_in[9];
    const float* bg        = (const float*)d_in[10];
    const float* gru_Wih   = (const float*)d_in[11];
    const float* gru_Whh   = (const float*)d_in[12];
    const float* gru_bih   = (const float*)d_in[13];
    const float* gru_bhh   = (const float*)d_in[14];
    const float* Wq        = (const float*)d_in[15];
    const float* bq        = (const float*)d_in[16];
    const float* Wk        = (const float*)d_in[17];
    const float* bk        = (const float*)d_in[18];
    const float* Wv        = (const float*)d_in[19];
    const float* bv        = (const float*)d_in[20];
    const float* Wd        = (const float*)d_in[21];
    const float* bd        = (const float*)d_in[22];
    const float* ctx       = (const float*)d_in[23];
    const float* Eemb      = (const float*)d_in[24];
    const float* lstm_Wih  = (const float*)d_in[25];
    const float* lstm_Whh  = (const float*)d_in[26];
    const float* lstm_b    = (const float*)d_in[27];
    const float* Wc        = (const float*)d_in[28];
    const float* bc        = (const float*)d_in[29];
    float* out = (float*)d_out;

    float* ws = (float*)d_ws;
    size_t off = 0;
    auto alloc = [&](size_t n){ n = (n+7)&~(size_t)7; float* p = ws + off; off += n; return p; };
    auto allocU = [&](size_t n){ return (ushort_t*)alloc((n+1)/2); };

    float* hm1     = alloc((size_t)Bc*Nc*Hc);
    float* hm23    = alloc((size_t)Bc*Nc*Hc);
    float* Spart   = alloc((size_t)8*Nc*Bc*CSc);
    float* gi      = alloc((size_t)Bc*Nc*H3c);
    float* gh      = alloc((size_t)Bc*Nc*H3c);     // contiguous with gi (g/gatesx alias)
    ushort_t* scoreb = allocU((size_t)Bc*Nc*Nc);
    ushort_t* X2b   = allocU((size_t)2*Bc*Nc*KPG);
    ushort_t* cob   = allocU((size_t)Bc*Nc*GSc);
    ushort_t* noA   = allocU((size_t)Bc*Nc*GSc);
    ushort_t* noB   = allocU((size_t)Bc*Nc*GSc);
    ushort_t* qb    = allocU((size_t)Bc*Nc*ATc);
    ushort_t* kb    = allocU((size_t)Bc*Nc*ATc);
    ushort_t* vT    = allocU((size_t)Hc*Bc*Nc);
    ushort_t* hb    = allocU((size_t)Bc*Nc*KPH);
    ushort_t* adjb  = allocU((size_t)Nc*Nc);
    ushort_t* YTb   = allocU((size_t)Bc*CSc*Nc);
    ushort_t* u_embb= allocU((size_t)Nc*GSc);
    ushort_t* WgT   = allocU((size_t)GSc*KPG);
    ushort_t* WqT   = allocU((size_t)ATc*GSc);
    ushort_t* WkviT = allocU((size_t)NKVI*GSc);
    ushort_t* WhhT  = allocU((size_t)H3c*KPH);
    ushort_t* WTl   = allocU((size_t)H4c*KPE);
    ushort_t* WhhRT = allocU((size_t)17*64*288);
    ushort_t* hbLA  = allocU((size_t)BEc*288);
    ushort_t* hbLB  = allocU((size_t)BEc*288);
    float* cst     = alloc((size_t)BEc*288);
    float* bkvi    = alloc((size_t)NKVI);
    float* outlast = alloc((size_t)Bc*Hc);
    float* o1      = alloc((size_t)Bc*Hc);
    float* hev     = alloc((size_t)BEc*Hc);
    float* part1   = alloc((size_t)Bc*8*320);
    float* part23  = alloc((size_t)Bc*8*320);

    float* g       = gi;                    // alias: qk scores (dead by next kvgi)
    float* gatesx  = gi;                    // alias: lstm input gates (post-loop)
    ushort_t* Xgb  = scoreb;                // alias: lstm gathered embeddings (post-loop)
    (void)ws_size; (void)in_sizes; (void)n_in; (void)out_size;

    // ---- single prep kernel: conversions + zero-fills ----
    {
        long long nb = (PRTOT + 255) / 256;
        prep_kernel<<<dim3((unsigned)nb), dim3(256), 0, stream>>>(
            adj, u_emb, Wg, Wq, gru_Whh, lstm_Wih, lstm_Whh,
            Wk, Wv, gru_Wih, bk, bv, gru_bih,
            adjb, u_embb, WgT, WqT, WhhT, WTl, WhhRT, WkviT,
            bkvi, hbLA, hbLB, cst, hb);
    }

    ushort_t* no_prev = noB;
    ushort_t* no_cur  = noA;
    for (int t=0; t<Tc; t++){
        build_YT_kernel<<<dim3(Bc*CSc), dim3(256), 0, stream>>>(code_x, neighbors, c_emb, n_emb, t, YTb);
        mfma_k<0,8,0><<<dim3(2,8,8),256,0,stream>>>(adjb, YTb, nullptr,
            Spart, nullptr, nullptr, nullptr, nullptr,
            Nc, Bc*CSc, Nc, Nc, Nc, Bc*CSc, 0,0,(long long)Nc*Bc*CSc, 0);
        build_conoin_kernel<<<dim3(1024),dim3(256),0,stream>>>(code_x, neighbors, c_emb, n_emb, Spart, t, X2b);
        mfma_k<1,0,0><<<dim3(1,64,1),256,0,stream>>>(X2b, WgT, bg,
            cob, no_cur, nullptr, nullptr, nullptr,
            2*Bc*Nc, GSc, KPG, KPG, KPG, GSc, 0,0,0, 0);
        // k|v|gi fused
        mfma_k<3,0,0><<<dim3(9,32,1),256,0,stream>>>(cob, WkviT, bkvi,
            kb, vT, gi, nullptr, nullptr,
            Bc*Nc, NKVI, GSc, GSc, GSc, 0, 0,0,0, 0);
        if (t == 0){
            gru_combine_t0_kernel<<<dim3(Bc*Nc), dim3(256), 0, stream>>>(gi, gru_bhh, divided, hb);
        } else {
            // q = (m3 ? u_emb : no_prev) @ Wq + bq  (select fused into staging)
            mfma_k<2,0,1><<<dim3(1,32,1),256,0,stream>>>(no_prev, WqT, bq,
                qb, nullptr, u_embb, nullptr, divided,
                Bc*Nc, ATc, GSc, GSc, GSc, ATc, 0,0,0, t);
            mfma_k<0,0,0><<<dim3(7,32,1),256,0,stream>>>(hb, WhhT, gru_bhh,
                gh, nullptr, nullptr, nullptr, nullptr,
                Bc*Nc, H3c, KPH, KPH, KPH, H3c, 0,0,0, 0);
            gru_combine_kernel<<<dim3(Bc*Nc), dim3(256), 0, stream>>>(gi, gh, hb, hm1);
            mfma_k<0,0,0><<<dim3(8,8,Bc),256,0,stream>>>(qb, kb, nullptr,
                g, nullptr, nullptr, nullptr, nullptr,
                Nc, Nc, ATc, ATc, ATc, Nc,
                (long long)Nc*ATc, (long long)Nc*ATc, 0, 0);
            softmax_kernel<<<dim3(Nc,Bc),256,0,stream>>>(g, divided, t, scoreb);
            mfma_k<4,0,0><<<dim3(3,8,Bc),256,0,stream>>>(scoreb, vT, nullptr,
                hb, hm23, nullptr, hm1, divided,
                Nc, Hc, Nc, Nc, Bc*Nc, 0,
                (long long)Nc*Nc, (long long)Nc, 0, t);
            if (t == Tc-1){
                outlast_partial_kernel<<<dim3(8, Bc), dim3(256), 0, stream>>>(divided, hm1, hm23, part1, part23);
                outlast_combine_kernel<<<dim3(Bc), dim3(320), 0, stream>>>(part1, part23, outlast);
            }
        }
        ushort_t* tmp = no_prev; no_prev = no_cur; no_cur = tmp;
    }

    // ---- LSTM over last-visit events ----
    gather_emb_kernel<<<dim3(BEc*Lc), dim3(256), 0, stream>>>(events, Eemb, Xgb);
    mfma_k<0,0,0><<<dim3(9,32,1),256,0,stream>>>(Xgb, WTl, lstm_b,
        gatesx, nullptr, nullptr, nullptr, nullptr,
        BEc*Lc, H4c, KPE, KPE, KPE, H4c, 0,0,0, 0);
    {
        ushort_t* hin = hbLA; ushort_t* hout = hbLB;
        for (int l=0; l<Lc; l++){
            lstm_step_mfma<<<dim3(68), dim3(256), 0, stream>>>(
                gatesx + (size_t)l*BEc*H4c, WhhRT, hin, hout, cst,
                (l == Lc-1) ? hev : nullptr);
            ushort_t* tmp = hin; hin = hout; hout = tmp;
        }
    }

    // ---- heads ----
    heads_kernel<<<dim3(Bc), dim3(256), 0, stream>>>(outlast, hev, Wd, bd, ctx, o1);
    {
        dim3 grid((OUTc+63)/64, 1, 1);
        gemm_kernel<3><<<grid,dim3(256),0,stream>>>(o1, Wc, bc, out, Bc, OUTc, Hc);
    }
}

// Round 5
// 1326.846 us; speedup vs baseline: 3.7855x; 1.1145x over previous
//
#include <hip/hip_runtime.h>
#include <hip/hip_bf16.h>
#include <math.h>

// Problem constants
#define Bc   4
#define Tc   6
#define Nc   1024
#define CSc  48
#define GSc  32
#define Hc   270
#define ATc  32
#define DAc  64
#define Ec   32
#define Lc   32
#define EDc  400
#define OUTc 4000
#define H3c  810
#define H4c  1080
#define BEc  128
#define KPE  416    // ED padded
#define KPG  64     // CS padded
#define KAB  320    // Abuf K: 32 co + 270 h + 18 pad
#define NCMB 1382   // combined N: 32 k + 270 v + 270 r + 270 z + 270 in + 270 hn
#define NZCAP 96
#define INV_SQRT_AT_F 0.17677669529663687f

typedef unsigned short ushort_t;
using s8v  = __attribute__((ext_vector_type(8))) short;
using f4v  = __attribute__((ext_vector_type(4))) float;
using u16x8= __attribute__((ext_vector_type(8))) unsigned short;

__device__ __forceinline__ float sigmoid_f(float x){ return 1.0f/(1.0f+expf(-x)); }
__device__ __forceinline__ ushort_t f2bf(float x){
    __hip_bfloat16 b = __float2bfloat16(x);
    return *reinterpret_cast<ushort_t*>(&b);
}
__device__ __forceinline__ float b2f(ushort_t u){
    return __uint_as_float(((unsigned int)u)<<16);
}

// ---------------------------------------------------------------------------
// bf16 MFMA GEMM, 128x128 tile, 4 waves.
// EPIL 0: f32 store (+bias)
// EPIL 1: leaky-relu dual bf16: row<4096 -> Abuf (stride KAB), else no (stride 32)
// EPIL 2: bf16 store P0 (+bias)
// EPIL 4: pv: x=tanh(acc); fused h-update: P0=Abuf (h at [g*KAB+32+col]), P1=hm23 f32,
//         PF=hm1, DV=divided, tpar=t
// EPIL 5: combined kvgi+gh: col<32 kb bf16; col<302 vT bf16 transposed; else gsum f32
// ASEL 1: q_in row select: m3 ? u_embb(P2) : A(no_prev); DV=divided
// ASEL 2: cono on-the-fly: A=c_emb(f32), P2=n_emb(f32), PF=S, DV=code_x, DV2=neighbors
// ASEL 3: lstm gather: PF=Eemb(f32), DV=events
// ---------------------------------------------------------------------------
template<int EPIL, int SPLITK, int ASEL>
__global__ __launch_bounds__(256)
void mfma_k(const ushort_t* __restrict__ A, const ushort_t* __restrict__ BT,
            const float* __restrict__ bias,
            void* __restrict__ P0, void* __restrict__ P1, void* __restrict__ P2,
            const float* __restrict__ PF, const int* __restrict__ DV,
            const int* __restrict__ DV2,
            int M, int N, int Kp, int lda, int ldb, int ldc,
            long long sA, long long sB, long long sC, int tpar)
{
    __shared__ ushort_t As[128*40];
    __shared__ ushort_t Bs[128*40];
    const int z = blockIdx.z;
    int kbeg = 0, kend = Kp;
    if (SPLITK > 0){
        int ks = Kp / SPLITK;
        kbeg = z*ks; kend = kbeg + ks;
    } else {
        if (ASEL == 0) A += (size_t)z * (size_t)sA;
        BT += (size_t)z * (size_t)sB;
    }
    const int m0 = blockIdx.y*128, n0 = blockIdx.x*128;
    const int tid = threadIdx.x;
    const int w = tid>>6, l = tid&63;
    const int wm = (w>>1)*64, wn = (w&1)*64;
    const int lr = l&15, lk = (l>>4)*8, lq = l>>4;
    const int srow = tid>>2, kseg = tid&3;

    f4v acc[4][4];
    #pragma unroll
    for (int mi=0;mi<4;mi++)
      #pragma unroll
      for (int ni=0;ni<4;ni++)
        acc[mi][ni] = (f4v){0.0f,0.0f,0.0f,0.0f};

    for (int k0=kbeg;k0<kend;k0+=32){
        #pragma unroll
        for (int i=0;i<2;i++){
            int row = srow + i*64;
            int ga = m0+row;
            uint4 va = make_uint4(0u,0u,0u,0u);
            if (ga < M){
                if (ASEL == 1){
                    int b = ga>>10, n = ga&1023;
                    bool m3 = DV[(((size_t)b*Tc+tpar)*Nc+n)*3 + 2] > 0;
                    const ushort_t* src = m3 ? ((const ushort_t*)P2 + (size_t)n*GSc)
                                             : (A + (size_t)ga*lda);
                    va = *(const uint4*)(src + k0 + kseg*8);
                } else if (ASEL == 2){
                    int isno = ga >> 12;
                    int r = ga & 4095; int b = r >> 10, n = r & 1023;
                    int kk = k0 + kseg*8;
                    if (kk < CSc){
                        const float* emb = isno ? (const float*)P2 : (const float*)A;
                        const int*   msk = isno ? DV2 : DV;
                        float m = (float)msk[((size_t)b*Tc + tpar)*Nc + n];
                        f4v e0 = *(const f4v*)(emb + (size_t)n*CSc + kk);
                        f4v e1 = *(const f4v*)(emb + (size_t)n*CSc + kk + 4);
                        f4v s0 = *(const f4v*)(PF + (size_t)n*(Bc*CSc) + b*CSc + kk);
                        f4v s1 = *(const f4v*)(PF + (size_t)n*(Bc*CSc) + b*CSc + kk + 4);
                        u16x8 tmp;
                        #pragma unroll
                        for (int j=0;j<4;j++) tmp[j]   = f2bf(m*(e0[j]+s0[j]));
                        #pragma unroll
                        for (int j=0;j<4;j++) tmp[4+j] = f2bf(m*(e1[j]+s1[j]));
                        va = *(uint4*)&tmp;
                    }
                } else if (ASEL == 3){
                    int ll = ga >> 7, be = ga & 127; int b = be >> 5, e = be & 31;
                    int kk = k0 + kseg*8;
                    if (kk < EDc){
                        int ev = DV[(((size_t)b*Tc + (Tc-1))*Ec + e)*Lc + ll];
                        const float* src = PF + (size_t)ev*EDc + kk;
                        f4v e0 = *(const f4v*)src;
                        f4v e1 = *(const f4v*)(src + 4);
                        u16x8 tmp;
                        #pragma unroll
                        for (int j=0;j<4;j++) tmp[j]   = f2bf(e0[j]);
                        #pragma unroll
                        for (int j=0;j<4;j++) tmp[4+j] = f2bf(e1[j]);
                        va = *(uint4*)&tmp;
                    }
                } else {
                    va = *(const uint4*)(A + (size_t)ga*lda + k0 + kseg*8);
                }
            }
            *(uint4*)&As[row*40 + kseg*8] = va;
            int gb = n0+row;
            uint4 vb = make_uint4(0u,0u,0u,0u);
            if (gb < N) vb = *(const uint4*)(BT + (size_t)gb*ldb + k0 + kseg*8);
            *(uint4*)&Bs[row*40 + kseg*8] = vb;
        }
        __syncthreads();
        s8v af[4], bfr[4];
        #pragma unroll
        for (int mi=0;mi<4;mi++) af[mi]  = *(const s8v*)&As[(wm+mi*16+lr)*40 + lk];
        #pragma unroll
        for (int ni=0;ni<4;ni++) bfr[ni] = *(const s8v*)&Bs[(wn+ni*16+lr)*40 + lk];
        #pragma unroll
        for (int mi=0;mi<4;mi++)
          #pragma unroll
          for (int ni=0;ni<4;ni++)
            acc[mi][ni] = __builtin_amdgcn_mfma_f32_16x16x32_bf16(af[mi], bfr[ni], acc[mi][ni], 0,0,0);
        __syncthreads();
    }

    #pragma unroll
    for (int mi=0;mi<4;mi++){
      #pragma unroll
      for (int ni=0;ni<4;ni++){
        int col = n0+wn+ni*16+lr;
        if (col >= N) continue;
        float bv_ = (EPIL!=4 && bias) ? bias[col] : 0.0f;
        #pragma unroll
        for (int r=0;r<4;r++){
          int row = m0+wm+mi*16+lq*4+r;
          if (row >= M) continue;
          float x = acc[mi][ni][r] + bv_;
          if (EPIL == 0){
              float* C = (float*)P0;
              size_t base = (SPLITK>0) ? (size_t)z*(size_t)sC : 0;
              size_t grow = (SPLITK>0) ? (size_t)row : (size_t)z*M + row;
              C[base + grow*ldc + col] = x;
          } else if (EPIL == 1){
              x = (x>0.0f) ? x : 0.01f*x;
              if (row < 4096) ((ushort_t*)P0)[(size_t)row*KAB + col] = f2bf(x);
              else            ((ushort_t*)P1)[(size_t)(row-4096)*32 + col] = f2bf(x);
          } else if (EPIL == 2){
              ((ushort_t*)P0)[(size_t)row*ldc + col] = f2bf(x);
          } else if (EPIL == 5){
              if (col < 32)        ((ushort_t*)P0)[(size_t)row*32 + col] = f2bf(x);
              else if (col < 302)  ((ushort_t*)P1)[(size_t)(col-32)*4096 + row] = f2bf(x);
              else                 ((float*)P2)[(size_t)row*H4c + (col-302)] = x;
          } else if (EPIL == 4){
              float xt = tanhf(x);
              size_t grow = (size_t)z*M + row;
              const int* dv = DV + (((size_t)z*Tc + tpar)*Nc + row)*3;
              bool m1  = dv[0] > 0;
              bool m23 = (dv[1] > 0) || (dv[2] > 0);
              bool use23 = (tpar > 0) && m23;
              float hv = use23 ? xt : (m1 ? PF[grow*Hc + col] : 0.0f);
              ((ushort_t*)P0)[grow*KAB + 32 + col] = f2bf(hv);
              ((float*)P1)[grow*Hc + col] = xt;
          }
        }
      }
    }
}

// ---------------------------------------------------------------------------
// f32 tiled GEMM (final layer). ACT 3 = sigmoid.
// ---------------------------------------------------------------------------
template<int ACT>
__global__ __launch_bounds__(256)
void gemm_kernel(const float* __restrict__ A, const float* __restrict__ Bm,
                 const float* __restrict__ bias, float* __restrict__ C,
                 int M, int Nn, int K)
{
    constexpr int BM=64, BN=64, BK=16;
    __shared__ float As[BK][BM+4];
    __shared__ float Bs[BK][BN+4];
    const int row0 = blockIdx.y*BM, col0 = blockIdx.x*BN;
    const int tid = threadIdx.x;
    const int tr = (tid>>4)<<2;
    const int tc = (tid&15)<<2;
    const int ar = tid>>2;
    const int ac = (tid&3)<<2;
    const int br = tid>>4;
    const int bc = (tid&15)<<2;
    float acc[4][4] = {};
    for (int k0=0;k0<K;k0+=BK){
        #pragma unroll
        for (int i=0;i<4;i++){
            int gr=row0+ar, gc=k0+ac+i;
            As[ac+i][ar] = (gr<M && gc<K) ? A[(size_t)gr*K+gc] : 0.0f;
        }
        #pragma unroll
        for (int i=0;i<4;i++){
            int gr=k0+br, gc=col0+bc+i;
            Bs[br][bc+i] = (gr<K && gc<Nn) ? Bm[(size_t)gr*Nn+gc] : 0.0f;
        }
        __syncthreads();
        #pragma unroll
        for (int kk=0;kk<BK;kk++){
            float a0=As[kk][tr+0], a1=As[kk][tr+1], a2=As[kk][tr+2], a3=As[kk][tr+3];
            float b0=Bs[kk][tc+0], b1=Bs[kk][tc+1], b2=Bs[kk][tc+2], b3=Bs[kk][tc+3];
            acc[0][0]+=a0*b0; acc[0][1]+=a0*b1; acc[0][2]+=a0*b2; acc[0][3]+=a0*b3;
            acc[1][0]+=a1*b0; acc[1][1]+=a1*b1; acc[1][2]+=a1*b2; acc[1][3]+=a1*b3;
            acc[2][0]+=a2*b0; acc[2][1]+=a2*b1; acc[2][2]+=a2*b2; acc[2][3]+=a2*b3;
            acc[3][0]+=a3*b0; acc[3][1]+=a3*b1; acc[3][2]+=a3*b2; acc[3][3]+=a3*b3;
        }
        __syncthreads();
    }
    #pragma unroll
    for (int i=0;i<4;i++){
        int r=row0+tr+i; if (r>=M) continue;
        #pragma unroll
        for (int j=0;j<4;j++){
            int c=col0+tc+j; if (c>=Nn) continue;
            float x = acc[i][j];
            if (bias) x += bias[c];
            if (ACT==3) x = 1.0f/(1.0f+expf(-x));
            C[(size_t)r*Nn+c] = x;
        }
    }
}

// ---------------------------------------------------------------------------
// Prep: all weight conversions + zero-fills (cascading ranges).
// ---------------------------------------------------------------------------
#define PR0 32768LL     // u_embb
#define PR1 2048LL      // WgT [32][64]
#define PR2 1024LL      // WqT
#define PR3 442240LL    // WB [1382][320]
#define PR4 1382LL      // biasB
#define PR5 449280LL    // WTl [1080][416]
#define PR6 313344LL    // WhhRT [17][64][288]
#define PR7 73728LL     // zero hbLA+hbLB
#define PR8 36864LL     // zero cst
#define PR9 1310720LL   // zero Abuf [4096][320]
#define PRTOT (PR0+PR1+PR2+PR3+PR4+PR5+PR6+PR7+PR8+PR9)

__global__ void prep_kernel(const float* __restrict__ u_emb,
                            const float* __restrict__ Wg, const float* __restrict__ Wq,
                            const float* __restrict__ Wk, const float* __restrict__ Wv,
                            const float* __restrict__ gru_Wih, const float* __restrict__ gru_Whh,
                            const float* __restrict__ bk, const float* __restrict__ bv,
                            const float* __restrict__ gru_bih, const float* __restrict__ gru_bhh,
                            const float* __restrict__ lstm_Wih, const float* __restrict__ lstm_Whh,
                            ushort_t* u_embb, ushort_t* WgT, ushort_t* WqT,
                            ushort_t* WB, float* biasB, ushort_t* WTl, ushort_t* WhhRT,
                            ushort_t* hbLA, ushort_t* hbLB, float* cst, ushort_t* Abuf)
{
    long long idx = (long long)blockIdx.x*256 + threadIdx.x;
    if (idx < PR0){ u_embb[idx] = f2bf(u_emb[idx]); return; } idx -= PR0;
    if (idx < PR1){ int n=(int)(idx>>6), k=(int)(idx&63);
        WgT[idx] = (k<CSc) ? f2bf(Wg[(size_t)k*GSc+n]) : (ushort_t)0; return; } idx -= PR1;
    if (idx < PR2){ int n=(int)(idx>>5), k=(int)(idx&31);
        WqT[idx] = f2bf(Wq[(size_t)k*ATc+n]); return; } idx -= PR2;
    if (idx < PR3){
        int n=(int)(idx/KAB), k=(int)(idx%KAB);
        float v = 0.0f;
        if (n < 32){            if (k<32) v = Wk[(size_t)k*ATc + n]; }
        else if (n < 302){      if (k<32) v = Wv[(size_t)k*Hc + (n-32)]; }
        else if (n < 572){ int j=n-302;
            if (k<32) v = gru_Wih[(size_t)k*H3c + j];
            else if (k<302) v = gru_Whh[(size_t)(k-32)*H3c + j]; }
        else if (n < 842){ int j=(n-572)+270;
            if (k<32) v = gru_Wih[(size_t)k*H3c + j];
            else if (k<302) v = gru_Whh[(size_t)(k-32)*H3c + j]; }
        else if (n < 1112){ int j=(n-842)+540;
            if (k<32) v = gru_Wih[(size_t)k*H3c + j]; }
        else { int j=(n-1112)+540;
            if (k>=32 && k<302) v = gru_Whh[(size_t)(k-32)*H3c + j]; }
        WB[idx] = f2bf(v); return; } idx -= PR3;
    if (idx < PR4){
        int n = (int)idx; float v;
        if (n < 32)        v = bk[n];
        else if (n < 302)  v = bv[n-32];
        else if (n < 572)  v = gru_bih[n-302] + gru_bhh[n-302];
        else if (n < 842)  v = gru_bih[(n-572)+270] + gru_bhh[(n-572)+270];
        else if (n < 1112) v = gru_bih[(n-842)+540];
        else               v = gru_bhh[(n-1112)+540];
        biasB[n] = v; return; } idx -= PR4;
    if (idx < PR5){ int n=(int)(idx/KPE), k=(int)(idx%KPE);
        WTl[idx] = (k<EDc) ? f2bf(lstm_Wih[(size_t)k*H4c+n]) : (ushort_t)0; return; } idx -= PR5;
    if (idx < PR6){
        int jg=(int)(idx/(64*288)); int r2=(int)(idx%(64*288));
        int n=r2/288, k=r2%288;
        int gate=n>>4, jj=n&15, j=jg*16+jj;
        WhhRT[idx] = (k<Hc && j<Hc) ? f2bf(lstm_Whh[(size_t)k*H4c + gate*Hc + j]) : (ushort_t)0;
        return; } idx -= PR6;
    if (idx < PR7){ if (idx < 36864) hbLA[idx] = 0; else hbLB[idx-36864] = 0; return; } idx -= PR7;
    if (idx < PR8){ cst[idx] = 0.0f; return; } idx -= PR8;
    if (idx < PR9){ Abuf[idx] = 0; }
}

// ---------------------------------------------------------------------------
// adj nonzero-list build (adj entries are exactly 0.0/1.0)
// ---------------------------------------------------------------------------
__global__ void nz_build_kernel(const float* __restrict__ adj, int* __restrict__ nzc,
                                int* __restrict__ nzidx)
{
    int n = blockIdx.x;
    __shared__ int cnt;
    if (threadIdx.x == 0) cnt = 0;
    __syncthreads();
    for (int k = threadIdx.x; k < Nc; k += 256){
        if (adj[(size_t)n*Nc + k] != 0.0f){
            int pos = atomicAdd(&cnt, 1);
            if (pos < NZCAP) nzidx[(size_t)n*NZCAP + pos] = k;
        }
    }
    __syncthreads();
    if (threadIdx.x == 0) nzc[n] = (cnt < NZCAP) ? cnt : NZCAP;
}

// ---------------------------------------------------------------------------
// Sparse S: S[n][b*CS+c] = sum_{k in nz(n)} cm(b,k)*c_emb[k][c] + nm(b,k)*n_emb[k][c]
// ---------------------------------------------------------------------------
__global__ __launch_bounds__(192)
void s_sparse_kernel(const int* __restrict__ code_x, const int* __restrict__ neighbors,
                     const float* __restrict__ c_emb, const float* __restrict__ n_emb,
                     const int* __restrict__ nzc, const int* __restrict__ nzidx,
                     int t, float* __restrict__ S)
{
    int n = blockIdx.x;
    int tid = threadIdx.x;          // 0..191 = b*48+c
    int b = tid / CSc, c = tid % CSc;
    int cnt = nzc[n];
    float s = 0.0f;
    for (int i=0; i<cnt; i++){
        int k = nzidx[(size_t)n*NZCAP + i];
        int cm = code_x  [((size_t)b*Tc+t)*Nc + k];
        int nm = neighbors[((size_t)b*Tc+t)*Nc + k];
        float e = 0.0f;
        if (cm) e += c_emb[(size_t)k*CSc + c];
        if (nm) e += n_emb[(size_t)k*CSc + c];
        s += e;
    }
    S[(size_t)n*(Bc*CSc) + tid] = s;
}

// ---------------------------------------------------------------------------
// GRU combine (t>=1): gsum layout [r][1080] = r|z|in|hn
// ---------------------------------------------------------------------------
__global__ void gru_combine_kernel(const float* __restrict__ gsum, const ushort_t* __restrict__ Abuf,
                                   float* __restrict__ hm1)
{
    int r = blockIdx.x;
    const float* G = gsum + (size_t)r*H4c;
    for (int j = threadIdx.x; j < Hc; j += blockDim.x){
        float rg = sigmoid_f(G[j]);
        float zg = sigmoid_f(G[270+j]);
        float ng = tanhf(G[540+j] + rg*G[810+j]);
        float h  = b2f(Abuf[(size_t)r*KAB + 32 + j]);
        hm1[(size_t)r*Hc + j] = (1.0f-zg)*ng + zg*h;
    }
}

// t=0: h=0; write h_new = m1 ? (1-z)*n : 0 directly into Abuf
__global__ void gru_combine_t0_kernel(const float* __restrict__ gsum, const int* __restrict__ divided,
                                      ushort_t* __restrict__ Abuf)
{
    int r = blockIdx.x;
    int b = r >> 10, n = r & 1023;
    bool m1 = divided[(((size_t)b*Tc+0)*Nc+n)*3 + 0] > 0;
    const float* G = gsum + (size_t)r*H4c;
    for (int j = threadIdx.x; j < Hc; j += blockDim.x){
        float rg = sigmoid_f(G[j]);
        float zg = sigmoid_f(G[270+j]);
        float ng = tanhf(G[540+j] + rg*G[810+j]);
        float hv = (1.0f-zg)*ng;
        Abuf[(size_t)r*KAB + 32 + j] = m1 ? f2bf(hv) : (ushort_t)0;
    }
}

// ---------------------------------------------------------------------------
// masked softmax over f32 g -> bf16 score
// ---------------------------------------------------------------------------
__global__ __launch_bounds__(256)
void softmax_kernel(const float* __restrict__ g, const int* __restrict__ divided,
                    int t, ushort_t* __restrict__ scoreb)
{
    int i = blockIdx.x, b = blockIdx.y;
    int tid = threadIdx.x;
    __shared__ float red[8];
    const float* gr = g + ((size_t)b*Nc + i)*Nc;

    float gvals[4];
    float lmax = -INFINITY, lhas = 0.0f;
    #pragma unroll
    for (int jj=0;jj<4;jj++){
        int j = jj*256 + tid;
        float d = gr[j] * INV_SQRT_AT_F;
        const int* dv = divided + (((size_t)b*Tc+t)*Nc + j)*3;
        bool m23 = (dv[1] > 0) || (dv[2] > 0);
        lhas = fmaxf(lhas, m23 ? 1.0f : 0.0f);
        d = m23 ? d : -INFINITY;
        gvals[jj] = d;
        lmax = fmaxf(lmax, d);
    }
    #pragma unroll
    for (int o=1;o<64;o<<=1){
        lmax = fmaxf(lmax, __shfl_xor(lmax, o, 64));
        lhas = fmaxf(lhas, __shfl_xor(lhas, o, 64));
    }
    int wid = tid >> 6;
    if ((tid & 63) == 0){ red[wid] = lmax; red[4+wid] = lhas; }
    __syncthreads();
    float gmax = fmaxf(fmaxf(red[0],red[1]), fmaxf(red[2],red[3]));
    bool  has  = fmaxf(fmaxf(red[4],red[5]), fmaxf(red[6],red[7])) > 0.5f;

    float evals[4];
    float lsum = 0.0f;
    #pragma unroll
    for (int jj=0;jj<4;jj++){
        float e_;
        if (has) e_ = (gvals[jj] == -INFINITY) ? 0.0f : expf(gvals[jj]-gmax);
        else     e_ = 1.0f;
        evals[jj] = e_; lsum += e_;
    }
    #pragma unroll
    for (int o=1;o<64;o<<=1) lsum += __shfl_xor(lsum, o, 64);
    __syncthreads();
    if ((tid & 63) == 0) red[wid] = lsum;
    __syncthreads();
    float invs = 1.0f/(red[0]+red[1]+red[2]+red[3]);
    #pragma unroll
    for (int jj=0;jj<4;jj++){
        int j = jj*256 + tid;
        scoreb[((size_t)b*Nc+i)*Nc + j] = f2bf(evals[jj]*invs);
    }
}

// ---------------------------------------------------------------------------
// out_last reduction (t=5), coalesced: grid (32 chunks, B), 320 threads (j)
// ---------------------------------------------------------------------------
__global__ __launch_bounds__(320)
void outlast_partial_kernel(const int* __restrict__ divided,
                            const float* __restrict__ hm1, const float* __restrict__ hm23,
                            float* __restrict__ part1, float* __restrict__ part23)
{
    int nc = blockIdx.x, b = blockIdx.y;
    int j = threadIdx.x;
    if (j >= Hc) return;
    float m1v = -INFINITY, m23v = -INFINITY;
    #pragma unroll 4
    for (int n = nc*32; n < nc*32+32; n++){
        const int* dv = divided + (((size_t)b*Tc + (Tc-1))*Nc + n)*3;
        bool m1  = dv[0] > 0;
        bool m23 = (dv[1] > 0) || (dv[2] > 0);
        size_t o = ((size_t)b*Nc+n)*Hc + j;
        if (m1)  m1v  = fmaxf(m1v,  hm1[o]);
        if (m23) m23v = fmaxf(m23v, hm23[o]);
    }
    part1 [((size_t)b*32+nc)*320 + j] = m1v;
    part23[((size_t)b*32+nc)*320 + j] = m23v;
}

__global__ __launch_bounds__(320)
void outlast_combine_kernel(const float* __restrict__ part1, const float* __restrict__ part23,
                            float* __restrict__ outlast)
{
    int b = blockIdx.x; int j = threadIdx.x;
    if (j >= Hc) return;
    float a = -INFINITY, c = -INFINITY;
    for (int nc=0;nc<32;nc++){
        a = fmaxf(a, part1 [((size_t)b*32+nc)*320 + j]);
        c = fmaxf(c, part23[((size_t)b*32+nc)*320 + j]);
    }
    outlast[(size_t)b*Hc + j] = (a==-INFINITY ? 0.0f : a) + (c==-INFINITY ? 0.0f : c);
}

// ---------------------------------------------------------------------------
// LSTM MFMA step: 68 blocks = 4 cellgroups(32) x 17 jgroups(16 j-cols)
// ---------------------------------------------------------------------------
__global__ __launch_bounds__(256)
void lstm_step_mfma(const float* __restrict__ gx,
                    const ushort_t* __restrict__ WhhRT,
                    const ushort_t* __restrict__ hb_in,
                    ushort_t* __restrict__ hb_out,
                    float* __restrict__ cst,
                    float* __restrict__ hev_out)
{
    int cg = blockIdx.x & 3, jg = blockIdx.x >> 2;
    int tid = threadIdx.x;
    int w = tid>>6, l = tid&63;
    int mi = w>>1, ni0 = (w&1)*2;
    int arow = cg*32 + mi*16 + (l&15);
    int koff = (l>>4)*8;
    const ushort_t* Wb = WhhRT + (size_t)jg*64*288;

    f4v acc0 = (f4v){0,0,0,0}, acc1 = (f4v){0,0,0,0};
    #pragma unroll
    for (int k0=0;k0<288;k0+=32){
        s8v a  = *(const s8v*)(hb_in + (size_t)arow*288 + k0 + koff);
        s8v b0 = *(const s8v*)(Wb + (size_t)(ni0*16 + (l&15))*288 + k0 + koff);
        s8v b1 = *(const s8v*)(Wb + (size_t)((ni0+1)*16 + (l&15))*288 + k0 + koff);
        acc0 = __builtin_amdgcn_mfma_f32_16x16x32_bf16(a, b0, acc0, 0,0,0);
        acc1 = __builtin_amdgcn_mfma_f32_16x16x32_bf16(a, b1, acc1, 0,0,0);
    }
    __shared__ float gs[32][64];
    int crow = mi*16 + (l>>4)*4;
    int ccol = l&15;
    #pragma unroll
    for (int r=0;r<4;r++){
        gs[crow+r][ni0*16 + ccol]     = acc0[r];
        gs[crow+r][(ni0+1)*16 + ccol] = acc1[r];
    }
    __syncthreads();
    #pragma unroll
    for (int p=0;p<2;p++){
        int idx = tid + p*256;
        int cl = idx>>4, jj = idx&15;
        int j = jg*16 + jj;
        if (j < Hc){
            int cell = cg*32 + cl;
            const float* g = gx + (size_t)cell*H4c;
            float ig = sigmoid_f(gs[cl][jj]      + g[j]);
            float fg = sigmoid_f(gs[cl][16+jj]   + g[Hc+j]);
            float gg = tanhf    (gs[cl][32+jj]   + g[2*Hc+j]);
            float og = sigmoid_f(gs[cl][48+jj]   + g[3*Hc+j]);
            size_t co = (size_t)cell*288 + j;
            float cn = fg*cst[co] + ig*gg;
            cst[co] = cn;
            float hn = og*tanhf(cn);
            hb_out[co] = f2bf(hn);
            if (hev_out) hev_out[(size_t)cell*Hc + j] = hn;
        }
    }
}

// ---------------------------------------------------------------------------
// heads: wdc + dp_attention over [outlast ; hev] -> o1 (o2 == o1)
// ---------------------------------------------------------------------------
__global__ __launch_bounds__(256)
void heads_kernel(const float* __restrict__ outlast, const float* __restrict__ hev,
                  const float* __restrict__ Wd, const float* __restrict__ bd,
                  const float* __restrict__ ctx, float* __restrict__ o1)
{
    int b = blockIdx.x, tid = threadIdx.x;
    __shared__ float wdc[Hc+1];
    __shared__ float sc[Ec+1];
    for (int j=tid;j<Hc;j+=256){
        float s = 0.0f;
        for (int d=0;d<DAc;d++) s += Wd[(size_t)j*DAc+d]*ctx[d];
        wdc[j] = s;
    }
    if (tid == 255){
        float s = 0.0f;
        for (int d=0;d<DAc;d++) s += bd[d]*ctx[d];
        wdc[Hc] = s;
    }
    __syncthreads();
    if (tid < Ec+1){
        const float* x = (tid==0) ? (outlast + (size_t)b*Hc)
                                  : (hev + ((size_t)b*Ec + tid-1)*Hc);
        float s = wdc[Hc];
        for (int j=0;j<Hc;j++) s += x[j]*wdc[j];
        sc[tid] = s;
    }
    __syncthreads();
    if (tid == 0){
        float m = -INFINITY;
        for (int s=0;s<Ec+1;s++) m = fmaxf(m, sc[s]);
        float sum = 0.0f;
        for (int s=0;s<Ec+1;s++){ sc[s] = expf(sc[s]-m); sum += sc[s]; }
        float inv = 1.0f/sum;
        for (int s=0;s<Ec+1;s++) sc[s] *= inv;
    }
    __syncthreads();
    for (int j=tid;j<Hc;j+=256){
        float acc = sc[0]*outlast[(size_t)b*Hc + j];
        for (int e=0;e<Ec;e++) acc += sc[1+e]*hev[((size_t)b*Ec+e)*Hc + j];
        o1[(size_t)b*Hc + j] = acc;
    }
}

// ---------------------------------------------------------------------------
extern "C" void kernel_launch(void* const* d_in, const int* in_sizes, int n_in,
                              void* d_out, int out_size, void* d_ws, size_t ws_size,
                              hipStream_t stream)
{
    const int*   code_x    = (const int*)d_in[0];
    const int*   divided   = (const int*)d_in[1];
    const int*   neighbors = (const int*)d_in[2];
    const int*   events    = (const int*)d_in[4];
    const float* c_emb     = (const float*)d_in[5];
    const float* n_emb     = (const float*)d_in[6];
    const float* u_emb     = (const float*)d_in[7];
    const float* adj       = (const float*)d_in[8];
    const float* Wg        = (const float*)d_in[9];
    const float* bg        = (const float*)d_in[10];
    const float* gru_Wih   = (const float*)d_in[11];
    const float* gru_Whh   = (const float*)d_in[12];
    const float* gru_bih   = (const float*)d_in[13];
    const float* gru_bhh   = (const float*)d_in[14];
    const float* Wq        = (const float*)d_in[15];
    const float* bq        = (const float*)d_in[16];
    const float* Wk        = (const float*)d_in[17];
    const float* bk        = (const float*)d_in[18];
    const float* Wv        = (const float*)d_in[19];
    const float* bv        = (const float*)d_in[20];
    const float* Wd        = (const float*)d_in[21];
    const float* bd        = (const float*)d_in[22];
    const float* ctx       = (const float*)d_in[23];
    const float* Eemb      = (const float*)d_in[24];
    const float* lstm_Wih  = (const float*)d_in[25];
    const float* lstm_Whh  = (const float*)d_in[26];
    const float* lstm_b    = (const float*)d_in[27];
    const float* Wc        = (const float*)d_in[28];
    const float* bc        = (const float*)d_in[29];
    float* out = (float*)d_out;

    float* ws = (float*)d_ws;
    size_t off = 0;
    auto alloc = [&](size_t n){ n = (n+7)&~(size_t)7; float* p = ws + off; off += n; return p; };
    auto allocU = [&](size_t n){ return (ushort_t*)alloc((n+1)/2); };

    float* hm1     = alloc((size_t)Bc*Nc*Hc);
    float* hm23    = alloc((size_t)Bc*Nc*Hc);
    float* S       = alloc((size_t)Nc*Bc*CSc);
    float* gsum    = alloc((size_t)Bc*Nc*H4c);          // also g (qk) & gatesx (lstm) alias
    ushort_t* scoreb = allocU((size_t)Bc*Nc*Nc);
    ushort_t* Abuf  = allocU((size_t)Bc*Nc*KAB);        // [4096][320]: co | h | pad
    ushort_t* noA   = allocU((size_t)Bc*Nc*GSc);
    ushort_t* noB   = allocU((size_t)Bc*Nc*GSc);
    ushort_t* qb    = allocU((size_t)Bc*Nc*ATc);
    ushort_t* kb    = allocU((size_t)Bc*Nc*ATc);
    ushort_t* vT    = allocU((size_t)Hc*Bc*Nc);
    ushort_t* u_embb= allocU((size_t)Nc*GSc);
    ushort_t* WgT   = allocU((size_t)GSc*KPG);
    ushort_t* WqT   = allocU((size_t)ATc*GSc);
    ushort_t* WB    = allocU((size_t)NCMB*KAB);
    ushort_t* WTl   = allocU((size_t)H4c*KPE);
    ushort_t* WhhRT = allocU((size_t)17*64*288);
    ushort_t* hbLA  = allocU((size_t)BEc*288);
    ushort_t* hbLB  = allocU((size_t)BEc*288);
    float* cst     = alloc((size_t)BEc*288);
    float* biasB   = alloc((size_t)NCMB);
    int*   nzc     = (int*)alloc((size_t)Nc);
    int*   nzidx   = (int*)alloc((size_t)Nc*NZCAP);
    float* outlast = alloc((size_t)Bc*Hc);
    float* o1      = alloc((size_t)Bc*Hc);
    float* hev     = alloc((size_t)BEc*Hc);
    float* part1   = alloc((size_t)Bc*32*320);
    float* part23  = alloc((size_t)Bc*32*320);

    float* g       = gsum;     // qk scores alias (gsum dead after gru_combine)
    float* gatesx  = gsum;     // lstm input gates alias (post-loop)
    (void)ws_size; (void)in_sizes; (void)n_in; (void)out_size;

    // ---- prep: conversions + zero fills; adj nz-lists ----
    {
        long long nb = (PRTOT + 255) / 256;
        prep_kernel<<<dim3((unsigned)nb), dim3(256), 0, stream>>>(
            u_emb, Wg, Wq, Wk, Wv, gru_Wih, gru_Whh, bk, bv, gru_bih, gru_bhh,
            lstm_Wih, lstm_Whh,
            u_embb, WgT, WqT, WB, biasB, WTl, WhhRT, hbLA, hbLB, cst, Abuf);
        nz_build_kernel<<<dim3(Nc), dim3(256), 0, stream>>>(adj, nzc, nzidx);
    }

    ushort_t* no_prev = noB;
    ushort_t* no_cur  = noA;
    for (int t=0; t<Tc; t++){
        s_sparse_kernel<<<dim3(Nc), dim3(192), 0, stream>>>(code_x, neighbors, c_emb, n_emb,
                                                            nzc, nzidx, t, S);
        // co|no = leaky((mask*(emb+S)) @ Wg + bg): A built on the fly (ASEL2)
        mfma_k<1,0,2><<<dim3(1,64,1),256,0,stream>>>(
            (const ushort_t*)c_emb, WgT, bg,
            Abuf, no_cur, (void*)n_emb, S, code_x, neighbors,
            2*Bc*Nc, GSc, KPG, 0, KPG, 0, 0,0,0, t);
        // combined k|v|gates = [co|h] @ WB + biasB
        mfma_k<5,0,0><<<dim3(11,32,1),256,0,stream>>>(
            Abuf, WB, biasB,
            kb, vT, gsum, nullptr, nullptr, nullptr,
            Bc*Nc, NCMB, KAB, KAB, KAB, 0, 0,0,0, 0);
        if (t == 0){
            gru_combine_t0_kernel<<<dim3(Bc*Nc), dim3(256), 0, stream>>>(gsum, divided, Abuf);
        } else {
            gru_combine_kernel<<<dim3(Bc*Nc), dim3(256), 0, stream>>>(gsum, Abuf, hm1);
            // q = (m3 ? u_emb : no_prev) @ Wq + bq
            mfma_k<2,0,1><<<dim3(1,32,1),256,0,stream>>>(
                no_prev, WqT, bq,
                qb, nullptr, u_embb, nullptr, divided, nullptr,
                Bc*Nc, ATc, GSc, GSc, GSc, ATc, 0,0,0, t);
            // g = q @ k^T (batched over b)
            mfma_k<0,0,0><<<dim3(8,8,Bc),256,0,stream>>>(
                qb, kb, nullptr,
                g, nullptr, nullptr, nullptr, nullptr, nullptr,
                Nc, Nc, ATc, ATc, ATc, Nc,
                (long long)Nc*ATc, (long long)Nc*ATc, 0, 0);
            softmax_kernel<<<dim3(Nc,Bc),256,0,stream>>>(g, divided, t, scoreb);
            // hm23 = tanh(score @ v); fused h-update into Abuf
            mfma_k<4,0,0><<<dim3(3,8,Bc),256,0,stream>>>(
                scoreb, vT, nullptr,
                Abuf, hm23, nullptr, hm1, divided, nullptr,
                Nc, Hc, Nc, Nc, Bc*Nc, 0,
                (long long)Nc*Nc, (long long)Nc, 0, t);
            if (t == Tc-1){
                outlast_partial_kernel<<<dim3(32, Bc), dim3(320), 0, stream>>>(divided, hm1, hm23, part1, part23);
                outlast_combine_kernel<<<dim3(Bc), dim3(320), 0, stream>>>(part1, part23, outlast);
            }
        }
        ushort_t* tmp = no_prev; no_prev = no_cur; no_cur = tmp;
    }

    // ---- LSTM over last-visit events (gather fused into A-staging, ASEL3) ----
    mfma_k<0,0,3><<<dim3(9,32,1),256,0,stream>>>(
        nullptr, WTl, lstm_b,
        gatesx, nullptr, nullptr, Eemb, events, nullptr,
        BEc*Lc, H4c, KPE, 0, KPE, H4c, 0,0,0, 0);
    {
        ushort_t* hin = hbLA; ushort_t* hout = hbLB;
        for (int l=0; l<Lc; l++){
            lstm_step_mfma<<<dim3(68), dim3(256), 0, stream>>>(
                gatesx + (size_t)l*BEc*H4c, WhhRT, hin, hout, cst,
                (l == Lc-1) ? hev : nullptr);
            ushort_t* tmp = hin; hin = hout; hout = tmp;
        }
    }

    // ---- heads ----
    heads_kernel<<<dim3(Bc), dim3(256), 0, stream>>>(outlast, hev, Wd, bd, ctx, o1);
    {
        dim3 grid((OUTc+63)/64, 1, 1);
        gemm_kernel<3><<<grid,dim3(256),0,stream>>>(o1, Wc, bc, out, Bc, OUTc, Hc);
    }
}

// Round 6
// 1201.061 us; speedup vs baseline: 4.1819x; 1.1047x over previous
//
#include <hip/hip_runtime.h>
#include <hip/hip_bf16.h>
#include <math.h>

// Problem constants
#define Bc   4
#define Tc   6
#define Nc   1024
#define CSc  48
#define GSc  32
#define Hc   270
#define ATc  32
#define DAc  64
#define Ec   32
#define Lc   32
#define EDc  400
#define OUTc 4000
#define H3c  810
#define H4c  1080
#define BEc  128
#define KPE  416    // ED padded
#define KPG  64     // CS padded
#define KAB  320    // Abuf K: 32 co + 270 h + 18 pad
#define NCMB 1382   // combined N: 32 k + 270 v + 270 r + 270 z + 270 in + 270 hn
#define NZCAP 96
#define INV_SQRT_AT_F 0.17677669529663687f

typedef unsigned short ushort_t;
using s8v  = __attribute__((ext_vector_type(8))) short;
using f4v  = __attribute__((ext_vector_type(4))) float;
using u16x8= __attribute__((ext_vector_type(8))) unsigned short;

__device__ __forceinline__ float sigmoid_f(float x){ return 1.0f/(1.0f+expf(-x)); }
__device__ __forceinline__ ushort_t f2bf(float x){
    __hip_bfloat16 b = __float2bfloat16(x);
    return *reinterpret_cast<ushort_t*>(&b);
}
__device__ __forceinline__ float b2f(ushort_t u){
    return __uint_as_float(((unsigned int)u)<<16);
}

// ---------------------------------------------------------------------------
// bf16 MFMA GEMM, 128x128 tile, 4 waves.
// EPIL 0: f32 store (+bias)
// EPIL 1: leaky-relu dual bf16: row<4096 -> Abuf (stride KAB), else no (stride 32)
// EPIL 5: combined kvgi+gh: col<32 kb bf16; col<302 vT bf16 transposed; else gsum f32
// ASEL 2: cono on-the-fly: A=c_emb(f32), P2=n_emb(f32), PF=S, DV=code_x, DV2=neighbors
// ASEL 3: lstm gather: PF=Eemb(f32), DV=events
// ---------------------------------------------------------------------------
template<int EPIL, int SPLITK, int ASEL>
__global__ __launch_bounds__(256)
void mfma_k(const ushort_t* __restrict__ A, const ushort_t* __restrict__ BT,
            const float* __restrict__ bias,
            void* __restrict__ P0, void* __restrict__ P1, void* __restrict__ P2,
            const float* __restrict__ PF, const int* __restrict__ DV,
            const int* __restrict__ DV2,
            int M, int N, int Kp, int lda, int ldb, int ldc,
            long long sA, long long sB, long long sC, int tpar)
{
    __shared__ ushort_t As[128*40];
    __shared__ ushort_t Bs[128*40];
    const int z = blockIdx.z;
    int kbeg = 0, kend = Kp;
    if (SPLITK > 0){
        int ks = Kp / SPLITK;
        kbeg = z*ks; kend = kbeg + ks;
    } else {
        if (ASEL == 0) A += (size_t)z * (size_t)sA;
        BT += (size_t)z * (size_t)sB;
    }
    const int m0 = blockIdx.y*128, n0 = blockIdx.x*128;
    const int tid = threadIdx.x;
    const int w = tid>>6, l = tid&63;
    const int wm = (w>>1)*64, wn = (w&1)*64;
    const int lr = l&15, lk = (l>>4)*8, lq = l>>4;
    const int srow = tid>>2, kseg = tid&3;

    f4v acc[4][4];
    #pragma unroll
    for (int mi=0;mi<4;mi++)
      #pragma unroll
      for (int ni=0;ni<4;ni++)
        acc[mi][ni] = (f4v){0.0f,0.0f,0.0f,0.0f};

    for (int k0=kbeg;k0<kend;k0+=32){
        #pragma unroll
        for (int i=0;i<2;i++){
            int row = srow + i*64;
            int ga = m0+row;
            uint4 va = make_uint4(0u,0u,0u,0u);
            if (ga < M){
                if (ASEL == 2){
                    int isno = ga >> 12;
                    int r = ga & 4095; int b = r >> 10, n = r & 1023;
                    int kk = k0 + kseg*8;
                    if (kk < CSc){
                        const float* emb = isno ? (const float*)P2 : (const float*)A;
                        const int*   msk = isno ? DV2 : DV;
                        float m = (float)msk[((size_t)b*Tc + tpar)*Nc + n];
                        f4v e0 = *(const f4v*)(emb + (size_t)n*CSc + kk);
                        f4v e1 = *(const f4v*)(emb + (size_t)n*CSc + kk + 4);
                        f4v s0 = *(const f4v*)(PF + (size_t)n*(Bc*CSc) + b*CSc + kk);
                        f4v s1 = *(const f4v*)(PF + (size_t)n*(Bc*CSc) + b*CSc + kk + 4);
                        u16x8 tmp;
                        #pragma unroll
                        for (int j=0;j<4;j++) tmp[j]   = f2bf(m*(e0[j]+s0[j]));
                        #pragma unroll
                        for (int j=0;j<4;j++) tmp[4+j] = f2bf(m*(e1[j]+s1[j]));
                        va = *(uint4*)&tmp;
                    }
                } else if (ASEL == 3){
                    int ll = ga >> 7, be = ga & 127; int b = be >> 5, e = be & 31;
                    int kk = k0 + kseg*8;
                    if (kk < EDc){
                        int ev = DV[(((size_t)b*Tc + (Tc-1))*Ec + e)*Lc + ll];
                        const float* src = PF + (size_t)ev*EDc + kk;
                        f4v e0 = *(const f4v*)src;
                        f4v e1 = *(const f4v*)(src + 4);
                        u16x8 tmp;
                        #pragma unroll
                        for (int j=0;j<4;j++) tmp[j]   = f2bf(e0[j]);
                        #pragma unroll
                        for (int j=0;j<4;j++) tmp[4+j] = f2bf(e1[j]);
                        va = *(uint4*)&tmp;
                    }
                } else {
                    va = *(const uint4*)(A + (size_t)ga*lda + k0 + kseg*8);
                }
            }
            *(uint4*)&As[row*40 + kseg*8] = va;
            int gb = n0+row;
            uint4 vb = make_uint4(0u,0u,0u,0u);
            if (gb < N) vb = *(const uint4*)(BT + (size_t)gb*ldb + k0 + kseg*8);
            *(uint4*)&Bs[row*40 + kseg*8] = vb;
        }
        __syncthreads();
        s8v af[4], bfr[4];
        #pragma unroll
        for (int mi=0;mi<4;mi++) af[mi]  = *(const s8v*)&As[(wm+mi*16+lr)*40 + lk];
        #pragma unroll
        for (int ni=0;ni<4;ni++) bfr[ni] = *(const s8v*)&Bs[(wn+ni*16+lr)*40 + lk];
        #pragma unroll
        for (int mi=0;mi<4;mi++)
          #pragma unroll
          for (int ni=0;ni<4;ni++)
            acc[mi][ni] = __builtin_amdgcn_mfma_f32_16x16x32_bf16(af[mi], bfr[ni], acc[mi][ni], 0,0,0);
        __syncthreads();
    }

    #pragma unroll
    for (int mi=0;mi<4;mi++){
      #pragma unroll
      for (int ni=0;ni<4;ni++){
        int col = n0+wn+ni*16+lr;
        if (col >= N) continue;
        float bv_ = bias ? bias[col] : 0.0f;
        #pragma unroll
        for (int r=0;r<4;r++){
          int row = m0+wm+mi*16+lq*4+r;
          if (row >= M) continue;
          float x = acc[mi][ni][r] + bv_;
          if (EPIL == 0){
              float* C = (float*)P0;
              size_t base = (SPLITK>0) ? (size_t)z*(size_t)sC : 0;
              size_t grow = (SPLITK>0) ? (size_t)row : (size_t)z*M + row;
              C[base + grow*ldc + col] = x;
          } else if (EPIL == 1){
              x = (x>0.0f) ? x : 0.01f*x;
              if (row < 4096) ((ushort_t*)P0)[(size_t)row*KAB + col] = f2bf(x);
              else            ((ushort_t*)P1)[(size_t)(row-4096)*32 + col] = f2bf(x);
          } else if (EPIL == 5){
              if (col < 32)        ((ushort_t*)P0)[(size_t)row*32 + col] = f2bf(x);
              else if (col < 302)  ((ushort_t*)P1)[(size_t)(col-32)*4096 + row] = f2bf(x);
              else                 ((float*)P2)[(size_t)row*H4c + (col-302)] = x;
          }
        }
      }
    }
}

// ---------------------------------------------------------------------------
// Fused attention: per block = 16 q-rows of one batch. Grid (64, B), 256 thr.
// qin-select + q-proj + QK^T + masked softmax + PV + tanh + h-update, score
// tile entirely in LDS.
// ---------------------------------------------------------------------------
__global__ __launch_bounds__(256)
void attn_fused_kernel(const ushort_t* __restrict__ no_prev, const ushort_t* __restrict__ u_embb,
                       const float* __restrict__ Wq, const float* __restrict__ bq,
                       const ushort_t* __restrict__ kb, const ushort_t* __restrict__ vT,
                       const int* __restrict__ divided, const float* __restrict__ hm1,
                       ushort_t* __restrict__ Abuf, float* __restrict__ hm23,
                       int t, int wr23)
{
    __shared__ float    scs[16*1028];    // 16 rows x 1024 score (stride 1028 vs bank conflicts)
    __shared__ ushort_t stg[288*72];     // K-chunk staging (phase1) / V staging (phase3)
    __shared__ ushort_t Qs[16*40];
    __shared__ float    qinS[16*33];
    __shared__ float    WqS[32*33];
    __shared__ float    mskS[1024];
    __shared__ float    rowmax[16], rowinv[16], hasS[4];

    const int rt = blockIdx.x;           // 0..63
    const int b  = blockIdx.y;           // 0..3
    const int tid = threadIdx.x;
    const int w = tid>>6, l = tid&63, lr = l&15, lq = l>>4;
    const int lk8 = lq*8;
    const int row0 = rt*16;
    const size_t gq = (size_t)b*Nc + row0;

    // mask (per col, shared by all rows) + has23
    bool lany = false;
    #pragma unroll
    for (int c4=0;c4<4;c4++){
        int c = tid*4 + c4;
        const int* dv = divided + (((size_t)b*Tc + t)*Nc + c)*3;
        bool m23 = (dv[1]>0)||(dv[2]>0);
        mskS[c] = m23 ? 1.0f : 0.0f;
        lany |= m23;
    }
    if (l==0) hasS[w] = 0.0f;
    bool wany = __any(lany);
    if (l==0) hasS[w] = wany ? 1.0f : 0.0f;

    // qin staging (m3 select) + Wq
    for (int i=tid;i<16*32;i+=256){
        int r = i>>5, j = i&31;
        int n = row0 + r;
        bool m3 = divided[(((size_t)b*Tc+t)*Nc+n)*3+2] > 0;
        qinS[r*33+j] = m3 ? b2f(u_embb[(size_t)n*GSc+j]) : b2f(no_prev[(gq+r)*GSc+j]);
    }
    for (int i=tid;i<32*32;i+=256){
        int j=i>>5, o=i&31;
        WqS[j*33+o] = Wq[(size_t)j*ATc+o];
    }
    __syncthreads();
    const bool has = (hasS[0]+hasS[1]+hasS[2]+hasS[3]) > 0.5f;

    // q = qin @ Wq + bq  -> Qs bf16 [16][40]
    {
        int r = tid>>4, o2 = (tid&15)*2;
        float a0 = bq[o2], a1 = bq[o2+1];
        for (int j=0;j<32;j++){
            float q = qinS[r*33+j];
            a0 += q*WqS[j*33+o2];
            a1 += q*WqS[j*33+o2+1];
        }
        Qs[r*40+o2]   = f2bf(a0);
        Qs[r*40+o2+1] = f2bf(a1);
    }
    __syncthreads();

    // phase 1: QK^T -> scs (raw logits)
    for (int kt=0;kt<8;kt++){
        #pragma unroll
        for (int i2=0;i2<2;i2++){
            int idx = tid*2+i2;             // 0..511
            int kr = idx>>2, seg = idx&3;
            *(uint4*)&stg[kr*40 + seg*8] =
                *(const uint4*)(kb + ((size_t)b*Nc + kt*128 + kr)*GSc + seg*8);
        }
        __syncthreads();
        s8v af = *(const s8v*)&Qs[lr*40 + lk8];
        #pragma unroll
        for (int ni=0;ni<2;ni++){
            int nt = w*2 + ni;
            s8v bf = *(const s8v*)&stg[(nt*16+lr)*40 + lk8];
            f4v a0 = (f4v){0,0,0,0};
            a0 = __builtin_amdgcn_mfma_f32_16x16x32_bf16(af, bf, a0, 0,0,0);
            #pragma unroll
            for (int r2=0;r2<4;r2++)
                scs[(lq*4+r2)*1028 + kt*128 + nt*16 + lr] = a0[r2];
        }
        __syncthreads();
    }

    // phase 2: masked softmax (16 lanes per row)
    {
        int r = tid>>4, i = tid&15;
        if (has){
            float m = -INFINITY;
            for (int j=0;j<64;j++){
                int c = i + 16*j;
                if (mskS[c] > 0.5f) m = fmaxf(m, scs[r*1028+c]*INV_SQRT_AT_F);
            }
            #pragma unroll
            for (int o=1;o<16;o<<=1) m = fmaxf(m, __shfl_xor(m, o, 64));
            if (i==0) rowmax[r] = m;
        }
        __syncthreads();
        float gm = has ? rowmax[r] : 0.0f;
        float s = 0.0f;
        for (int j=0;j<64;j++){
            int c = i + 16*j;
            float p;
            if (has) p = (mskS[c]>0.5f) ? expf(scs[r*1028+c]*INV_SQRT_AT_F - gm) : 0.0f;
            else     p = 1.0f;
            scs[r*1028+c] = p;
            s += p;
        }
        #pragma unroll
        for (int o=1;o<16;o<<=1) s += __shfl_xor(s, o, 64);
        if (i==0) rowinv[r] = 1.0f/s;
    }
    // zero V pad rows 270..287 (only cols 0..63 are read)
    for (int i=tid;i<18*72;i+=256)
        stg[(270+(i/72))*72 + (i%72)] = 0;
    __syncthreads();
    const float inv = rowinv[lr];

    // phase 3: PV. wave w owns n-tiles {w, w+4, w+8, w+12, w+16(<18)}
    f4v acc[5];
    #pragma unroll
    for (int j=0;j<5;j++) acc[j] = (f4v){0,0,0,0};
    for (int vc=0;vc<16;vc++){
        for (int idx=tid; idx<2160; idx+=256){
            int n = idx>>3, seg = idx&7;
            *(uint4*)&stg[n*72 + seg*8] =
                *(const uint4*)(vT + (size_t)n*(Bc*Nc) + (size_t)b*Nc + vc*64 + seg*8);
        }
        __syncthreads();
        #pragma unroll
        for (int ki=0;ki<2;ki++){
            int kbase = vc*64 + ki*32 + lk8;
            u16x8 a16;
            #pragma unroll
            for (int e=0;e<8;e++) a16[e] = f2bf(scs[lr*1028 + kbase + e] * inv);
            s8v af = *(s8v*)&a16;
            #pragma unroll
            for (int j=0;j<5;j++){
                int nt = w + 4*j;
                if (nt < 18){
                    s8v bf = *(const s8v*)&stg[(nt*16+lr)*72 + ki*32 + lk8];
                    acc[j] = __builtin_amdgcn_mfma_f32_16x16x32_bf16(af, bf, acc[j], 0,0,0);
                }
            }
        }
        __syncthreads();
    }

    // phase 4: tanh + h-update epilogue
    #pragma unroll
    for (int j=0;j<5;j++){
        int nt = w + 4*j;
        if (nt >= 18) continue;
        int col = nt*16 + lr;
        if (col >= Hc) continue;
        #pragma unroll
        for (int r2=0;r2<4;r2++){
            int row16 = lq*4 + r2;
            size_t grow = gq + row16;
            int n = row0 + row16;
            const int* dv = divided + (((size_t)b*Tc + t)*Nc + n)*3;
            bool m1  = dv[0]>0;
            bool m23 = (dv[1]>0)||(dv[2]>0);
            float xt = tanhf(acc[j][r2]);
            float hv = m23 ? xt : (m1 ? hm1[grow*Hc + col] : 0.0f);
            Abuf[grow*KAB + 32 + col] = f2bf(hv);
            if (wr23) hm23[grow*Hc + col] = xt;
        }
    }
}

// ---------------------------------------------------------------------------
// f32 tiled GEMM (final layer). ACT 3 = sigmoid.
// ---------------------------------------------------------------------------
template<int ACT>
__global__ __launch_bounds__(256)
void gemm_kernel(const float* __restrict__ A, const float* __restrict__ Bm,
                 const float* __restrict__ bias, float* __restrict__ C,
                 int M, int Nn, int K)
{
    constexpr int BM=64, BN=64, BK=16;
    __shared__ float As[BK][BM+4];
    __shared__ float Bs[BK][BN+4];
    const int row0 = blockIdx.y*BM, col0 = blockIdx.x*BN;
    const int tid = threadIdx.x;
    const int tr = (tid>>4)<<2;
    const int tc = (tid&15)<<2;
    const int ar = tid>>2;
    const int ac = (tid&3)<<2;
    const int br = tid>>4;
    const int bc = (tid&15)<<2;
    float acc[4][4] = {};
    for (int k0=0;k0<K;k0+=BK){
        #pragma unroll
        for (int i=0;i<4;i++){
            int gr=row0+ar, gc=k0+ac+i;
            As[ac+i][ar] = (gr<M && gc<K) ? A[(size_t)gr*K+gc] : 0.0f;
        }
        #pragma unroll
        for (int i=0;i<4;i++){
            int gr=k0+br, gc=col0+bc+i;
            Bs[br][bc+i] = (gr<K && gc<Nn) ? Bm[(size_t)gr*Nn+gc] : 0.0f;
        }
        __syncthreads();
        #pragma unroll
        for (int kk=0;kk<BK;kk++){
            float a0=As[kk][tr+0], a1=As[kk][tr+1], a2=As[kk][tr+2], a3=As[kk][tr+3];
            float b0=Bs[kk][tc+0], b1=Bs[kk][tc+1], b2=Bs[kk][tc+2], b3=Bs[kk][tc+3];
            acc[0][0]+=a0*b0; acc[0][1]+=a0*b1; acc[0][2]+=a0*b2; acc[0][3]+=a0*b3;
            acc[1][0]+=a1*b0; acc[1][1]+=a1*b1; acc[1][2]+=a1*b2; acc[1][3]+=a1*b3;
            acc[2][0]+=a2*b0; acc[2][1]+=a2*b1; acc[2][2]+=a2*b2; acc[2][3]+=a2*b3;
            acc[3][0]+=a3*b0; acc[3][1]+=a3*b1; acc[3][2]+=a3*b2; acc[3][3]+=a3*b3;
        }
        __syncthreads();
    }
    #pragma unroll
    for (int i=0;i<4;i++){
        int r=row0+tr+i; if (r>=M) continue;
        #pragma unroll
        for (int j=0;j<4;j++){
            int c=col0+tc+j; if (c>=Nn) continue;
            float x = acc[i][j];
            if (bias) x += bias[c];
            if (ACT==3) x = 1.0f/(1.0f+expf(-x));
            C[(size_t)r*Nn+c] = x;
        }
    }
}

// ---------------------------------------------------------------------------
// Prep: all weight conversions + zero-fills (cascading ranges).
// ---------------------------------------------------------------------------
#define PR0 32768LL     // u_embb
#define PR1 2048LL      // WgT [32][64]
#define PR3 442240LL    // WB [1382][320]
#define PR4 1382LL      // biasB
#define PR5 449280LL    // WTl [1080][416]
#define PR6 313344LL    // WhhRT [17][64][288]
#define PR7 73728LL     // zero hbLA+hbLB
#define PR8 36864LL     // zero cst
#define PR9 1310720LL   // zero Abuf [4096][320]
#define PRTOT (PR0+PR1+PR3+PR4+PR5+PR6+PR7+PR8+PR9)

__global__ void prep_kernel(const float* __restrict__ u_emb,
                            const float* __restrict__ Wg,
                            const float* __restrict__ Wk, const float* __restrict__ Wv,
                            const float* __restrict__ gru_Wih, const float* __restrict__ gru_Whh,
                            const float* __restrict__ bk, const float* __restrict__ bv,
                            const float* __restrict__ gru_bih, const float* __restrict__ gru_bhh,
                            const float* __restrict__ lstm_Wih, const float* __restrict__ lstm_Whh,
                            ushort_t* u_embb, ushort_t* WgT,
                            ushort_t* WB, float* biasB, ushort_t* WTl, ushort_t* WhhRT,
                            ushort_t* hbLA, ushort_t* hbLB, float* cst, ushort_t* Abuf)
{
    long long idx = (long long)blockIdx.x*256 + threadIdx.x;
    if (idx < PR0){ u_embb[idx] = f2bf(u_emb[idx]); return; } idx -= PR0;
    if (idx < PR1){ int n=(int)(idx>>6), k=(int)(idx&63);
        WgT[idx] = (k<CSc) ? f2bf(Wg[(size_t)k*GSc+n]) : (ushort_t)0; return; } idx -= PR1;
    if (idx < PR3){
        int n=(int)(idx/KAB), k=(int)(idx%KAB);
        float v = 0.0f;
        if (n < 32){            if (k<32) v = Wk[(size_t)k*ATc + n]; }
        else if (n < 302){      if (k<32) v = Wv[(size_t)k*Hc + (n-32)]; }
        else if (n < 572){ int j=n-302;
            if (k<32) v = gru_Wih[(size_t)k*H3c + j];
            else if (k<302) v = gru_Whh[(size_t)(k-32)*H3c + j]; }
        else if (n < 842){ int j=(n-572)+270;
            if (k<32) v = gru_Wih[(size_t)k*H3c + j];
            else if (k<302) v = gru_Whh[(size_t)(k-32)*H3c + j]; }
        else if (n < 1112){ int j=(n-842)+540;
            if (k<32) v = gru_Wih[(size_t)k*H3c + j]; }
        else { int j=(n-1112)+540;
            if (k>=32 && k<302) v = gru_Whh[(size_t)(k-32)*H3c + j]; }
        WB[idx] = f2bf(v); return; } idx -= PR3;
    if (idx < PR4){
        int n = (int)idx; float v;
        if (n < 32)        v = bk[n];
        else if (n < 302)  v = bv[n-32];
        else if (n < 572)  v = gru_bih[n-302] + gru_bhh[n-302];
        else if (n < 842)  v = gru_bih[(n-572)+270] + gru_bhh[(n-572)+270];
        else if (n < 1112) v = gru_bih[(n-842)+540];
        else               v = gru_bhh[(n-1112)+540];
        biasB[n] = v; return; } idx -= PR4;
    if (idx < PR5){ int n=(int)(idx/KPE), k=(int)(idx%KPE);
        WTl[idx] = (k<EDc) ? f2bf(lstm_Wih[(size_t)k*H4c+n]) : (ushort_t)0; return; } idx -= PR5;
    if (idx < PR6){
        int jg=(int)(idx/(64*288)); int r2=(int)(idx%(64*288));
        int n=r2/288, k=r2%288;
        int gate=n>>4, jj=n&15, j=jg*16+jj;
        WhhRT[idx] = (k<Hc && j<Hc) ? f2bf(lstm_Whh[(size_t)k*H4c + gate*Hc + j]) : (ushort_t)0;
        return; } idx -= PR6;
    if (idx < PR7){ if (idx < 36864) hbLA[idx] = 0; else hbLB[idx-36864] = 0; return; } idx -= PR7;
    if (idx < PR8){ cst[idx] = 0.0f; return; } idx -= PR8;
    if (idx < PR9){ Abuf[idx] = 0; }
}

// ---------------------------------------------------------------------------
// adj nonzero-list build (adj entries are exactly 0.0/1.0)
// ---------------------------------------------------------------------------
__global__ void nz_build_kernel(const float* __restrict__ adj, int* __restrict__ nzc,
                                int* __restrict__ nzidx)
{
    int n = blockIdx.x;
    __shared__ int cnt;
    if (threadIdx.x == 0) cnt = 0;
    __syncthreads();
    for (int k = threadIdx.x; k < Nc; k += 256){
        if (adj[(size_t)n*Nc + k] != 0.0f){
            int pos = atomicAdd(&cnt, 1);
            if (pos < NZCAP) nzidx[(size_t)n*NZCAP + pos] = k;
        }
    }
    __syncthreads();
    if (threadIdx.x == 0) nzc[n] = (cnt < NZCAP) ? cnt : NZCAP;
}

// ---------------------------------------------------------------------------
// Sparse S: S[n][b*CS+c] = sum_{k in nz(n)} cm(b,k)*c_emb[k][c] + nm(b,k)*n_emb[k][c]
// ---------------------------------------------------------------------------
__global__ __launch_bounds__(192)
void s_sparse_kernel(const int* __restrict__ code_x, const int* __restrict__ neighbors,
                     const float* __restrict__ c_emb, const float* __restrict__ n_emb,
                     const int* __restrict__ nzc, const int* __restrict__ nzidx,
                     int t, float* __restrict__ S)
{
    int n = blockIdx.x;
    int tid = threadIdx.x;
    int b = tid / CSc, c = tid % CSc;
    int cnt = nzc[n];
    float s = 0.0f;
    for (int i=0; i<cnt; i++){
        int k = nzidx[(size_t)n*NZCAP + i];
        int cm = code_x  [((size_t)b*Tc+t)*Nc + k];
        int nm = neighbors[((size_t)b*Tc+t)*Nc + k];
        float e = 0.0f;
        if (cm) e += c_emb[(size_t)k*CSc + c];
        if (nm) e += n_emb[(size_t)k*CSc + c];
        s += e;
    }
    S[(size_t)n*(Bc*CSc) + tid] = s;
}

// ---------------------------------------------------------------------------
// GRU combine (t>=1): gsum layout [r][1080] = r|z|in|hn
// ---------------------------------------------------------------------------
__global__ void gru_combine_kernel(const float* __restrict__ gsum, const ushort_t* __restrict__ Abuf,
                                   float* __restrict__ hm1)
{
    int r = blockIdx.x;
    const float* G = gsum + (size_t)r*H4c;
    for (int j = threadIdx.x; j < Hc; j += blockDim.x){
        float rg = sigmoid_f(G[j]);
        float zg = sigmoid_f(G[270+j]);
        float ng = tanhf(G[540+j] + rg*G[810+j]);
        float h  = b2f(Abuf[(size_t)r*KAB + 32 + j]);
        hm1[(size_t)r*Hc + j] = (1.0f-zg)*ng + zg*h;
    }
}

// t=0: h=0; write h_new = m1 ? (1-z)*n : 0 directly into Abuf
__global__ void gru_combine_t0_kernel(const float* __restrict__ gsum, const int* __restrict__ divided,
                                      ushort_t* __restrict__ Abuf)
{
    int r = blockIdx.x;
    int b = r >> 10, n = r & 1023;
    bool m1 = divided[(((size_t)b*Tc+0)*Nc+n)*3 + 0] > 0;
    const float* G = gsum + (size_t)r*H4c;
    for (int j = threadIdx.x; j < Hc; j += blockDim.x){
        float rg = sigmoid_f(G[j]);
        float zg = sigmoid_f(G[270+j]);
        float ng = tanhf(G[540+j] + rg*G[810+j]);
        float hv = (1.0f-zg)*ng;
        Abuf[(size_t)r*KAB + 32 + j] = m1 ? f2bf(hv) : (ushort_t)0;
    }
}

// ---------------------------------------------------------------------------
// out_last reduction (t=5), coalesced
// ---------------------------------------------------------------------------
__global__ __launch_bounds__(320)
void outlast_partial_kernel(const int* __restrict__ divided,
                            const float* __restrict__ hm1, const float* __restrict__ hm23,
                            float* __restrict__ part1, float* __restrict__ part23)
{
    int nc = blockIdx.x, b = blockIdx.y;
    int j = threadIdx.x;
    if (j >= Hc) return;
    float m1v = -INFINITY, m23v = -INFINITY;
    #pragma unroll 4
    for (int n = nc*32; n < nc*32+32; n++){
        const int* dv = divided + (((size_t)b*Tc + (Tc-1))*Nc + n)*3;
        bool m1  = dv[0] > 0;
        bool m23 = (dv[1] > 0) || (dv[2] > 0);
        size_t o = ((size_t)b*Nc+n)*Hc + j;
        if (m1)  m1v  = fmaxf(m1v,  hm1[o]);
        if (m23) m23v = fmaxf(m23v, hm23[o]);
    }
    part1 [((size_t)b*32+nc)*320 + j] = m1v;
    part23[((size_t)b*32+nc)*320 + j] = m23v;
}

__global__ __launch_bounds__(320)
void outlast_combine_kernel(const float* __restrict__ part1, const float* __restrict__ part23,
                            float* __restrict__ outlast)
{
    int b = blockIdx.x; int j = threadIdx.x;
    if (j >= Hc) return;
    float a = -INFINITY, c = -INFINITY;
    for (int nc=0;nc<32;nc++){
        a = fmaxf(a, part1 [((size_t)b*32+nc)*320 + j]);
        c = fmaxf(c, part23[((size_t)b*32+nc)*320 + j]);
    }
    outlast[(size_t)b*Hc + j] = (a==-INFINITY ? 0.0f : a) + (c==-INFINITY ? 0.0f : c);
}

// ---------------------------------------------------------------------------
// LSTM MFMA step: 68 blocks = 4 cellgroups(32) x 17 jgroups(16 j-cols)
// ---------------------------------------------------------------------------
__global__ __launch_bounds__(256)
void lstm_step_mfma(const float* __restrict__ gx,
                    const ushort_t* __restrict__ WhhRT,
                    const ushort_t* __restrict__ hb_in,
                    ushort_t* __restrict__ hb_out,
                    float* __restrict__ cst,
                    float* __restrict__ hev_out)
{
    int cg = blockIdx.x & 3, jg = blockIdx.x >> 2;
    int tid = threadIdx.x;
    int w = tid>>6, l = tid&63;
    int mi = w>>1, ni0 = (w&1)*2;
    int arow = cg*32 + mi*16 + (l&15);
    int koff = (l>>4)*8;
    const ushort_t* Wb = WhhRT + (size_t)jg*64*288;

    f4v acc0 = (f4v){0,0,0,0}, acc1 = (f4v){0,0,0,0};
    #pragma unroll
    for (int k0=0;k0<288;k0+=32){
        s8v a  = *(const s8v*)(hb_in + (size_t)arow*288 + k0 + koff);
        s8v b0 = *(const s8v*)(Wb + (size_t)(ni0*16 + (l&15))*288 + k0 + koff);
        s8v b1 = *(const s8v*)(Wb + (size_t)((ni0+1)*16 + (l&15))*288 + k0 + koff);
        acc0 = __builtin_amdgcn_mfma_f32_16x16x32_bf16(a, b0, acc0, 0,0,0);
        acc1 = __builtin_amdgcn_mfma_f32_16x16x32_bf16(a, b1, acc1, 0,0,0);
    }
    __shared__ float gs[32][64];
    int crow = mi*16 + (l>>4)*4;
    int ccol = l&15;
    #pragma unroll
    for (int r=0;r<4;r++){
        gs[crow+r][ni0*16 + ccol]     = acc0[r];
        gs[crow+r][(ni0+1)*16 + ccol] = acc1[r];
    }
    __syncthreads();
    #pragma unroll
    for (int p=0;p<2;p++){
        int idx = tid + p*256;
        int cl = idx>>4, jj = idx&15;
        int j = jg*16 + jj;
        if (j < Hc){
            int cell = cg*32 + cl;
            const float* g = gx + (size_t)cell*H4c;
            float ig = sigmoid_f(gs[cl][jj]      + g[j]);
            float fg = sigmoid_f(gs[cl][16+jj]   + g[Hc+j]);
            float gg = tanhf    (gs[cl][32+jj]   + g[2*Hc+j]);
            float og = sigmoid_f(gs[cl][48+jj]   + g[3*Hc+j]);
            size_t co = (size_t)cell*288 + j;
            float cn = fg*cst[co] + ig*gg;
            cst[co] = cn;
            float hn = og*tanhf(cn);
            hb_out[co] = f2bf(hn);
            if (hev_out) hev_out[(size_t)cell*Hc + j] = hn;
        }
    }
}

// ---------------------------------------------------------------------------
// heads: wdc + dp_attention over [outlast ; hev] -> o1 (o2 == o1)
// ---------------------------------------------------------------------------
__global__ __launch_bounds__(256)
void heads_kernel(const float* __restrict__ outlast, const float* __restrict__ hev,
                  const float* __restrict__ Wd, const float* __restrict__ bd,
                  const float* __restrict__ ctx, float* __restrict__ o1)
{
    int b = blockIdx.x, tid = threadIdx.x;
    __shared__ float wdc[Hc+1];
    __shared__ float sc[Ec+1];
    for (int j=tid;j<Hc;j+=256){
        float s = 0.0f;
        for (int d=0;d<DAc;d++) s += Wd[(size_t)j*DAc+d]*ctx[d];
        wdc[j] = s;
    }
    if (tid == 255){
        float s = 0.0f;
        for (int d=0;d<DAc;d++) s += bd[d]*ctx[d];
        wdc[Hc] = s;
    }
    __syncthreads();
    if (tid < Ec+1){
        const float* x = (tid==0) ? (outlast + (size_t)b*Hc)
                                  : (hev + ((size_t)b*Ec + tid-1)*Hc);
        float s = wdc[Hc];
        for (int j=0;j<Hc;j++) s += x[j]*wdc[j];
        sc[tid] = s;
    }
    __syncthreads();
    if (tid == 0){
        float m = -INFINITY;
        for (int s=0;s<Ec+1;s++) m = fmaxf(m, sc[s]);
        float sum = 0.0f;
        for (int s=0;s<Ec+1;s++){ sc[s] = expf(sc[s]-m); sum += sc[s]; }
        float inv = 1.0f/sum;
        for (int s=0;s<Ec+1;s++) sc[s] *= inv;
    }
    __syncthreads();
    for (int j=tid;j<Hc;j+=256){
        float acc = sc[0]*outlast[(size_t)b*Hc + j];
        for (int e=0;e<Ec;e++) acc += sc[1+e]*hev[((size_t)b*Ec+e)*Hc + j];
        o1[(size_t)b*Hc + j] = acc;
    }
}

// ---------------------------------------------------------------------------
extern "C" void kernel_launch(void* const* d_in, const int* in_sizes, int n_in,
                              void* d_out, int out_size, void* d_ws, size_t ws_size,
                              hipStream_t stream)
{
    const int*   code_x    = (const int*)d_in[0];
    const int*   divided   = (const int*)d_in[1];
    const int*   neighbors = (const int*)d_in[2];
    const int*   events    = (const int*)d_in[4];
    const float* c_emb     = (const float*)d_in[5];
    const float* n_emb     = (const float*)d_in[6];
    const float* u_emb     = (const float*)d_in[7];
    const float* adj       = (const float*)d_in[8];
    const float* Wg        = (const float*)d_in[9];
    const float* bg        = (const float*)d_in[10];
    const float* gru_Wih   = (const float*)d_in[11];
    const float* gru_Whh   = (const float*)d_in[12];
    const float* gru_bih   = (const float*)d_in[13];
    const float* gru_bhh   = (const float*)d_in[14];
    const float* Wq        = (const float*)d_in[15];
    const float* bq        = (const float*)d_in[16];
    const float* Wk        = (const float*)d_in[17];
    const float* bk        = (const float*)d_in[18];
    const float* Wv        = (const float*)d_in[19];
    const float* bv        = (const float*)d_in[20];
    const float* Wd        = (const float*)d_in[21];
    const float* bd        = (const float*)d_in[22];
    const float* ctx       = (const float*)d_in[23];
    const float* Eemb      = (const float*)d_in[24];
    const float* lstm_Wih  = (const float*)d_in[25];
    const float* lstm_Whh  = (const float*)d_in[26];
    const float* lstm_b    = (const float*)d_in[27];
    const float* Wc        = (const float*)d_in[28];
    const float* bc        = (const float*)d_in[29];
    float* out = (float*)d_out;

    float* ws = (float*)d_ws;
    size_t off = 0;
    auto alloc = [&](size_t n){ n = (n+7)&~(size_t)7; float* p = ws + off; off += n; return p; };
    auto allocU = [&](size_t n){ return (ushort_t*)alloc((n+1)/2); };

    float* hm1     = alloc((size_t)Bc*Nc*Hc);
    float* hm23    = alloc((size_t)Bc*Nc*Hc);
    float* S       = alloc((size_t)Nc*Bc*CSc);
    float* gsum    = alloc((size_t)Bc*Nc*H4c);          // also gatesx (lstm) alias
    ushort_t* Abuf  = allocU((size_t)Bc*Nc*KAB);        // [4096][320]: co | h | pad
    ushort_t* noA   = allocU((size_t)Bc*Nc*GSc);
    ushort_t* noB   = allocU((size_t)Bc*Nc*GSc);
    ushort_t* kb    = allocU((size_t)Bc*Nc*ATc);
    ushort_t* vT    = allocU((size_t)Hc*Bc*Nc);
    ushort_t* u_embb= allocU((size_t)Nc*GSc);
    ushort_t* WgT   = allocU((size_t)GSc*KPG);
    ushort_t* WB    = allocU((size_t)NCMB*KAB);
    ushort_t* WTl   = allocU((size_t)H4c*KPE);
    ushort_t* WhhRT = allocU((size_t)17*64*288);
    ushort_t* hbLA  = allocU((size_t)BEc*288);
    ushort_t* hbLB  = allocU((size_t)BEc*288);
    float* cst     = alloc((size_t)BEc*288);
    float* biasB   = alloc((size_t)NCMB);
    int*   nzc     = (int*)alloc((size_t)Nc);
    int*   nzidx   = (int*)alloc((size_t)Nc*NZCAP);
    float* outlast = alloc((size_t)Bc*Hc);
    float* o1      = alloc((size_t)Bc*Hc);
    float* hev     = alloc((size_t)BEc*Hc);
    float* part1   = alloc((size_t)Bc*32*320);
    float* part23  = alloc((size_t)Bc*32*320);

    float* gatesx  = gsum;     // lstm input gates alias (post-loop)
    (void)ws_size; (void)in_sizes; (void)n_in; (void)out_size;

    // ---- prep: conversions + zero fills; adj nz-lists ----
    {
        long long nb = (PRTOT + 255) / 256;
        prep_kernel<<<dim3((unsigned)nb), dim3(256), 0, stream>>>(
            u_emb, Wg, Wk, Wv, gru_Wih, gru_Whh, bk, bv, gru_bih, gru_bhh,
            lstm_Wih, lstm_Whh,
            u_embb, WgT, WB, biasB, WTl, WhhRT, hbLA, hbLB, cst, Abuf);
        nz_build_kernel<<<dim3(Nc), dim3(256), 0, stream>>>(adj, nzc, nzidx);
    }

    ushort_t* no_prev = noB;
    ushort_t* no_cur  = noA;
    for (int t=0; t<Tc; t++){
        s_sparse_kernel<<<dim3(Nc), dim3(192), 0, stream>>>(code_x, neighbors, c_emb, n_emb,
                                                            nzc, nzidx, t, S);
        // co|no = leaky((mask*(emb+S)) @ Wg + bg): A built on the fly (ASEL2)
        mfma_k<1,0,2><<<dim3(1,64,1),256,0,stream>>>(
            (const ushort_t*)c_emb, WgT, bg,
            Abuf, no_cur, (void*)n_emb, S, code_x, neighbors,
            2*Bc*Nc, GSc, KPG, 0, KPG, 0, 0,0,0, t);
        // combined k|v|gates = [co|h] @ WB + biasB
        mfma_k<5,0,0><<<dim3(11,32,1),256,0,stream>>>(
            Abuf, WB, biasB,
            kb, vT, gsum, nullptr, nullptr, nullptr,
            Bc*Nc, NCMB, KAB, KAB, KAB, 0, 0,0,0, 0);
        if (t == 0){
            gru_combine_t0_kernel<<<dim3(Bc*Nc), dim3(256), 0, stream>>>(gsum, divided, Abuf);
        } else {
            gru_combine_kernel<<<dim3(Bc*Nc), dim3(256), 0, stream>>>(gsum, Abuf, hm1);
            // fused attention: qin-select + q + QK^T + softmax + PV + h-update
            attn_fused_kernel<<<dim3(64, Bc), dim3(256), 0, stream>>>(
                no_prev, u_embb, Wq, bq, kb, vT, divided, hm1,
                Abuf, hm23, t, (t == Tc-1) ? 1 : 0);
            if (t == Tc-1){
                outlast_partial_kernel<<<dim3(32, Bc), dim3(320), 0, stream>>>(divided, hm1, hm23, part1, part23);
                outlast_combine_kernel<<<dim3(Bc), dim3(320), 0, stream>>>(part1, part23, outlast);
            }
        }
        ushort_t* tmp = no_prev; no_prev = no_cur; no_cur = tmp;
    }

    // ---- LSTM over last-visit events (gather fused into A-staging, ASEL3) ----
    mfma_k<0,0,3><<<dim3(9,32,1),256,0,stream>>>(
        nullptr, WTl, lstm_b,
        gatesx, nullptr, nullptr, Eemb, events, nullptr,
        BEc*Lc, H4c, KPE, 0, KPE, H4c, 0,0,0, 0);
    {
        ushort_t* hin = hbLA; ushort_t* hout = hbLB;
        for (int l=0; l<Lc; l++){
            lstm_step_mfma<<<dim3(68), dim3(256), 0, stream>>>(
                gatesx + (size_t)l*BEc*H4c, WhhRT, hin, hout, cst,
                (l == Lc-1) ? hev : nullptr);
            ushort_t* tmp = hin; hin = hout; hout = tmp;
        }
    }

    // ---- heads ----
    heads_kernel<<<dim3(Bc), dim3(256), 0, stream>>>(outlast, hev, Wd, bd, ctx, o1);
    {
        dim3 grid((OUTc+63)/64, 1, 1);
        gemm_kernel<3><<<grid,dim3(256),0,stream>>>(o1, Wc, bc, out, Bc, OUTc, Hc);
    }
}